// Round 9
// baseline (1287.922 us; speedup 1.0000x reference)
//
#include <hip/hip_runtime.h>
#include <hip/hip_bf16.h>
#include <math.h>

#define B_ 4
#define S_ 1024
#define D_ 512
#define H_ 8
#define L_ 4
#define DFF_ 2048
#define V_ 32000
#define DK_ 64
#define KTOP 307
#define SRS 1048    // score row stride in u16 elems

using bf16x8 = __attribute__((ext_vector_type(8))) __bf16;
using bf16x4 = __attribute__((ext_vector_type(4))) __bf16;
using bf16x2 = __attribute__((ext_vector_type(2))) __bf16;
using f32x4v = __attribute__((ext_vector_type(4))) float;

__device__ __forceinline__ void gload_lds16(const __bf16* g, __bf16* l) {
  __builtin_amdgcn_global_load_lds(
      (const __attribute__((address_space(1))) void*)g,
      (__attribute__((address_space(3))) void*)l, 16, 0, 0);
}

// fp32 -> bf16 bits (RNE), as low 16 of u32
__device__ __forceinline__ unsigned int f32_to_bf16_bits(float s) {
  unsigned int x = __float_as_uint(s);
  return (x + 0x7FFFu + ((x >> 16) & 1u)) >> 16;
}

// ---- DPP 16-lane reductions (row teams == DPP rows) ----
__device__ __forceinline__ int red16i(int x) {
  x += __builtin_amdgcn_update_dpp(0, x, 0xB1, 0xF, 0xF, true);
  x += __builtin_amdgcn_update_dpp(0, x, 0x4E, 0xF, 0xF, true);
  x += __builtin_amdgcn_update_dpp(0, x, 0x141, 0xF, 0xF, true);
  x += __builtin_amdgcn_update_dpp(0, x, 0x140, 0xF, 0xF, true);
  return x;
}
__device__ __forceinline__ unsigned int red16umax(unsigned int x) {
  unsigned int t;
  t = (unsigned int)__builtin_amdgcn_update_dpp(0, (int)x, 0xB1, 0xF, 0xF, true);  x = t > x ? t : x;
  t = (unsigned int)__builtin_amdgcn_update_dpp(0, (int)x, 0x4E, 0xF, 0xF, true);  x = t > x ? t : x;
  t = (unsigned int)__builtin_amdgcn_update_dpp(0, (int)x, 0x141, 0xF, 0xF, true); x = t > x ? t : x;
  t = (unsigned int)__builtin_amdgcn_update_dpp(0, (int)x, 0x140, 0xF, 0xF, true); x = t > x ? t : x;
  return x;
}
__device__ __forceinline__ float red16f(float x) {
  x += __int_as_float(__builtin_amdgcn_update_dpp(0, __float_as_int(x), 0xB1, 0xF, 0xF, true));
  x += __int_as_float(__builtin_amdgcn_update_dpp(0, __float_as_int(x), 0x4E, 0xF, 0xF, true));
  x += __int_as_float(__builtin_amdgcn_update_dpp(0, __float_as_int(x), 0x141, 0xF, 0xF, true));
  x += __int_as_float(__builtin_amdgcn_update_dpp(0, __float_as_int(x), 0x140, 0xF, 0xF, true));
  return x;
}
__device__ __forceinline__ float red64f(float x) {
  x = red16f(x);
  x += __shfl_xor(x, 16, 64);
  x += __shfl_xor(x, 32, 64);
  return x;
}

// ---- st_16x32-swizzled [R][64] bf16 LDS helpers; XOR (row&7)<<3 elements ----
template<int ROWS>
__device__ __forceinline__ void stage_tile4(const __bf16* src, int Kd, __bf16* lds,
                                            int w, int lane) {
  #pragma unroll
  for (int c = 0; c < ROWS / 32; ++c) {
    int rblk = (c * 4 + w) * 8;
    int row = rblk + (lane >> 3);
    int col = (lane & 7) * 8;
    int scol = col ^ ((row & 7) << 3);
    gload_lds16(src + (size_t)row * Kd + scol, lds + rblk * 64);
  }
}
__device__ __forceinline__ void stage_half8(const __bf16* src, int Kd, __bf16* lds,
                                            int w, int lane) {
  #pragma unroll
  for (int c = 0; c < 2; ++c) {
    int rblk = (c * 8 + w) * 8;
    int row = rblk + (lane >> 3);
    int col = (lane & 7) * 8;
    int scol = col ^ ((row & 7) << 3);
    gload_lds16(src + (size_t)row * Kd + scol, lds + rblk * 64);
  }
}
__device__ __forceinline__ bf16x8 lds_frag64(const __bf16* lds, int row, int colbase) {
  int col = colbase ^ ((row & 7) << 3);
  return *reinterpret_cast<const bf16x8*>(lds + row * 64 + col);
}

// ---------------- embedding ----------------
__global__ void embed_kernel(const int* __restrict__ x, const float* __restrict__ tok,
                             const float* __restrict__ pos, float* __restrict__ h) {
  int row = blockIdx.x;
  int t = threadIdx.x;
  int s = row & (S_ - 1);
  int token = x[row];
  const float4* t4 = reinterpret_cast<const float4*>(tok + (size_t)token * D_);
  const float4* p4 = reinterpret_cast<const float4*>(pos + (size_t)s * D_);
  float4 a = t4[t];
  float4 b = p4[t];
  a.x += b.x; a.y += b.y; a.z += b.z; a.w += b.w;
  reinterpret_cast<float4*>(h + (size_t)row * D_)[t] = a;
}

// ---------------- layernorm ----------------
__global__ void ln_kernel(const float* __restrict__ xin, const float* __restrict__ g,
                          const float* __restrict__ bta, __bf16* __restrict__ y) {
  int row = blockIdx.x;
  int t = threadIdx.x;
  const float2* x2 = reinterpret_cast<const float2*>(xin + (size_t)row * D_);
  float2 v = x2[t];
  float s = v.x + v.y;
  float q = v.x * v.x + v.y * v.y;
  s = red64f(s);
  q = red64f(q);
  __shared__ float red[4];
  __shared__ float red2[4];
  int wid = t >> 6, lane = t & 63;
  if (lane == 0) { red[wid] = s; red2[wid] = q; }
  __syncthreads();
  float mu = (red[0] + red[1] + red[2] + red[3]) * (1.0f / D_);
  float ex2 = (red2[0] + red2[1] + red2[2] + red2[3]) * (1.0f / D_);
  float var = ex2 - mu * mu;
  float rstd = rsqrtf(var + 1e-5f);
  float2 gg = reinterpret_cast<const float2*>(g)[t];
  float2 bb = reinterpret_cast<const float2*>(bta)[t];
  bf16x2 o2;
  o2[0] = (__bf16)((v.x - mu) * rstd * gg.x + bb.x);
  o2[1] = (__bf16)((v.y - mu) * rstd * gg.y + bb.y);
  *reinterpret_cast<bf16x2*>(y + (size_t)row * D_ + t * 2) = o2;
}

// ------------- transpose fp32 [Kd][N] -> bf16 [N][Kd] -------------
__global__ void transpose_bf16_kernel(const float* __restrict__ in, __bf16* __restrict__ out,
                                      int Kd, int N, long in_bstride, long out_bstride) {
  __shared__ float tile[32][33];
  const float* ib = in + (size_t)blockIdx.z * in_bstride;
  __bf16* ob = out + (size_t)blockIdx.z * out_bstride;
  int n0 = blockIdx.x * 32, k0 = blockIdx.y * 32;
  int tx = threadIdx.x & 31, ty = threadIdx.x >> 5;
  #pragma unroll
  for (int i = 0; i < 4; ++i)
    tile[ty + i * 8][tx] = ib[(size_t)(k0 + ty + i * 8) * N + n0 + tx];
  __syncthreads();
  #pragma unroll
  for (int i = 0; i < 4; ++i)
    ob[(size_t)(n0 + ty + i * 8) * Kd + k0 + tx] = (__bf16)tile[tx][ty + i * 8];
}

// ---------------- bias concat for fused QKV ----------------
__global__ void concat_bias_kernel(const float* __restrict__ bq, const float* __restrict__ bk,
                                   const float* __restrict__ bv, float* __restrict__ bqkv) {
  int i = blockIdx.x * 256 + threadIdx.x;
  int l = i / 1536, c = i - l * 1536;
  float v = (c < 512) ? bq[l * 512 + c]
          : (c < 1024) ? bk[l * 512 + c - 512]
                       : bv[l * 512 + c - 1024];
  bqkv[i] = v;
}

// ---------------- bf16 MFMA GEMM, 128x128 tile, BK=64, swizzled LDS ----------------
#define BM 128
#define BN 128
#define BK 64

template<int OMODE, bool GELU_ACT, bool RES, bool SWZ>
__global__ __launch_bounds__(256)
void gemm_bf16_kernel(const __bf16* __restrict__ A, const __bf16* __restrict__ WT,
                      const float* __restrict__ bias, const float* __restrict__ res,
                      void* __restrict__ outp, void* __restrict__ outp2, void* __restrict__ outp3,
                      int M, int N, int Kd) {
  __shared__ __bf16 As[BM * BK];
  __shared__ __bf16 Ws[BN * BK];
  int tid = threadIdx.x;
  int lane = tid & 63, w = tid >> 6;
  int wr = w >> 1, wc = w & 1;
  int lr = lane & 15, lg = lane >> 4;
  int bx, by;
  if (SWZ) {
    int lid = blockIdx.x;
    int cpx = gridDim.x >> 3;
    int swz = (lid & 7) * cpx + (lid >> 3);
    int gx = M >> 7;
    bx = swz % gx;
    by = swz / gx;
  } else {
    bx = blockIdx.x; by = blockIdx.y;
  }
  int row0 = bx * BM, col0 = by * BN;

  const __bf16* Abase = A + (size_t)row0 * Kd;
  const __bf16* Wbase = WT + (size_t)col0 * Kd;

  f32x4v acc[4][4];
  #pragma unroll
  for (int i = 0; i < 4; ++i)
    #pragma unroll
    for (int j = 0; j < 4; ++j)
      #pragma unroll
      for (int e = 0; e < 4; ++e) acc[i][j][e] = 0.0f;

  for (int k0 = 0; k0 < Kd; k0 += BK) {
    stage_tile4<128>(Abase + k0, Kd, As, w, lane);
    stage_tile4<128>(Wbase + k0, Kd, Ws, w, lane);
    __syncthreads();
    bf16x8 af[4][2], bfr[4][2];
    #pragma unroll
    for (int mr = 0; mr < 4; ++mr)
      #pragma unroll
      for (int kk = 0; kk < 2; ++kk)
        af[mr][kk] = lds_frag64(As, wr * 64 + mr * 16 + lr, kk * 32 + lg * 8);
    #pragma unroll
    for (int nc = 0; nc < 4; ++nc)
      #pragma unroll
      for (int kk = 0; kk < 2; ++kk)
        bfr[nc][kk] = lds_frag64(Ws, wc * 64 + nc * 16 + lr, kk * 32 + lg * 8);
    __builtin_amdgcn_s_setprio(1);
    #pragma unroll
    for (int mr = 0; mr < 4; ++mr)
      #pragma unroll
      for (int nc = 0; nc < 4; ++nc) {
        acc[mr][nc] = __builtin_amdgcn_mfma_f32_16x16x32_bf16(af[mr][0], bfr[nc][0], acc[mr][nc], 0, 0, 0);
        acc[mr][nc] = __builtin_amdgcn_mfma_f32_16x16x32_bf16(af[mr][1], bfr[nc][1], acc[mr][nc], 0, 0, 0);
      }
    __builtin_amdgcn_s_setprio(0);
    __syncthreads();
  }

  #pragma unroll
  for (int mr = 0; mr < 4; ++mr) {
    #pragma unroll
    for (int nc = 0; nc < 4; ++nc) {
      int c = col0 + wc * 64 + nc * 16 + lr;
      int rb = row0 + wr * 64 + mr * 16 + lg * 4;
      float vv[4];
      #pragma unroll
      for (int j = 0; j < 4; ++j) {
        float t = acc[mr][nc][j] + bias[c];
        if (RES) t += res[(size_t)(rb + j) * N + c];
        if (GELU_ACT) t = 0.5f * t * (1.0f + erff(t * 0.70710678118654752f));
        vv[j] = t;
      }
      if (OMODE == 0) {
        float* out = (float*)outp;
        #pragma unroll
        for (int j = 0; j < 4; ++j) out[(size_t)(rb + j) * N + c] = vv[j];
      } else if (OMODE == 1) {
        __bf16* out = (__bf16*)outp;
        #pragma unroll
        for (int j = 0; j < 4; ++j) out[(size_t)(rb + j) * N + c] = (__bf16)vv[j];
      } else if (OMODE == 3) {
        float* out = (float*)outp;
        __bf16* out2 = (__bf16*)outp2;
        #pragma unroll
        for (int j = 0; j < 4; ++j) {
          out[(size_t)(rb + j) * N + c] = vv[j];
          out2[(size_t)(rb + j) * N + c] = (__bf16)vv[j];
        }
      } else {  // OMODE 4: fused QKV epilogue
        if (col0 < 512) {
          __bf16* out = (__bf16*)outp;
          #pragma unroll
          for (int j = 0; j < 4; ++j) out[(size_t)(rb + j) * D_ + c] = (__bf16)vv[j];
        } else if (col0 < 1024) {
          __bf16* out = (__bf16*)outp2;
          #pragma unroll
          for (int j = 0; j < 4; ++j) out[(size_t)(rb + j) * D_ + (c - 512)] = (__bf16)vv[j];
        } else {
          __bf16* out = (__bf16*)outp3;   // vt [B][D][S]
          int b = rb >> 10, s0 = rb & (S_ - 1);
          bf16x4 pk;
          #pragma unroll
          for (int j = 0; j < 4; ++j) pk[j] = (__bf16)vv[j];
          *reinterpret_cast<bf16x4*>(&out[((size_t)b * D_ + (c - 1024)) * S_ + s0]) = pk;
        }
      }
    }
  }
}

// ---------------- 64x128-tile GEMM for N=512 shapes (Wo, W2), BK=64 ----------------
template<int OMODE, bool RES>
__global__ __launch_bounds__(256)
void gemm64_kernel(const __bf16* __restrict__ A, const __bf16* __restrict__ WT,
                   const float* __restrict__ bias, const float* __restrict__ res,
                   void* __restrict__ outp, void* __restrict__ outp2,
                   int M, int N, int Kd) {
  __shared__ __bf16 As[64 * BK];
  __shared__ __bf16 Ws[BN * BK];
  int tid = threadIdx.x;
  int lane = tid & 63, w = tid >> 6;
  int wr = w >> 1, wc = w & 1;
  int lr = lane & 15, lg = lane >> 4;
  int row0 = blockIdx.x * 64, col0 = blockIdx.y * BN;

  const __bf16* Abase = A + (size_t)row0 * Kd;
  const __bf16* Wbase = WT + (size_t)col0 * Kd;

  f32x4v acc[2][4];
  #pragma unroll
  for (int i = 0; i < 2; ++i)
    #pragma unroll
    for (int j = 0; j < 4; ++j)
      #pragma unroll
      for (int e = 0; e < 4; ++e) acc[i][j][e] = 0.0f;

  for (int k0 = 0; k0 < Kd; k0 += BK) {
    stage_tile4<64>(Abase + k0, Kd, As, w, lane);
    stage_tile4<128>(Wbase + k0, Kd, Ws, w, lane);
    __syncthreads();
    bf16x8 af[2][2], bfr[4][2];
    #pragma unroll
    for (int mr = 0; mr < 2; ++mr)
      #pragma unroll
      for (int kk = 0; kk < 2; ++kk)
        af[mr][kk] = lds_frag64(As, wr * 32 + mr * 16 + lr, kk * 32 + lg * 8);
    #pragma unroll
    for (int nc = 0; nc < 4; ++nc)
      #pragma unroll
      for (int kk = 0; kk < 2; ++kk)
        bfr[nc][kk] = lds_frag64(Ws, wc * 64 + nc * 16 + lr, kk * 32 + lg * 8);
    __builtin_amdgcn_s_setprio(1);
    #pragma unroll
    for (int mr = 0; mr < 2; ++mr)
      #pragma unroll
      for (int nc = 0; nc < 4; ++nc) {
        acc[mr][nc] = __builtin_amdgcn_mfma_f32_16x16x32_bf16(af[mr][0], bfr[nc][0], acc[mr][nc], 0, 0, 0);
        acc[mr][nc] = __builtin_amdgcn_mfma_f32_16x16x32_bf16(af[mr][1], bfr[nc][1], acc[mr][nc], 0, 0, 0);
      }
    __builtin_amdgcn_s_setprio(0);
    __syncthreads();
  }

  #pragma unroll
  for (int mr = 0; mr < 2; ++mr) {
    #pragma unroll
    for (int nc = 0; nc < 4; ++nc) {
      int c = col0 + wc * 64 + nc * 16 + lr;
      int rb = row0 + wr * 32 + mr * 16 + lg * 4;
      float vv[4];
      #pragma unroll
      for (int j = 0; j < 4; ++j) {
        float t = acc[mr][nc][j] + bias[c];
        if (RES) t += res[(size_t)(rb + j) * N + c];
        vv[j] = t;
      }
      if (OMODE == 0) {
        float* out = (float*)outp;
        #pragma unroll
        for (int j = 0; j < 4; ++j) out[(size_t)(rb + j) * N + c] = vv[j];
      } else {
        float* out = (float*)outp;
        __bf16* out2 = (__bf16*)outp2;
        #pragma unroll
        for (int j = 0; j < 4; ++j) {
          out[(size_t)(rb + j) * N + c] = vv[j];
          out2[(size_t)(rb + j) * N + c] = (__bf16)vv[j];
        }
      }
    }
  }
}

// ------- mid GEMM: 256x128 tile, 8 waves (4Mx2N), BK=64, double-buffered counted-vmcnt -------
// For W1/Wm (N=2048): grid 16x16 = 256 blocks = 1/CU. out bf16 + bias + optional GELU.
template<bool GELU_ACT>
__global__ __launch_bounds__(512)
void gemm_mid_kernel(const __bf16* __restrict__ A, const __bf16* __restrict__ WT,
                     const float* __restrict__ bias, __bf16* __restrict__ out,
                     int M, int N, int Kd) {
  __shared__ __bf16 ldsA[2][256 * 64];   // 64 KB
  __shared__ __bf16 ldsB[2][128 * 64];   // 32 KB
  const int tid = threadIdx.x;
  const int lane = tid & 63, w = tid >> 6;    // 8 waves
  const int wr = w >> 1, wc = w & 1;          // 4 x 2, each wave 64x64
  const int lr = lane & 15, lg = lane >> 4;
  int row0 = blockIdx.x * 256, col0 = blockIdx.y * 128;

  const __bf16* Asrc = A + (size_t)row0 * Kd;
  const __bf16* Bsrc = WT + (size_t)col0 * Kd;

  f32x4v acc[4][4];
  #pragma unroll
  for (int i = 0; i < 4; ++i)
    #pragma unroll
    for (int j = 0; j < 4; ++j)
      #pragma unroll
      for (int e = 0; e < 4; ++e) acc[i][j][e] = 0.0f;

  const int NT = Kd / 64;
  // prologue: stage tile 0 (6 loads/thread)
  stage_half8(Asrc,                    Kd, &ldsA[0][0],    w, lane);
  stage_half8(Asrc + (size_t)128 * Kd, Kd, &ldsA[0][8192], w, lane);
  stage_half8(Bsrc,                    Kd, &ldsB[0][0],    w, lane);

  for (int t = 0; t < NT; ++t) {
    int cur = t & 1, nxt = cur ^ 1;
    int k1 = (t + 1) * 64;
    // issue-early: all of tile t+1's stages go in flight before we wait on tile t
    if (t < NT - 1) {
      stage_half8(Asrc + k1,                    Kd, &ldsA[nxt][0],    w, lane);
      stage_half8(Asrc + (size_t)128 * Kd + k1, Kd, &ldsA[nxt][8192], w, lane);
      stage_half8(Bsrc + k1,                    Kd, &ldsB[nxt][0],    w, lane);
      asm volatile("s_waitcnt vmcnt(6)" ::: "memory");   // tile t's 6 loads complete
    } else {
      asm volatile("s_waitcnt vmcnt(0)" ::: "memory");
    }
    __builtin_amdgcn_s_barrier();
    const __bf16* Ab = &ldsA[cur][0];
    const __bf16* Bb = &ldsB[cur][0];
    bf16x8 bfr[4][2];
    #pragma unroll
    for (int nn = 0; nn < 4; ++nn)
      #pragma unroll
      for (int kk = 0; kk < 2; ++kk)
        bfr[nn][kk] = lds_frag64(Bb, wc * 64 + nn * 16 + lr, kk * 32 + lg * 8);
    #pragma unroll
    for (int p = 0; p < 4; ++p) {
      bf16x8 af0 = lds_frag64(Ab, wr * 64 + p * 16 + lr, lg * 8);
      bf16x8 af1 = lds_frag64(Ab, wr * 64 + p * 16 + lr, 32 + lg * 8);
      asm volatile("s_waitcnt lgkmcnt(0)" ::: "memory");
      __builtin_amdgcn_sched_barrier(0);
      __builtin_amdgcn_s_setprio(1);
      #pragma unroll
      for (int nn = 0; nn < 4; ++nn) {
        acc[p][nn] = __builtin_amdgcn_mfma_f32_16x16x32_bf16(af0, bfr[nn][0], acc[p][nn], 0, 0, 0);
        acc[p][nn] = __builtin_amdgcn_mfma_f32_16x16x32_bf16(af1, bfr[nn][1], acc[p][nn], 0, 0, 0);
      }
      __builtin_amdgcn_s_setprio(0);
    }
    // all ds_reads of cur are complete (lgkmcnt(0) in each phase) -> safe to barrier and
    // let next iteration overwrite cur's partner buffer
    __builtin_amdgcn_s_barrier();
  }

  #pragma unroll
  for (int p = 0; p < 4; ++p) {
    #pragma unroll
    for (int nn = 0; nn < 4; ++nn) {
      int c = col0 + wc * 64 + nn * 16 + lr;
      int rb = row0 + wr * 64 + p * 16 + lg * 4;
      float b = bias[c];
      #pragma unroll
      for (int j = 0; j < 4; ++j) {
        float t = acc[p][nn][j] + b;
        if (GELU_ACT) t = 0.5f * t * (1.0f + erff(t * 0.70710678118654752f));
        out[(size_t)(rb + j) * N + c] = (__bf16)t;
      }
    }
  }
}

// ------- head GEMM: 256x256 tile, 8 waves, BK=64, double-buffered counted-vmcnt pipeline -------
__global__ __launch_bounds__(512)
void gemm_head_kernel(const __bf16* __restrict__ A, const __bf16* __restrict__ WT,
                      const float* __restrict__ bias, float* __restrict__ out,
                      int M, int N, int Kd) {
  __shared__ __bf16 lds[2][2][256 * 64];   // 128 KB
  const int tid = threadIdx.x;
  const int lane = tid & 63, w = tid >> 6;
  const int wr = w >> 2, wc = w & 3;
  const int lr = lane & 15, lg = lane >> 4;

  int lid = blockIdx.x;
  int cpx = gridDim.x >> 3;
  int swz = (lid & 7) * cpx + (lid >> 3);
  int gx = M >> 8;
  int bx = swz % gx, by = swz / gx;
  int row0 = bx * 256, col0 = by * 256;

  const __bf16* Asrc = A + (size_t)row0 * Kd;
  const __bf16* Bsrc = WT + (size_t)col0 * Kd;

  f32x4v acc[8][4];
  #pragma unroll
  for (int i = 0; i < 8; ++i)
    #pragma unroll
    for (int j = 0; j < 4; ++j)
      #pragma unroll
      for (int e = 0; e < 4; ++e) acc[i][j][e] = 0.0f;

  const int NT = Kd / 64;
  stage_half8(Asrc,                      Kd, &lds[0][0][0],    w, lane);
  stage_half8(Asrc + (size_t)128 * Kd,   Kd, &lds[0][0][8192], w, lane);
  stage_half8(Bsrc,                      Kd, &lds[0][1][0],    w, lane);
  stage_half8(Bsrc + (size_t)128 * Kd,   Kd, &lds[0][1][8192], w, lane);

  for (int t = 0; t < NT; ++t) {
    int cur = t & 1, nxt = cur ^ 1;
    int k1 = (t + 1) * 64;
    const __bf16* Ab = &lds[cur][0][0];
    const __bf16* Bb = &lds[cur][1][0];
    bf16x8 bfr[4][2];
    #pragma unroll
    for (int p = 0; p < 4; ++p) {
      if (t < NT - 1) {
        const __bf16* s;
        __bf16* d;
        if (p == 0)      { s = Asrc + k1;                    d = &lds[nxt][0][0]; }
        else if (p == 1) { s = Asrc + (size_t)128 * Kd + k1; d = &lds[nxt][0][8192]; }
        else if (p == 2) { s = Bsrc + k1;                    d = &lds[nxt][1][0]; }
        else             { s = Bsrc + (size_t)128 * Kd + k1; d = &lds[nxt][1][8192]; }
        stage_half8(s, Kd, d, w, lane);
      }
      if (p == 0) {
        if (t < NT - 1) asm volatile("s_waitcnt vmcnt(2)" ::: "memory");
        else            asm volatile("s_waitcnt vmcnt(0)" ::: "memory");
        __builtin_amdgcn_s_barrier();
        #pragma unroll
        for (int nn = 0; nn < 4; ++nn)
          #pragma unroll
          for (int kk = 0; kk < 2; ++kk)
            bfr[nn][kk] = lds_frag64(Bb, wc * 64 + nn * 16 + lr, kk * 32 + lg * 8);
      }
      bf16x8 af[2][2];
      #pragma unroll
      for (int mm = 0; mm < 2; ++mm)
        #pragma unroll
        for (int kk = 0; kk < 2; ++kk)
          af[mm][kk] = lds_frag64(Ab, wr * 128 + p * 32 + mm * 16 + lr, kk * 32 + lg * 8);
      asm volatile("s_waitcnt lgkmcnt(0)" ::: "memory");
      __builtin_amdgcn_sched_barrier(0);
      __builtin_amdgcn_s_setprio(1);
      #pragma unroll
      for (int mm = 0; mm < 2; ++mm)
        #pragma unroll
        for (int nn = 0; nn < 4; ++nn) {
          acc[p * 2 + mm][nn] = __builtin_amdgcn_mfma_f32_16x16x32_bf16(af[mm][0], bfr[nn][0], acc[p * 2 + mm][nn], 0, 0, 0);
          acc[p * 2 + mm][nn] = __builtin_amdgcn_mfma_f32_16x16x32_bf16(af[mm][1], bfr[nn][1], acc[p * 2 + mm][nn], 0, 0, 0);
        }
      __builtin_amdgcn_s_setprio(0);
    }
    __builtin_amdgcn_s_barrier();
  }

  #pragma unroll
  for (int mg = 0; mg < 8; ++mg) {
    #pragma unroll
    for (int nn = 0; nn < 4; ++nn) {
      int c = col0 + wc * 64 + nn * 16 + lr;
      int rb = row0 + wr * 128 + mg * 16 + lg * 4;
      float b = bias[c];
      #pragma unroll
      for (int j = 0; j < 4; ++j)
        out[(size_t)(rb + j) * N + c] = acc[mg][nn][j] + b;
    }
  }
}

// ---------------- fused attention ----------------
__global__ __launch_bounds__(256)
void attn_kernel(const __bf16* __restrict__ qm, const __bf16* __restrict__ km,
                 const __bf16* __restrict__ vt, __bf16* __restrict__ o) {
  __shared__ unsigned short sc16[16][SRS];
  __shared__ float rs[16];
  const int q0 = blockIdx.x * 16;
  const int hh = blockIdx.y;
  const int bb = blockIdx.z;
  const int tid = threadIdx.x;
  const int lane = tid & 63, w = tid >> 6;
  const int lr = lane & 15, lg = lane >> 4;

  const __bf16* qrow = qm + ((size_t)(bb * S_ + q0 + lr)) * D_ + hh * DK_;
  bf16x8 qf0 = *reinterpret_cast<const bf16x8*>(qrow + lg * 8);
  bf16x8 qf1 = *reinterpret_cast<const bf16x8*>(qrow + 32 + lg * 8);

  const __bf16* kbase = km + ((size_t)bb * S_) * D_ + hh * DK_;
  #pragma unroll 4
  for (int kt = 0; kt < 16; ++kt) {
    int key0 = kt * 64 + w * 16;
    const __bf16* krow = kbase + (size_t)(key0 + lr) * D_;
    bf16x8 kf0 = *reinterpret_cast<const bf16x8*>(krow + lg * 8);
    bf16x8 kf1 = *reinterpret_cast<const bf16x8*>(krow + 32 + lg * 8);
    f32x4v d = {0.0f, 0.0f, 0.0f, 0.0f};
    __builtin_amdgcn_s_setprio(1);
    d = __builtin_amdgcn_mfma_f32_16x16x32_bf16(qf0, kf0, d, 0, 0, 0);
    d = __builtin_amdgcn_mfma_f32_16x16x32_bf16(qf1, kf1, d, 0, 0, 0);
    __builtin_amdgcn_s_setprio(0);
    #pragma unroll
    for (int j = 0; j < 4; ++j) {
      unsigned int u = f32_to_bf16_bits(d[j] * 0.125f);
      u = (u & 0x8000u) ? (~u & 0xFFFFu) : (u | 0x8000u);
      sc16[lg * 4 + j][key0 + lr] = (unsigned short)u;
    }
  }
  __syncthreads();

  {
    int r = tid >> 4, tc = tid & 15;
    const unsigned int* srow = reinterpret_cast<const unsigned int*>(&sc16[r][0]);
    unsigned int wv[32];
    #pragma unroll
    for (int g = 0; g < 8; ++g) {
      uint4 t4 = *reinterpret_cast<const uint4*>(&srow[g * 64 + tc * 4]);
      wv[g * 4 + 0] = t4.x; wv[g * 4 + 1] = t4.y;
      wv[g * 4 + 2] = t4.z; wv[g * 4 + 3] = t4.w;
    }
    unsigned int umax = 0;
    #pragma unroll
    for (int i = 0; i < 32; ++i) {
      unsigned int a = wv[i] & 0xFFFFu, b = wv[i] >> 16;
      unsigned int mx = a > b ? a : b;
      umax = mx > umax ? mx : umax;
    }
    umax = red16umax(umax);
    unsigned int lo = 0;
    for (int bit = 15; bit >= 0; --bit) {
      unsigned int cs = (lo | (1u << bit)) << 16;
      int cnt = 0;
      #pragma unroll
      for (int i = 0; i < 32; ++i) {
        cnt += ((wv[i] << 16) >= cs) ? 1 : 0;
        cnt += (wv[i] >= cs) ? 1 : 0;
      }
      cnt = red16i(cnt);
      if (cnt >= KTOP) lo |= (1u << bit);
    }
    unsigned int um = (umax & 0x8000u) ? (umax ^ 0x8000u) : (~umax & 0xFFFFu);
    float mval = __uint_as_float(um << 16);

    __bf16* P = reinterpret_cast<__bf16*>(&sc16[r][0]);
    float lsum = 0.0f;
    #pragma unroll
    for (int g = 0; g < 8; ++g) {
      bf16x8 pk;
      #pragma unroll
      for (int e = 0; e < 8; ++e) {
        unsigned int wrd = wv[g * 4 + (e >> 1)];
        unsigned int u = (e & 1) ? (wrd >> 16) : (wrd & 0xFFFFu);
        float p = 0.0f;
        if (u >= lo) {
          unsigned int ub = (u & 0x8000u) ? (u ^ 0x8000u) : (~u & 0xFFFFu);
          p = __expf(__uint_as_float(ub << 16) - mval);
        }
        pk[e] = (__bf16)p;
        lsum += (float)pk[e];
      }
      *reinterpret_cast<bf16x8*>(&P[tc * 8 + g * 128]) = pk;
    }
    lsum = red16f(lsum);
    if (tc == 0) rs[r] = lsum;
  }
  __syncthreads();

  {
    const __bf16* P0 = reinterpret_cast<const __bf16*>(&sc16[0][0]);
    const __bf16* vbase = vt + ((size_t)bb * D_ + hh * DK_ + w * 16 + lr) * S_;
    const __bf16* prow = P0 + (size_t)lr * SRS;
    f32x4v oacc = {0.0f, 0.0f, 0.0f, 0.0f};
    #pragma unroll 4
    for (int kt = 0; kt < 32; ++kt) {
      bf16x8 a = *reinterpret_cast<const bf16x8*>(prow + kt * 32 + lg * 8);
      bf16x8 b = *reinterpret_cast<const bf16x8*>(vbase + kt * 32 + lg * 8);
      __builtin_amdgcn_s_setprio(1);
      oacc = __builtin_amdgcn_mfma_f32_16x16x32_bf16(a, b, oacc, 0, 0, 0);
      __builtin_amdgcn_s_setprio(0);
    }
    #pragma unroll
    for (int j = 0; j < 4; ++j) {
      int qr = lg * 4 + j;
      float ov = oacc[j] / rs[qr];
      o[((size_t)(bb * S_ + q0 + qr)) * D_ + hh * DK_ + w * 16 + lr] = (__bf16)ov;
    }
  }
}

extern "C" void kernel_launch(void* const* d_in, const int* in_sizes, int n_in,
                              void* d_out, int out_size, void* d_ws, size_t ws_size,
                              hipStream_t stream) {
  (void)in_sizes; (void)n_in; (void)out_size; (void)ws_size;
  const int*   x    = (const int*)d_in[0];
  const float* tok  = (const float*)d_in[1];
  const float* pos  = (const float*)d_in[2];
  const float* Wq   = (const float*)d_in[3];
  const float* bq   = (const float*)d_in[4];
  const float* Wk   = (const float*)d_in[5];
  const float* bk   = (const float*)d_in[6];
  const float* Wv   = (const float*)d_in[7];
  const float* bv   = (const float*)d_in[8];
  const float* Wo   = (const float*)d_in[9];
  const float* bo   = (const float*)d_in[10];
  const float* g1   = (const float*)d_in[11];
  const float* be1  = (const float*)d_in[12];
  const float* g2   = (const float*)d_in[13];
  const float* be2  = (const float*)d_in[14];
  const float* W1   = (const float*)d_in[15];
  const float* b1   = (const float*)d_in[16];
  const float* Wm   = (const float*)d_in[17];
  const float* bm   = (const float*)d_in[18];
  const float* W2   = (const float*)d_in[19];
  const float* b2   = (const float*)d_in[20];
  const float* Wout = (const float*)d_in[21];
  const float* bout = (const float*)d_in[22];
  float* logits = (float*)d_out;

  const int M = B_ * S_;  // 4096
  float* ws = (float*)d_ws;
  float* h    = ws;
  float* bqkv = h + (size_t)M * D_;
  __bf16* y16  = (__bf16*)(bqkv + (size_t)L_ * 1536);
  __bf16* f1b  = y16  + (size_t)M * D_;
  __bf16* f2b  = f1b  + (size_t)M * DFF_;
  __bf16* qb16 = f2b  + (size_t)M * DFF_;
  __bf16* kb16 = qb16 + (size_t)M * D_;
  __bf16* vt16 = kb16 + (size_t)M * D_;
  __bf16* ob16 = vt16 + (size_t)M * D_;
  __bf16* h16  = ob16 + (size_t)M * D_;
  __bf16* WqkvT = h16 + (size_t)M * D_;
  __bf16* WoT  = WqkvT + (size_t)L_ * 1536 * D_;
  __bf16* W1T  = WoT  + (size_t)L_ * D_ * D_;
  __bf16* WmT  = W1T  + (size_t)L_ * D_ * DFF_;
  __bf16* W2T  = WmT  + (size_t)L_ * DFF_ * DFF_;
  __bf16* WoutT = W2T + (size_t)L_ * D_ * DFF_;

  const long DD = (long)D_ * D_;
  transpose_bf16_kernel<<<dim3(D_/32,  D_/32,   L_), 256, 0, stream>>>(Wq, WqkvT,            D_, D_, DD, 1536L*D_);
  transpose_bf16_kernel<<<dim3(D_/32,  D_/32,   L_), 256, 0, stream>>>(Wk, WqkvT + 512*512,  D_, D_, DD, 1536L*D_);
  transpose_bf16_kernel<<<dim3(D_/32,  D_/32,   L_), 256, 0, stream>>>(Wv, WqkvT + 1024*512, D_, D_, DD, 1536L*D_);
  transpose_bf16_kernel<<<dim3(D_/32,  D_/32,   L_), 256, 0, stream>>>(Wo, WoT, D_, D_, DD, DD);
  transpose_bf16_kernel<<<dim3(DFF_/32, D_/32,  L_), 256, 0, stream>>>(W1, W1T, D_, DFF_, (long)D_*DFF_, (long)D_*DFF_);
  transpose_bf16_kernel<<<dim3(DFF_/32, DFF_/32,L_), 256, 0, stream>>>(Wm, WmT, DFF_, DFF_, (long)DFF_*DFF_, (long)DFF_*DFF_);
  transpose_bf16_kernel<<<dim3(D_/32,  DFF_/32, L_), 256, 0, stream>>>(W2, W2T, DFF_, D_, (long)D_*DFF_, (long)D_*DFF_);
  transpose_bf16_kernel<<<dim3(V_/32,  D_/32,   1 ), 256, 0, stream>>>(Wout, WoutT, D_, V_, (long)D_*V_, (long)D_*V_);
  concat_bias_kernel<<<(L_*1536)/256, 256, 0, stream>>>(bq, bk, bv, bqkv);

  embed_kernel<<<M, 128, 0, stream>>>(x, tok, pos, h);

  for (int l = 0; l < L_; ++l) {
    ln_kernel<<<M, 256, 0, stream>>>(h, g1 + l * D_, be1 + l * D_, y16);
    gemm_bf16_kernel<4,false,false,true><<<dim3((M/BM) * (1536/BN)), 256, 0, stream>>>(
        y16, WqkvT + (size_t)l * 1536 * D_, bqkv + l * 1536, nullptr,
        qb16, kb16, vt16, M, 1536, D_);
    attn_kernel<<<dim3(S_/16, H_, B_), 256, 0, stream>>>(qb16, kb16, vt16, ob16);
    gemm64_kernel<0,true><<<dim3(M/64, D_/BN), 256, 0, stream>>>(
        ob16, WoT + (size_t)l * DD, bo + l * D_, h, h, nullptr, M, D_, D_);
    ln_kernel<<<M, 256, 0, stream>>>(h, g2 + l * D_, be2 + l * D_, y16);
    gemm_mid_kernel<true><<<dim3(M/256, DFF_/128), 512, 0, stream>>>(
        y16, W1T + (size_t)l * D_ * DFF_, b1 + l * DFF_, f1b, M, DFF_, D_);
    gemm_mid_kernel<true><<<dim3(M/256, DFF_/128), 512, 0, stream>>>(
        f1b, WmT + (size_t)l * DFF_ * DFF_, bm + l * DFF_, f2b, M, DFF_, DFF_);
    gemm64_kernel<3,true><<<dim3(M/64, D_/BN), 256, 0, stream>>>(
        f2b, W2T + (size_t)l * D_ * DFF_, b2 + l * D_, h, h, h16, M, D_, DFF_);
  }
  gemm_head_kernel<<<dim3((M/256) * (V_/256)), 512, 0, stream>>>(
      h16, WoutT, bout, logits, M, V_, D_);
}

// Round 10
// 1250.623 us; speedup vs baseline: 1.0298x; 1.0298x over previous
//
#include <hip/hip_runtime.h>
#include <hip/hip_bf16.h>
#include <math.h>

#define B_ 4
#define S_ 1024
#define D_ 512
#define H_ 8
#define L_ 4
#define DFF_ 2048
#define V_ 32000
#define DK_ 64
#define KTOP 307
#define SRS 1048    // score row stride in u16 elems

using bf16x8 = __attribute__((ext_vector_type(8))) __bf16;
using bf16x4 = __attribute__((ext_vector_type(4))) __bf16;
using bf16x2 = __attribute__((ext_vector_type(2))) __bf16;
using f32x4v = __attribute__((ext_vector_type(4))) float;

__device__ __forceinline__ void gload_lds16(const __bf16* g, __bf16* l) {
  __builtin_amdgcn_global_load_lds(
      (const __attribute__((address_space(1))) void*)g,
      (__attribute__((address_space(3))) void*)l, 16, 0, 0);
}

// fp32 -> bf16 bits (RNE), as low 16 of u32
__device__ __forceinline__ unsigned int f32_to_bf16_bits(float s) {
  unsigned int x = __float_as_uint(s);
  return (x + 0x7FFFu + ((x >> 16) & 1u)) >> 16;
}

// ---- DPP 16-lane reductions (row teams == DPP rows) ----
__device__ __forceinline__ int red16i(int x) {
  x += __builtin_amdgcn_update_dpp(0, x, 0xB1, 0xF, 0xF, true);
  x += __builtin_amdgcn_update_dpp(0, x, 0x4E, 0xF, 0xF, true);
  x += __builtin_amdgcn_update_dpp(0, x, 0x141, 0xF, 0xF, true);
  x += __builtin_amdgcn_update_dpp(0, x, 0x140, 0xF, 0xF, true);
  return x;
}
__device__ __forceinline__ unsigned int red16umax(unsigned int x) {
  unsigned int t;
  t = (unsigned int)__builtin_amdgcn_update_dpp(0, (int)x, 0xB1, 0xF, 0xF, true);  x = t > x ? t : x;
  t = (unsigned int)__builtin_amdgcn_update_dpp(0, (int)x, 0x4E, 0xF, 0xF, true);  x = t > x ? t : x;
  t = (unsigned int)__builtin_amdgcn_update_dpp(0, (int)x, 0x141, 0xF, 0xF, true); x = t > x ? t : x;
  t = (unsigned int)__builtin_amdgcn_update_dpp(0, (int)x, 0x140, 0xF, 0xF, true); x = t > x ? t : x;
  return x;
}
__device__ __forceinline__ float red16f(float x) {
  x += __int_as_float(__builtin_amdgcn_update_dpp(0, __float_as_int(x), 0xB1, 0xF, 0xF, true));
  x += __int_as_float(__builtin_amdgcn_update_dpp(0, __float_as_int(x), 0x4E, 0xF, 0xF, true));
  x += __int_as_float(__builtin_amdgcn_update_dpp(0, __float_as_int(x), 0x141, 0xF, 0xF, true));
  x += __int_as_float(__builtin_amdgcn_update_dpp(0, __float_as_int(x), 0x140, 0xF, 0xF, true));
  return x;
}
__device__ __forceinline__ float red64f(float x) {
  x = red16f(x);
  x += __shfl_xor(x, 16, 64);
  x += __shfl_xor(x, 32, 64);
  return x;
}

// ---- st_16x32-swizzled [R][64] bf16 LDS helpers; XOR (row&7)<<3 elements ----
template<int ROWS>
__device__ __forceinline__ void stage_tile4(const __bf16* src, int Kd, __bf16* lds,
                                            int w, int lane) {
  #pragma unroll
  for (int c = 0; c < ROWS / 32; ++c) {
    int rblk = (c * 4 + w) * 8;
    int row = rblk + (lane >> 3);
    int col = (lane & 7) * 8;
    int scol = col ^ ((row & 7) << 3);
    gload_lds16(src + (size_t)row * Kd + scol, lds + rblk * 64);
  }
}
__device__ __forceinline__ void stage_half8(const __bf16* src, int Kd, __bf16* lds,
                                            int w, int lane) {
  #pragma unroll
  for (int c = 0; c < 2; ++c) {
    int rblk = (c * 8 + w) * 8;
    int row = rblk + (lane >> 3);
    int col = (lane & 7) * 8;
    int scol = col ^ ((row & 7) << 3);
    gload_lds16(src + (size_t)row * Kd + scol, lds + rblk * 64);
  }
}
__device__ __forceinline__ bf16x8 lds_frag64(const __bf16* lds, int row, int colbase) {
  int col = colbase ^ ((row & 7) << 3);
  return *reinterpret_cast<const bf16x8*>(lds + row * 64 + col);
}

// ---------------- embedding ----------------
__global__ void embed_kernel(const int* __restrict__ x, const float* __restrict__ tok,
                             const float* __restrict__ pos, float* __restrict__ h) {
  int row = blockIdx.x;
  int t = threadIdx.x;
  int s = row & (S_ - 1);
  int token = x[row];
  const float4* t4 = reinterpret_cast<const float4*>(tok + (size_t)token * D_);
  const float4* p4 = reinterpret_cast<const float4*>(pos + (size_t)s * D_);
  float4 a = t4[t];
  float4 b = p4[t];
  a.x += b.x; a.y += b.y; a.z += b.z; a.w += b.w;
  reinterpret_cast<float4*>(h + (size_t)row * D_)[t] = a;
}

// ---------------- layernorm ----------------
__global__ void ln_kernel(const float* __restrict__ xin, const float* __restrict__ g,
                          const float* __restrict__ bta, __bf16* __restrict__ y) {
  int row = blockIdx.x;
  int t = threadIdx.x;
  const float2* x2 = reinterpret_cast<const float2*>(xin + (size_t)row * D_);
  float2 v = x2[t];
  float s = v.x + v.y;
  float q = v.x * v.x + v.y * v.y;
  s = red64f(s);
  q = red64f(q);
  __shared__ float red[4];
  __shared__ float red2[4];
  int wid = t >> 6, lane = t & 63;
  if (lane == 0) { red[wid] = s; red2[wid] = q; }
  __syncthreads();
  float mu = (red[0] + red[1] + red[2] + red[3]) * (1.0f / D_);
  float ex2 = (red2[0] + red2[1] + red2[2] + red2[3]) * (1.0f / D_);
  float var = ex2 - mu * mu;
  float rstd = rsqrtf(var + 1e-5f);
  float2 gg = reinterpret_cast<const float2*>(g)[t];
  float2 bb = reinterpret_cast<const float2*>(bta)[t];
  bf16x2 o2;
  o2[0] = (__bf16)((v.x - mu) * rstd * gg.x + bb.x);
  o2[1] = (__bf16)((v.y - mu) * rstd * gg.y + bb.y);
  *reinterpret_cast<bf16x2*>(y + (size_t)row * D_ + t * 2) = o2;
}

// ------------- transpose fp32 [Kd][N] -> bf16 [N][Kd] -------------
__global__ void transpose_bf16_kernel(const float* __restrict__ in, __bf16* __restrict__ out,
                                      int Kd, int N, long in_bstride, long out_bstride) {
  __shared__ float tile[32][33];
  const float* ib = in + (size_t)blockIdx.z * in_bstride;
  __bf16* ob = out + (size_t)blockIdx.z * out_bstride;
  int n0 = blockIdx.x * 32, k0 = blockIdx.y * 32;
  int tx = threadIdx.x & 31, ty = threadIdx.x >> 5;
  #pragma unroll
  for (int i = 0; i < 4; ++i)
    tile[ty + i * 8][tx] = ib[(size_t)(k0 + ty + i * 8) * N + n0 + tx];
  __syncthreads();
  #pragma unroll
  for (int i = 0; i < 4; ++i)
    ob[(size_t)(n0 + ty + i * 8) * Kd + k0 + tx] = (__bf16)tile[tx][ty + i * 8];
}

// ---------------- bias concat for fused QKV ----------------
__global__ void concat_bias_kernel(const float* __restrict__ bq, const float* __restrict__ bk,
                                   const float* __restrict__ bv, float* __restrict__ bqkv) {
  int i = blockIdx.x * 256 + threadIdx.x;
  int l = i / 1536, c = i - l * 1536;
  float v = (c < 512) ? bq[l * 512 + c]
          : (c < 1024) ? bk[l * 512 + c - 512]
                       : bv[l * 512 + c - 1024];
  bqkv[i] = v;
}

// ---------------- bf16 MFMA GEMM, 128x128 tile, BK=64, swizzled LDS (W1/Wm) ----------------
#define BM 128
#define BN 128
#define BK 64

template<int OMODE, bool GELU_ACT, bool RES, bool SWZ>
__global__ __launch_bounds__(256)
void gemm_bf16_kernel(const __bf16* __restrict__ A, const __bf16* __restrict__ WT,
                      const float* __restrict__ bias, const float* __restrict__ res,
                      void* __restrict__ outp, void* __restrict__ outp2, void* __restrict__ outp3,
                      int M, int N, int Kd) {
  __shared__ __bf16 As[BM * BK];
  __shared__ __bf16 Ws[BN * BK];
  int tid = threadIdx.x;
  int lane = tid & 63, w = tid >> 6;
  int wr = w >> 1, wc = w & 1;
  int lr = lane & 15, lg = lane >> 4;
  int bx, by;
  if (SWZ) {
    int lid = blockIdx.x;
    int cpx = gridDim.x >> 3;
    int swz = (lid & 7) * cpx + (lid >> 3);
    int gx = M >> 7;
    bx = swz % gx;
    by = swz / gx;
  } else {
    bx = blockIdx.x; by = blockIdx.y;
  }
  int row0 = bx * BM, col0 = by * BN;

  const __bf16* Abase = A + (size_t)row0 * Kd;
  const __bf16* Wbase = WT + (size_t)col0 * Kd;

  f32x4v acc[4][4];
  #pragma unroll
  for (int i = 0; i < 4; ++i)
    #pragma unroll
    for (int j = 0; j < 4; ++j)
      #pragma unroll
      for (int e = 0; e < 4; ++e) acc[i][j][e] = 0.0f;

  for (int k0 = 0; k0 < Kd; k0 += BK) {
    stage_tile4<128>(Abase + k0, Kd, As, w, lane);
    stage_tile4<128>(Wbase + k0, Kd, Ws, w, lane);
    __syncthreads();
    bf16x8 af[4][2], bfr[4][2];
    #pragma unroll
    for (int mr = 0; mr < 4; ++mr)
      #pragma unroll
      for (int kk = 0; kk < 2; ++kk)
        af[mr][kk] = lds_frag64(As, wr * 64 + mr * 16 + lr, kk * 32 + lg * 8);
    #pragma unroll
    for (int nc = 0; nc < 4; ++nc)
      #pragma unroll
      for (int kk = 0; kk < 2; ++kk)
        bfr[nc][kk] = lds_frag64(Ws, wc * 64 + nc * 16 + lr, kk * 32 + lg * 8);
    __builtin_amdgcn_s_setprio(1);
    #pragma unroll
    for (int mr = 0; mr < 4; ++mr)
      #pragma unroll
      for (int nc = 0; nc < 4; ++nc) {
        acc[mr][nc] = __builtin_amdgcn_mfma_f32_16x16x32_bf16(af[mr][0], bfr[nc][0], acc[mr][nc], 0, 0, 0);
        acc[mr][nc] = __builtin_amdgcn_mfma_f32_16x16x32_bf16(af[mr][1], bfr[nc][1], acc[mr][nc], 0, 0, 0);
      }
    __builtin_amdgcn_s_setprio(0);
    __syncthreads();
  }

  #pragma unroll
  for (int mr = 0; mr < 4; ++mr) {
    #pragma unroll
    for (int nc = 0; nc < 4; ++nc) {
      int c = col0 + wc * 64 + nc * 16 + lr;
      int rb = row0 + wr * 64 + mr * 16 + lg * 4;
      float vv[4];
      #pragma unroll
      for (int j = 0; j < 4; ++j) {
        float t = acc[mr][nc][j] + bias[c];
        if (RES) t += res[(size_t)(rb + j) * N + c];
        if (GELU_ACT) t = 0.5f * t * (1.0f + erff(t * 0.70710678118654752f));
        vv[j] = t;
      }
      if (OMODE == 0) {
        float* out = (float*)outp;
        #pragma unroll
        for (int j = 0; j < 4; ++j) out[(size_t)(rb + j) * N + c] = vv[j];
      } else if (OMODE == 1) {
        __bf16* out = (__bf16*)outp;
        #pragma unroll
        for (int j = 0; j < 4; ++j) out[(size_t)(rb + j) * N + c] = (__bf16)vv[j];
      } else if (OMODE == 3) {
        float* out = (float*)outp;
        __bf16* out2 = (__bf16*)outp2;
        #pragma unroll
        for (int j = 0; j < 4; ++j) {
          out[(size_t)(rb + j) * N + c] = vv[j];
          out2[(size_t)(rb + j) * N + c] = (__bf16)vv[j];
        }
      }
    }
  }
}

// ----- 64x128-tile GEMM, BK=64: Wo (OMODE 0), W2 (OMODE 3), QKV (OMODE 4) -----
template<int OMODE, bool RES>
__global__ __launch_bounds__(256)
void gemm64_kernel(const __bf16* __restrict__ A, const __bf16* __restrict__ WT,
                   const float* __restrict__ bias, const float* __restrict__ res,
                   void* __restrict__ outp, void* __restrict__ outp2, void* __restrict__ outp3,
                   int M, int N, int Kd) {
  __shared__ __bf16 As[64 * BK];
  __shared__ __bf16 Ws[BN * BK];
  int tid = threadIdx.x;
  int lane = tid & 63, w = tid >> 6;
  int wr = w >> 1, wc = w & 1;
  int lr = lane & 15, lg = lane >> 4;
  int row0 = blockIdx.x * 64, col0 = blockIdx.y * BN;

  const __bf16* Abase = A + (size_t)row0 * Kd;
  const __bf16* Wbase = WT + (size_t)col0 * Kd;

  f32x4v acc[2][4];
  #pragma unroll
  for (int i = 0; i < 2; ++i)
    #pragma unroll
    for (int j = 0; j < 4; ++j)
      #pragma unroll
      for (int e = 0; e < 4; ++e) acc[i][j][e] = 0.0f;

  for (int k0 = 0; k0 < Kd; k0 += BK) {
    stage_tile4<64>(Abase + k0, Kd, As, w, lane);
    stage_tile4<128>(Wbase + k0, Kd, Ws, w, lane);
    __syncthreads();
    bf16x8 af[2][2], bfr[4][2];
    #pragma unroll
    for (int mr = 0; mr < 2; ++mr)
      #pragma unroll
      for (int kk = 0; kk < 2; ++kk)
        af[mr][kk] = lds_frag64(As, wr * 32 + mr * 16 + lr, kk * 32 + lg * 8);
    #pragma unroll
    for (int nc = 0; nc < 4; ++nc)
      #pragma unroll
      for (int kk = 0; kk < 2; ++kk)
        bfr[nc][kk] = lds_frag64(Ws, wc * 64 + nc * 16 + lr, kk * 32 + lg * 8);
    __builtin_amdgcn_s_setprio(1);
    #pragma unroll
    for (int mr = 0; mr < 2; ++mr)
      #pragma unroll
      for (int nc = 0; nc < 4; ++nc) {
        acc[mr][nc] = __builtin_amdgcn_mfma_f32_16x16x32_bf16(af[mr][0], bfr[nc][0], acc[mr][nc], 0, 0, 0);
        acc[mr][nc] = __builtin_amdgcn_mfma_f32_16x16x32_bf16(af[mr][1], bfr[nc][1], acc[mr][nc], 0, 0, 0);
      }
    __builtin_amdgcn_s_setprio(0);
    __syncthreads();
  }

  #pragma unroll
  for (int mr = 0; mr < 2; ++mr) {
    #pragma unroll
    for (int nc = 0; nc < 4; ++nc) {
      int c = col0 + wc * 64 + nc * 16 + lr;
      int rb = row0 + wr * 32 + mr * 16 + lg * 4;
      float vv[4];
      #pragma unroll
      for (int j = 0; j < 4; ++j) {
        float t = acc[mr][nc][j] + bias[c];
        if (RES) t += res[(size_t)(rb + j) * N + c];
        vv[j] = t;
      }
      if (OMODE == 0) {
        float* out = (float*)outp;
        #pragma unroll
        for (int j = 0; j < 4; ++j) out[(size_t)(rb + j) * N + c] = vv[j];
      } else if (OMODE == 3) {
        float* out = (float*)outp;
        __bf16* out2 = (__bf16*)outp2;
        #pragma unroll
        for (int j = 0; j < 4; ++j) {
          out[(size_t)(rb + j) * N + c] = vv[j];
          out2[(size_t)(rb + j) * N + c] = (__bf16)vv[j];
        }
      } else {  // OMODE 4: fused QKV epilogue
        if (col0 < 512) {
          __bf16* out = (__bf16*)outp;
          #pragma unroll
          for (int j = 0; j < 4; ++j) out[(size_t)(rb + j) * D_ + c] = (__bf16)vv[j];
        } else if (col0 < 1024) {
          __bf16* out = (__bf16*)outp2;
          #pragma unroll
          for (int j = 0; j < 4; ++j) out[(size_t)(rb + j) * D_ + (c - 512)] = (__bf16)vv[j];
        } else {
          __bf16* out = (__bf16*)outp3;   // vt [B][D][S]
          int b = rb >> 10, s0 = rb & (S_ - 1);
          bf16x4 pk;
          #pragma unroll
          for (int j = 0; j < 4; ++j) pk[j] = (__bf16)vv[j];
          *reinterpret_cast<bf16x4*>(&out[((size_t)b * D_ + (c - 1024)) * S_ + s0]) = pk;
        }
      }
    }
  }
}

// ------- head GEMM: 256x256 tile, 8 waves, BK=64, double-buffered counted-vmcnt pipeline -------
__global__ __launch_bounds__(512)
void gemm_head_kernel(const __bf16* __restrict__ A, const __bf16* __restrict__ WT,
                      const float* __restrict__ bias, float* __restrict__ out,
                      int M, int N, int Kd) {
  __shared__ __bf16 lds[2][2][256 * 64];   // 128 KB
  const int tid = threadIdx.x;
  const int lane = tid & 63, w = tid >> 6;
  const int wr = w >> 2, wc = w & 3;
  const int lr = lane & 15, lg = lane >> 4;

  int lid = blockIdx.x;
  int cpx = gridDim.x >> 3;
  int swz = (lid & 7) * cpx + (lid >> 3);
  int gx = M >> 8;
  int bx = swz % gx, by = swz / gx;
  int row0 = bx * 256, col0 = by * 256;

  const __bf16* Asrc = A + (size_t)row0 * Kd;
  const __bf16* Bsrc = WT + (size_t)col0 * Kd;

  f32x4v acc[8][4];
  #pragma unroll
  for (int i = 0; i < 8; ++i)
    #pragma unroll
    for (int j = 0; j < 4; ++j)
      #pragma unroll
      for (int e = 0; e < 4; ++e) acc[i][j][e] = 0.0f;

  const int NT = Kd / 64;
  stage_half8(Asrc,                      Kd, &lds[0][0][0],    w, lane);
  stage_half8(Asrc + (size_t)128 * Kd,   Kd, &lds[0][0][8192], w, lane);
  stage_half8(Bsrc,                      Kd, &lds[0][1][0],    w, lane);
  stage_half8(Bsrc + (size_t)128 * Kd,   Kd, &lds[0][1][8192], w, lane);

  for (int t = 0; t < NT; ++t) {
    int cur = t & 1, nxt = cur ^ 1;
    int k1 = (t + 1) * 64;
    const __bf16* Ab = &lds[cur][0][0];
    const __bf16* Bb = &lds[cur][1][0];
    bf16x8 bfr[4][2];
    #pragma unroll
    for (int p = 0; p < 4; ++p) {
      if (t < NT - 1) {
        const __bf16* s;
        __bf16* d;
        if (p == 0)      { s = Asrc + k1;                    d = &lds[nxt][0][0]; }
        else if (p == 1) { s = Asrc + (size_t)128 * Kd + k1; d = &lds[nxt][0][8192]; }
        else if (p == 2) { s = Bsrc + k1;                    d = &lds[nxt][1][0]; }
        else             { s = Bsrc + (size_t)128 * Kd + k1; d = &lds[nxt][1][8192]; }
        stage_half8(s, Kd, d, w, lane);
      }
      if (p == 0) {
        if (t < NT - 1) asm volatile("s_waitcnt vmcnt(2)" ::: "memory");
        else            asm volatile("s_waitcnt vmcnt(0)" ::: "memory");
        __builtin_amdgcn_s_barrier();
        #pragma unroll
        for (int nn = 0; nn < 4; ++nn)
          #pragma unroll
          for (int kk = 0; kk < 2; ++kk)
            bfr[nn][kk] = lds_frag64(Bb, wc * 64 + nn * 16 + lr, kk * 32 + lg * 8);
      }
      bf16x8 af[2][2];
      #pragma unroll
      for (int mm = 0; mm < 2; ++mm)
        #pragma unroll
        for (int kk = 0; kk < 2; ++kk)
          af[mm][kk] = lds_frag64(Ab, wr * 128 + p * 32 + mm * 16 + lr, kk * 32 + lg * 8);
      asm volatile("s_waitcnt lgkmcnt(0)" ::: "memory");
      __builtin_amdgcn_sched_barrier(0);
      __builtin_amdgcn_s_setprio(1);
      #pragma unroll
      for (int mm = 0; mm < 2; ++mm)
        #pragma unroll
        for (int nn = 0; nn < 4; ++nn) {
          acc[p * 2 + mm][nn] = __builtin_amdgcn_mfma_f32_16x16x32_bf16(af[mm][0], bfr[nn][0], acc[p * 2 + mm][nn], 0, 0, 0);
          acc[p * 2 + mm][nn] = __builtin_amdgcn_mfma_f32_16x16x32_bf16(af[mm][1], bfr[nn][1], acc[p * 2 + mm][nn], 0, 0, 0);
        }
      __builtin_amdgcn_s_setprio(0);
    }
    __builtin_amdgcn_s_barrier();
  }

  #pragma unroll
  for (int mg = 0; mg < 8; ++mg) {
    #pragma unroll
    for (int nn = 0; nn < 4; ++nn) {
      int c = col0 + wc * 64 + nn * 16 + lr;
      int rb = row0 + wr * 128 + mg * 16 + lg * 4;
      float b = bias[c];
      #pragma unroll
      for (int j = 0; j < 4; ++j)
        out[(size_t)(rb + j) * N + c] = acc[mg][nn][j] + b;
    }
  }
}

// ---------------- fused attention ----------------
__global__ __launch_bounds__(256)
void attn_kernel(const __bf16* __restrict__ qm, const __bf16* __restrict__ km,
                 const __bf16* __restrict__ vt, __bf16* __restrict__ o) {
  __shared__ unsigned short sc16[16][SRS];
  __shared__ float rs[16];   // reciprocal row sums
  const int q0 = blockIdx.x * 16;
  const int hh = blockIdx.y;
  const int bb = blockIdx.z;
  const int tid = threadIdx.x;
  const int lane = tid & 63, w = tid >> 6;
  const int lr = lane & 15, lg = lane >> 4;

  const __bf16* qrow = qm + ((size_t)(bb * S_ + q0 + lr)) * D_ + hh * DK_;
  bf16x8 qf0 = *reinterpret_cast<const bf16x8*>(qrow + lg * 8);
  bf16x8 qf1 = *reinterpret_cast<const bf16x8*>(qrow + 32 + lg * 8);

  const __bf16* kbase = km + ((size_t)bb * S_) * D_ + hh * DK_;
  #pragma unroll 8
  for (int kt = 0; kt < 16; ++kt) {
    int key0 = kt * 64 + w * 16;
    const __bf16* krow = kbase + (size_t)(key0 + lr) * D_;
    bf16x8 kf0 = *reinterpret_cast<const bf16x8*>(krow + lg * 8);
    bf16x8 kf1 = *reinterpret_cast<const bf16x8*>(krow + 32 + lg * 8);
    f32x4v d = {0.0f, 0.0f, 0.0f, 0.0f};
    __builtin_amdgcn_s_setprio(1);
    d = __builtin_amdgcn_mfma_f32_16x16x32_bf16(qf0, kf0, d, 0, 0, 0);
    d = __builtin_amdgcn_mfma_f32_16x16x32_bf16(qf1, kf1, d, 0, 0, 0);
    __builtin_amdgcn_s_setprio(0);
    #pragma unroll
    for (int j = 0; j < 4; ++j) {
      unsigned int u = f32_to_bf16_bits(d[j] * 0.125f);
      u = (u & 0x8000u) ? (~u & 0xFFFFu) : (u | 0x8000u);
      sc16[lg * 4 + j][key0 + lr] = (unsigned short)u;
    }
  }
  __syncthreads();

  {
    int r = tid >> 4, tc = tid & 15;
    const unsigned int* srow = reinterpret_cast<const unsigned int*>(&sc16[r][0]);
    unsigned int wv[32];
    #pragma unroll
    for (int g = 0; g < 8; ++g) {
      uint4 t4 = *reinterpret_cast<const uint4*>(&srow[g * 64 + tc * 4]);
      wv[g * 4 + 0] = t4.x; wv[g * 4 + 1] = t4.y;
      wv[g * 4 + 2] = t4.z; wv[g * 4 + 3] = t4.w;
    }
    unsigned int umax = 0;
    #pragma unroll
    for (int i = 0; i < 32; ++i) {
      unsigned int a = wv[i] & 0xFFFFu, b = wv[i] >> 16;
      unsigned int mx = a > b ? a : b;
      umax = mx > umax ? mx : umax;
    }
    umax = red16umax(umax);
    unsigned int lo = 0;
    for (int bit = 15; bit >= 0; --bit) {
      unsigned int cs = (lo | (1u << bit)) << 16;
      int cnt = 0;
      #pragma unroll
      for (int i = 0; i < 32; ++i) {
        cnt += ((wv[i] << 16) >= cs) ? 1 : 0;
        cnt += (wv[i] >= cs) ? 1 : 0;
      }
      cnt = red16i(cnt);
      if (cnt >= KTOP) lo |= (1u << bit);
    }
    unsigned int um = (umax & 0x8000u) ? (umax ^ 0x8000u) : (~umax & 0xFFFFu);
    float mval = __uint_as_float(um << 16);

    __bf16* P = reinterpret_cast<__bf16*>(&sc16[r][0]);
    float lsum = 0.0f;
    #pragma unroll
    for (int g = 0; g < 8; ++g) {
      bf16x8 pk;
      #pragma unroll
      for (int e = 0; e < 8; ++e) {
        unsigned int wrd = wv[g * 4 + (e >> 1)];
        unsigned int u = (e & 1) ? (wrd >> 16) : (wrd & 0xFFFFu);
        float p = 0.0f;
        if (u >= lo) {
          unsigned int ub = (u & 0x8000u) ? (u ^ 0x8000u) : (~u & 0xFFFFu);
          p = __expf(__uint_as_float(ub << 16) - mval);
        }
        pk[e] = (__bf16)p;
        lsum += (float)pk[e];
      }
      *reinterpret_cast<bf16x8*>(&P[tc * 8 + g * 128]) = pk;
    }
    lsum = red16f(lsum);
    if (tc == 0) rs[r] = 1.0f / lsum;
  }
  __syncthreads();

  {
    const __bf16* P0 = reinterpret_cast<const __bf16*>(&sc16[0][0]);
    const __bf16* vbase = vt + ((size_t)bb * D_ + hh * DK_ + w * 16 + lr) * S_;
    const __bf16* prow = P0 + (size_t)lr * SRS;
    f32x4v oacc = {0.0f, 0.0f, 0.0f, 0.0f};
    __builtin_amdgcn_s_setprio(1);
    #pragma unroll 8
    for (int kt = 0; kt < 32; ++kt) {
      bf16x8 a = *reinterpret_cast<const bf16x8*>(prow + kt * 32 + lg * 8);
      bf16x8 b = *reinterpret_cast<const bf16x8*>(vbase + kt * 32 + lg * 8);
      oacc = __builtin_amdgcn_mfma_f32_16x16x32_bf16(a, b, oacc, 0, 0, 0);
    }
    __builtin_amdgcn_s_setprio(0);
    #pragma unroll
    for (int j = 0; j < 4; ++j) {
      int qr = lg * 4 + j;
      float ov = oacc[j] * rs[qr];
      o[((size_t)(bb * S_ + q0 + qr)) * D_ + hh * DK_ + w * 16 + lr] = (__bf16)ov;
    }
  }
}

extern "C" void kernel_launch(void* const* d_in, const int* in_sizes, int n_in,
                              void* d_out, int out_size, void* d_ws, size_t ws_size,
                              hipStream_t stream) {
  (void)in_sizes; (void)n_in; (void)out_size; (void)ws_size;
  const int*   x    = (const int*)d_in[0];
  const float* tok  = (const float*)d_in[1];
  const float* pos  = (const float*)d_in[2];
  const float* Wq   = (const float*)d_in[3];
  const float* bq   = (const float*)d_in[4];
  const float* Wk   = (const float*)d_in[5];
  const float* bk   = (const float*)d_in[6];
  const float* Wv   = (const float*)d_in[7];
  const float* bv   = (const float*)d_in[8];
  const float* Wo   = (const float*)d_in[9];
  const float* bo   = (const float*)d_in[10];
  const float* g1   = (const float*)d_in[11];
  const float* be1  = (const float*)d_in[12];
  const float* g2   = (const float*)d_in[13];
  const float* be2  = (const float*)d_in[14];
  const float* W1   = (const float*)d_in[15];
  const float* b1   = (const float*)d_in[16];
  const float* Wm   = (const float*)d_in[17];
  const float* bm   = (const float*)d_in[18];
  const float* W2   = (const float*)d_in[19];
  const float* b2   = (const float*)d_in[20];
  const float* Wout = (const float*)d_in[21];
  const float* bout = (const float*)d_in[22];
  float* logits = (float*)d_out;

  const int M = B_ * S_;  // 4096
  float* ws = (float*)d_ws;
  float* h    = ws;
  float* bqkv = h + (size_t)M * D_;
  __bf16* y16  = (__bf16*)(bqkv + (size_t)L_ * 1536);
  __bf16* f1b  = y16  + (size_t)M * D_;
  __bf16* f2b  = f1b  + (size_t)M * DFF_;
  __bf16* qb16 = f2b  + (size_t)M * DFF_;
  __bf16* kb16 = qb16 + (size_t)M * D_;
  __bf16* vt16 = kb16 + (size_t)M * D_;
  __bf16* ob16 = vt16 + (size_t)M * D_;
  __bf16* h16  = ob16 + (size_t)M * D_;
  __bf16* WqkvT = h16 + (size_t)M * D_;
  __bf16* WoT  = WqkvT + (size_t)L_ * 1536 * D_;
  __bf16* W1T  = WoT  + (size_t)L_ * D_ * D_;
  __bf16* WmT  = W1T  + (size_t)L_ * D_ * DFF_;
  __bf16* W2T  = WmT  + (size_t)L_ * DFF_ * DFF_;
  __bf16* WoutT = W2T + (size_t)L_ * D_ * DFF_;

  const long DD = (long)D_ * D_;
  transpose_bf16_kernel<<<dim3(D_/32,  D_/32,   L_), 256, 0, stream>>>(Wq, WqkvT,            D_, D_, DD, 1536L*D_);
  transpose_bf16_kernel<<<dim3(D_/32,  D_/32,   L_), 256, 0, stream>>>(Wk, WqkvT + 512*512,  D_, D_, DD, 1536L*D_);
  transpose_bf16_kernel<<<dim3(D_/32,  D_/32,   L_), 256, 0, stream>>>(Wv, WqkvT + 1024*512, D_, D_, DD, 1536L*D_);
  transpose_bf16_kernel<<<dim3(D_/32,  D_/32,   L_), 256, 0, stream>>>(Wo, WoT, D_, D_, DD, DD);
  transpose_bf16_kernel<<<dim3(DFF_/32, D_/32,  L_), 256, 0, stream>>>(W1, W1T, D_, DFF_, (long)D_*DFF_, (long)D_*DFF_);
  transpose_bf16_kernel<<<dim3(DFF_/32, DFF_/32,L_), 256, 0, stream>>>(Wm, WmT, DFF_, DFF_, (long)DFF_*DFF_, (long)DFF_*DFF_);
  transpose_bf16_kernel<<<dim3(D_/32,  DFF_/32, L_), 256, 0, stream>>>(W2, W2T, DFF_, D_, (long)D_*DFF_, (long)D_*DFF_);
  transpose_bf16_kernel<<<dim3(V_/32,  D_/32,   1 ), 256, 0, stream>>>(Wout, WoutT, D_, V_, (long)D_*V_, (long)D_*V_);
  concat_bias_kernel<<<(L_*1536)/256, 256, 0, stream>>>(bq, bk, bv, bqkv);

  embed_kernel<<<M, 128, 0, stream>>>(x, tok, pos, h);

  for (int l = 0; l < L_; ++l) {
    ln_kernel<<<M, 256, 0, stream>>>(h, g1 + l * D_, be1 + l * D_, y16);
    gemm64_kernel<4,false><<<dim3(M/64, 1536/BN), 256, 0, stream>>>(
        y16, WqkvT + (size_t)l * 1536 * D_, bqkv + l * 1536, nullptr,
        qb16, kb16, vt16, M, 1536, D_);
    attn_kernel<<<dim3(S_/16, H_, B_), 256, 0, stream>>>(qb16, kb16, vt16, ob16);
    gemm64_kernel<0,true><<<dim3(M/64, D_/BN), 256, 0, stream>>>(
        ob16, WoT + (size_t)l * DD, bo + l * D_, h, h, nullptr, nullptr, M, D_, D_);
    ln_kernel<<<M, 256, 0, stream>>>(h, g2 + l * D_, be2 + l * D_, y16);
    gemm_bf16_kernel<1,true,false,true><<<dim3((M/BM) * (DFF_/BN)), 256, 0, stream>>>(
        y16, W1T + (size_t)l * D_ * DFF_, b1 + l * DFF_, nullptr, f1b, nullptr, nullptr, M, DFF_, D_);
    gemm_bf16_kernel<1,true,false,true><<<dim3((M/BM) * (DFF_/BN)), 256, 0, stream>>>(
        f1b, WmT + (size_t)l * DFF_ * DFF_, bm + l * DFF_, nullptr, f2b, nullptr, nullptr, M, DFF_, DFF_);
    gemm64_kernel<3,true><<<dim3(M/64, D_/BN), 256, 0, stream>>>(
        f2b, W2T + (size_t)l * D_ * DFF_, b2 + l * D_, h, h, h16, nullptr, M, D_, DFF_);
  }
  gemm_head_kernel<<<dim3((M/256) * (V_/256)), 512, 0, stream>>>(
      h16, WoutT, bout, logits, M, V_, D_);
}

// Round 11
// 1211.309 us; speedup vs baseline: 1.0632x; 1.0325x over previous
//
#include <hip/hip_runtime.h>
#include <hip/hip_bf16.h>
#include <math.h>

#define B_ 4
#define S_ 1024
#define D_ 512
#define H_ 8
#define L_ 4
#define DFF_ 2048
#define V_ 32000
#define DK_ 64
#define KTOP 307
#define SRS 1048    // score row stride in u16 elems

using bf16x8 = __attribute__((ext_vector_type(8))) __bf16;
using bf16x4 = __attribute__((ext_vector_type(4))) __bf16;
using bf16x2 = __attribute__((ext_vector_type(2))) __bf16;
using f32x4v = __attribute__((ext_vector_type(4))) float;

__device__ __forceinline__ void gload_lds16(const __bf16* g, __bf16* l) {
  __builtin_amdgcn_global_load_lds(
      (const __attribute__((address_space(1))) void*)g,
      (__attribute__((address_space(3))) void*)l, 16, 0, 0);
}

// fp32 -> bf16 bits (RNE), as low 16 of u32
__device__ __forceinline__ unsigned int f32_to_bf16_bits(float s) {
  unsigned int x = __float_as_uint(s);
  return (x + 0x7FFFu + ((x >> 16) & 1u)) >> 16;
}

// ---- DPP 16-lane reductions (teams aligned to DPP rows) ----
__device__ __forceinline__ int red16i(int x) {
  x += __builtin_amdgcn_update_dpp(0, x, 0xB1, 0xF, 0xF, true);
  x += __builtin_amdgcn_update_dpp(0, x, 0x4E, 0xF, 0xF, true);
  x += __builtin_amdgcn_update_dpp(0, x, 0x141, 0xF, 0xF, true);
  x += __builtin_amdgcn_update_dpp(0, x, 0x140, 0xF, 0xF, true);
  return x;
}
__device__ __forceinline__ unsigned int red16umax(unsigned int x) {
  unsigned int t;
  t = (unsigned int)__builtin_amdgcn_update_dpp(0, (int)x, 0xB1, 0xF, 0xF, true);  x = t > x ? t : x;
  t = (unsigned int)__builtin_amdgcn_update_dpp(0, (int)x, 0x4E, 0xF, 0xF, true);  x = t > x ? t : x;
  t = (unsigned int)__builtin_amdgcn_update_dpp(0, (int)x, 0x141, 0xF, 0xF, true); x = t > x ? t : x;
  t = (unsigned int)__builtin_amdgcn_update_dpp(0, (int)x, 0x140, 0xF, 0xF, true); x = t > x ? t : x;
  return x;
}
__device__ __forceinline__ float red16f(float x) {
  x += __int_as_float(__builtin_amdgcn_update_dpp(0, __float_as_int(x), 0xB1, 0xF, 0xF, true));
  x += __int_as_float(__builtin_amdgcn_update_dpp(0, __float_as_int(x), 0x4E, 0xF, 0xF, true));
  x += __int_as_float(__builtin_amdgcn_update_dpp(0, __float_as_int(x), 0x141, 0xF, 0xF, true));
  x += __int_as_float(__builtin_amdgcn_update_dpp(0, __float_as_int(x), 0x140, 0xF, 0xF, true));
  return x;
}
__device__ __forceinline__ float red64f(float x) {
  x = red16f(x);
  x += __shfl_xor(x, 16, 64);
  x += __shfl_xor(x, 32, 64);
  return x;
}

// ---- st_16x32-swizzled [R][64] bf16 LDS helpers; XOR (row&7)<<3 elements ----
template<int ROWS>
__device__ __forceinline__ void stage_tile4(const __bf16* src, int Kd, __bf16* lds,
                                            int w, int lane) {
  #pragma unroll
  for (int c = 0; c < ROWS / 32; ++c) {
    int rblk = (c * 4 + w) * 8;
    int row = rblk + (lane >> 3);
    int col = (lane & 7) * 8;
    int scol = col ^ ((row & 7) << 3);
    gload_lds16(src + (size_t)row * Kd + scol, lds + rblk * 64);
  }
}
__device__ __forceinline__ void stage_half8(const __bf16* src, int Kd, __bf16* lds,
                                            int w, int lane) {
  #pragma unroll
  for (int c = 0; c < 2; ++c) {
    int rblk = (c * 8 + w) * 8;
    int row = rblk + (lane >> 3);
    int col = (lane & 7) * 8;
    int scol = col ^ ((row & 7) << 3);
    gload_lds16(src + (size_t)row * Kd + scol, lds + rblk * 64);
  }
}
__device__ __forceinline__ bf16x8 lds_frag64(const __bf16* lds, int row, int colbase) {
  int col = colbase ^ ((row & 7) << 3);
  return *reinterpret_cast<const bf16x8*>(lds + row * 64 + col);
}

// ---------------- embedding ----------------
__global__ void embed_kernel(const int* __restrict__ x, const float* __restrict__ tok,
                             const float* __restrict__ pos, float* __restrict__ h) {
  int row = blockIdx.x;
  int t = threadIdx.x;
  int s = row & (S_ - 1);
  int token = x[row];
  const float4* t4 = reinterpret_cast<const float4*>(tok + (size_t)token * D_);
  const float4* p4 = reinterpret_cast<const float4*>(pos + (size_t)s * D_);
  float4 a = t4[t];
  float4 b = p4[t];
  a.x += b.x; a.y += b.y; a.z += b.z; a.w += b.w;
  reinterpret_cast<float4*>(h + (size_t)row * D_)[t] = a;
}

// ---------------- layernorm: one WAVE per row, no LDS/barrier ----------------
__global__ __launch_bounds__(256)
void ln_kernel(const float* __restrict__ xin, const float* __restrict__ g,
               const float* __restrict__ bta, __bf16* __restrict__ y) {
  int w = threadIdx.x >> 6, lane = threadIdx.x & 63;
  int row = blockIdx.x * 4 + w;
  const float4* x4 = reinterpret_cast<const float4*>(xin + (size_t)row * D_);
  float4 a = x4[lane * 2];
  float4 b = x4[lane * 2 + 1];
  float s = a.x + a.y + a.z + a.w + b.x + b.y + b.z + b.w;
  float q = a.x * a.x + a.y * a.y + a.z * a.z + a.w * a.w
          + b.x * b.x + b.y * b.y + b.z * b.z + b.w * b.w;
  s = red64f(s);
  q = red64f(q);
  float mu = s * (1.0f / D_);
  float var = q * (1.0f / D_) - mu * mu;
  float rstd = rsqrtf(var + 1e-5f);
  const float4* g4 = reinterpret_cast<const float4*>(g);
  const float4* b4 = reinterpret_cast<const float4*>(bta);
  float4 g0 = g4[lane * 2], g1 = g4[lane * 2 + 1];
  float4 e0 = b4[lane * 2], e1 = b4[lane * 2 + 1];
  bf16x8 o8;
  o8[0] = (__bf16)((a.x - mu) * rstd * g0.x + e0.x);
  o8[1] = (__bf16)((a.y - mu) * rstd * g0.y + e0.y);
  o8[2] = (__bf16)((a.z - mu) * rstd * g0.z + e0.z);
  o8[3] = (__bf16)((a.w - mu) * rstd * g0.w + e0.w);
  o8[4] = (__bf16)((b.x - mu) * rstd * g1.x + e1.x);
  o8[5] = (__bf16)((b.y - mu) * rstd * g1.y + e1.y);
  o8[6] = (__bf16)((b.z - mu) * rstd * g1.z + e1.z);
  o8[7] = (__bf16)((b.w - mu) * rstd * g1.w + e1.w);
  *reinterpret_cast<bf16x8*>(y + (size_t)row * D_ + lane * 8) = o8;
}

// ------------- transpose fp32 [Kd][N] -> bf16 [N][Kd] -------------
__global__ void transpose_bf16_kernel(const float* __restrict__ in, __bf16* __restrict__ out,
                                      int Kd, int N, long in_bstride, long out_bstride) {
  __shared__ float tile[32][33];
  const float* ib = in + (size_t)blockIdx.z * in_bstride;
  __bf16* ob = out + (size_t)blockIdx.z * out_bstride;
  int n0 = blockIdx.x * 32, k0 = blockIdx.y * 32;
  int tx = threadIdx.x & 31, ty = threadIdx.x >> 5;
  #pragma unroll
  for (int i = 0; i < 4; ++i)
    tile[ty + i * 8][tx] = ib[(size_t)(k0 + ty + i * 8) * N + n0 + tx];
  __syncthreads();
  #pragma unroll
  for (int i = 0; i < 4; ++i)
    ob[(size_t)(n0 + ty + i * 8) * Kd + k0 + tx] = (__bf16)tile[tx][ty + i * 8];
}

// ---------------- bias concat for fused QKV ----------------
__global__ void concat_bias_kernel(const float* __restrict__ bq, const float* __restrict__ bk,
                                   const float* __restrict__ bv, float* __restrict__ bqkv) {
  int i = blockIdx.x * 256 + threadIdx.x;
  int l = i / 1536, c = i - l * 1536;
  float v = (c < 512) ? bq[l * 512 + c]
          : (c < 1024) ? bk[l * 512 + c - 512]
                       : bv[l * 512 + c - 1024];
  bqkv[i] = v;
}

// ---------------- bf16 MFMA GEMM, 128x128 tile, BK=64, swizzled LDS (W1/Wm) ----------------
#define BM 128
#define BN 128
#define BK 64

template<int OMODE, bool GELU_ACT, bool RES, bool SWZ>
__global__ __launch_bounds__(256)
void gemm_bf16_kernel(const __bf16* __restrict__ A, const __bf16* __restrict__ WT,
                      const float* __restrict__ bias, const float* __restrict__ res,
                      void* __restrict__ outp, void* __restrict__ outp2, void* __restrict__ outp3,
                      int M, int N, int Kd) {
  __shared__ __bf16 As[BM * BK];
  __shared__ __bf16 Ws[BN * BK];
  int tid = threadIdx.x;
  int lane = tid & 63, w = tid >> 6;
  int wr = w >> 1, wc = w & 1;
  int lr = lane & 15, lg = lane >> 4;
  int bx, by;
  if (SWZ) {
    int lid = blockIdx.x;
    int cpx = gridDim.x >> 3;
    int swz = (lid & 7) * cpx + (lid >> 3);
    int gx = M >> 7;
    bx = swz % gx;
    by = swz / gx;
  } else {
    bx = blockIdx.x; by = blockIdx.y;
  }
  int row0 = bx * BM, col0 = by * BN;

  const __bf16* Abase = A + (size_t)row0 * Kd;
  const __bf16* Wbase = WT + (size_t)col0 * Kd;

  f32x4v acc[4][4];
  #pragma unroll
  for (int i = 0; i < 4; ++i)
    #pragma unroll
    for (int j = 0; j < 4; ++j)
      #pragma unroll
      for (int e = 0; e < 4; ++e) acc[i][j][e] = 0.0f;

  for (int k0 = 0; k0 < Kd; k0 += BK) {
    stage_tile4<128>(Abase + k0, Kd, As, w, lane);
    stage_tile4<128>(Wbase + k0, Kd, Ws, w, lane);
    __syncthreads();
    bf16x8 af[4][2], bfr[4][2];
    #pragma unroll
    for (int mr = 0; mr < 4; ++mr)
      #pragma unroll
      for (int kk = 0; kk < 2; ++kk)
        af[mr][kk] = lds_frag64(As, wr * 64 + mr * 16 + lr, kk * 32 + lg * 8);
    #pragma unroll
    for (int nc = 0; nc < 4; ++nc)
      #pragma unroll
      for (int kk = 0; kk < 2; ++kk)
        bfr[nc][kk] = lds_frag64(Ws, wc * 64 + nc * 16 + lr, kk * 32 + lg * 8);
    __builtin_amdgcn_s_setprio(1);
    #pragma unroll
    for (int mr = 0; mr < 4; ++mr)
      #pragma unroll
      for (int nc = 0; nc < 4; ++nc) {
        acc[mr][nc] = __builtin_amdgcn_mfma_f32_16x16x32_bf16(af[mr][0], bfr[nc][0], acc[mr][nc], 0, 0, 0);
        acc[mr][nc] = __builtin_amdgcn_mfma_f32_16x16x32_bf16(af[mr][1], bfr[nc][1], acc[mr][nc], 0, 0, 0);
      }
    __builtin_amdgcn_s_setprio(0);
    __syncthreads();
  }

  #pragma unroll
  for (int mr = 0; mr < 4; ++mr) {
    #pragma unroll
    for (int nc = 0; nc < 4; ++nc) {
      int c = col0 + wc * 64 + nc * 16 + lr;
      int rb = row0 + wr * 64 + mr * 16 + lg * 4;
      float vv[4];
      #pragma unroll
      for (int j = 0; j < 4; ++j) {
        float t = acc[mr][nc][j] + bias[c];
        if (RES) t += res[(size_t)(rb + j) * N + c];
        if (GELU_ACT) t = 0.5f * t * (1.0f + erff(t * 0.70710678118654752f));
        vv[j] = t;
      }
      if (OMODE == 0) {
        float* out = (float*)outp;
        #pragma unroll
        for (int j = 0; j < 4; ++j) out[(size_t)(rb + j) * N + c] = vv[j];
      } else if (OMODE == 1) {
        __bf16* out = (__bf16*)outp;
        #pragma unroll
        for (int j = 0; j < 4; ++j) out[(size_t)(rb + j) * N + c] = (__bf16)vv[j];
      } else if (OMODE == 3) {
        float* out = (float*)outp;
        __bf16* out2 = (__bf16*)outp2;
        #pragma unroll
        for (int j = 0; j < 4; ++j) {
          out[(size_t)(rb + j) * N + c] = vv[j];
          out2[(size_t)(rb + j) * N + c] = (__bf16)vv[j];
        }
      }
    }
  }
}

// ----- 64x128-tile GEMM, BK=64: Wo (OMODE 0), W2 (OMODE 3), QKV (OMODE 4) -----
template<int OMODE, bool RES>
__global__ __launch_bounds__(256)
void gemm64_kernel(const __bf16* __restrict__ A, const __bf16* __restrict__ WT,
                   const float* __restrict__ bias, const float* __restrict__ res,
                   void* __restrict__ outp, void* __restrict__ outp2, void* __restrict__ outp3,
                   int M, int N, int Kd) {
  __shared__ __bf16 As[64 * BK];
  __shared__ __bf16 Ws[BN * BK];
  int tid = threadIdx.x;
  int lane = tid & 63, w = tid >> 6;
  int wr = w >> 1, wc = w & 1;
  int lr = lane & 15, lg = lane >> 4;
  int row0 = blockIdx.x * 64, col0 = blockIdx.y * BN;

  const __bf16* Abase = A + (size_t)row0 * Kd;
  const __bf16* Wbase = WT + (size_t)col0 * Kd;

  f32x4v acc[2][4];
  #pragma unroll
  for (int i = 0; i < 2; ++i)
    #pragma unroll
    for (int j = 0; j < 4; ++j)
      #pragma unroll
      for (int e = 0; e < 4; ++e) acc[i][j][e] = 0.0f;

  for (int k0 = 0; k0 < Kd; k0 += BK) {
    stage_tile4<64>(Abase + k0, Kd, As, w, lane);
    stage_tile4<128>(Wbase + k0, Kd, Ws, w, lane);
    __syncthreads();
    bf16x8 af[2][2], bfr[4][2];
    #pragma unroll
    for (int mr = 0; mr < 2; ++mr)
      #pragma unroll
      for (int kk = 0; kk < 2; ++kk)
        af[mr][kk] = lds_frag64(As, wr * 32 + mr * 16 + lr, kk * 32 + lg * 8);
    #pragma unroll
    for (int nc = 0; nc < 4; ++nc)
      #pragma unroll
      for (int kk = 0; kk < 2; ++kk)
        bfr[nc][kk] = lds_frag64(Ws, wc * 64 + nc * 16 + lr, kk * 32 + lg * 8);
    __builtin_amdgcn_s_setprio(1);
    #pragma unroll
    for (int mr = 0; mr < 2; ++mr)
      #pragma unroll
      for (int nc = 0; nc < 4; ++nc) {
        acc[mr][nc] = __builtin_amdgcn_mfma_f32_16x16x32_bf16(af[mr][0], bfr[nc][0], acc[mr][nc], 0, 0, 0);
        acc[mr][nc] = __builtin_amdgcn_mfma_f32_16x16x32_bf16(af[mr][1], bfr[nc][1], acc[mr][nc], 0, 0, 0);
      }
    __builtin_amdgcn_s_setprio(0);
    __syncthreads();
  }

  #pragma unroll
  for (int mr = 0; mr < 2; ++mr) {
    #pragma unroll
    for (int nc = 0; nc < 4; ++nc) {
      int c = col0 + wc * 64 + nc * 16 + lr;
      int rb = row0 + wr * 32 + mr * 16 + lg * 4;
      float vv[4];
      #pragma unroll
      for (int j = 0; j < 4; ++j) {
        float t = acc[mr][nc][j] + bias[c];
        if (RES) t += res[(size_t)(rb + j) * N + c];
        vv[j] = t;
      }
      if (OMODE == 0) {
        float* out = (float*)outp;
        #pragma unroll
        for (int j = 0; j < 4; ++j) out[(size_t)(rb + j) * N + c] = vv[j];
      } else if (OMODE == 3) {
        float* out = (float*)outp;
        __bf16* out2 = (__bf16*)outp2;
        #pragma unroll
        for (int j = 0; j < 4; ++j) {
          out[(size_t)(rb + j) * N + c] = vv[j];
          out2[(size_t)(rb + j) * N + c] = (__bf16)vv[j];
        }
      } else {  // OMODE 4: fused QKV epilogue
        if (col0 < 512) {
          __bf16* out = (__bf16*)outp;
          #pragma unroll
          for (int j = 0; j < 4; ++j) out[(size_t)(rb + j) * D_ + c] = (__bf16)vv[j];
        } else if (col0 < 1024) {
          __bf16* out = (__bf16*)outp2;
          #pragma unroll
          for (int j = 0; j < 4; ++j) out[(size_t)(rb + j) * D_ + (c - 512)] = (__bf16)vv[j];
        } else {
          __bf16* out = (__bf16*)outp3;   // vt [B][D][S]
          int b = rb >> 10, s0 = rb & (S_ - 1);
          bf16x4 pk;
          #pragma unroll
          for (int j = 0; j < 4; ++j) pk[j] = (__bf16)vv[j];
          *reinterpret_cast<bf16x4*>(&out[((size_t)b * D_ + (c - 1024)) * S_ + s0]) = pk;
        }
      }
    }
  }
}

// ------- head GEMM: 256x256 tile, 8 waves, BK=64, double-buffered counted-vmcnt pipeline -------
__global__ __launch_bounds__(512)
void gemm_head_kernel(const __bf16* __restrict__ A, const __bf16* __restrict__ WT,
                      const float* __restrict__ bias, float* __restrict__ out,
                      int M, int N, int Kd) {
  __shared__ __bf16 lds[2][2][256 * 64];   // 128 KB
  const int tid = threadIdx.x;
  const int lane = tid & 63, w = tid >> 6;
  const int wr = w >> 2, wc = w & 3;
  const int lr = lane & 15, lg = lane >> 4;

  int lid = blockIdx.x;
  int cpx = gridDim.x >> 3;
  int swz = (lid & 7) * cpx + (lid >> 3);
  int gx = M >> 8;
  int bx = swz % gx, by = swz / gx;
  int row0 = bx * 256, col0 = by * 256;

  const __bf16* Asrc = A + (size_t)row0 * Kd;
  const __bf16* Bsrc = WT + (size_t)col0 * Kd;

  f32x4v acc[8][4];
  #pragma unroll
  for (int i = 0; i < 8; ++i)
    #pragma unroll
    for (int j = 0; j < 4; ++j)
      #pragma unroll
      for (int e = 0; e < 4; ++e) acc[i][j][e] = 0.0f;

  const int NT = Kd / 64;
  stage_half8(Asrc,                      Kd, &lds[0][0][0],    w, lane);
  stage_half8(Asrc + (size_t)128 * Kd,   Kd, &lds[0][0][8192], w, lane);
  stage_half8(Bsrc,                      Kd, &lds[0][1][0],    w, lane);
  stage_half8(Bsrc + (size_t)128 * Kd,   Kd, &lds[0][1][8192], w, lane);

  for (int t = 0; t < NT; ++t) {
    int cur = t & 1, nxt = cur ^ 1;
    int k1 = (t + 1) * 64;
    const __bf16* Ab = &lds[cur][0][0];
    const __bf16* Bb = &lds[cur][1][0];
    bf16x8 bfr[4][2];
    #pragma unroll
    for (int p = 0; p < 4; ++p) {
      if (t < NT - 1) {
        const __bf16* s;
        __bf16* d;
        if (p == 0)      { s = Asrc + k1;                    d = &lds[nxt][0][0]; }
        else if (p == 1) { s = Asrc + (size_t)128 * Kd + k1; d = &lds[nxt][0][8192]; }
        else if (p == 2) { s = Bsrc + k1;                    d = &lds[nxt][1][0]; }
        else             { s = Bsrc + (size_t)128 * Kd + k1; d = &lds[nxt][1][8192]; }
        stage_half8(s, Kd, d, w, lane);
      }
      if (p == 0) {
        if (t < NT - 1) asm volatile("s_waitcnt vmcnt(2)" ::: "memory");
        else            asm volatile("s_waitcnt vmcnt(0)" ::: "memory");
        __builtin_amdgcn_s_barrier();
        #pragma unroll
        for (int nn = 0; nn < 4; ++nn)
          #pragma unroll
          for (int kk = 0; kk < 2; ++kk)
            bfr[nn][kk] = lds_frag64(Bb, wc * 64 + nn * 16 + lr, kk * 32 + lg * 8);
      }
      bf16x8 af[2][2];
      #pragma unroll
      for (int mm = 0; mm < 2; ++mm)
        #pragma unroll
        for (int kk = 0; kk < 2; ++kk)
          af[mm][kk] = lds_frag64(Ab, wr * 128 + p * 32 + mm * 16 + lr, kk * 32 + lg * 8);
      asm volatile("s_waitcnt lgkmcnt(0)" ::: "memory");
      __builtin_amdgcn_sched_barrier(0);
      __builtin_amdgcn_s_setprio(1);
      #pragma unroll
      for (int mm = 0; mm < 2; ++mm)
        #pragma unroll
        for (int nn = 0; nn < 4; ++nn) {
          acc[p * 2 + mm][nn] = __builtin_amdgcn_mfma_f32_16x16x32_bf16(af[mm][0], bfr[nn][0], acc[p * 2 + mm][nn], 0, 0, 0);
          acc[p * 2 + mm][nn] = __builtin_amdgcn_mfma_f32_16x16x32_bf16(af[mm][1], bfr[nn][1], acc[p * 2 + mm][nn], 0, 0, 0);
        }
      __builtin_amdgcn_s_setprio(0);
    }
    __builtin_amdgcn_s_barrier();
  }

  #pragma unroll
  for (int mg = 0; mg < 8; ++mg) {
    #pragma unroll
    for (int nn = 0; nn < 4; ++nn) {
      int c = col0 + wc * 64 + nn * 16 + lr;
      int rb = row0 + wr * 128 + mg * 16 + lg * 4;
      float b = bias[c];
      #pragma unroll
      for (int j = 0; j < 4; ++j)
        out[(size_t)(rb + j) * N + c] = acc[mg][nn][j] + b;
    }
  }
}

// ---------------- fused attention: 8 waves, 16 q-rows, u16 scores ----------------
__global__ __launch_bounds__(512)
void attn_kernel(const __bf16* __restrict__ qm, const __bf16* __restrict__ km,
                 const __bf16* __restrict__ vt, __bf16* __restrict__ o) {
  __shared__ unsigned short sc16[16][SRS];
  __shared__ float ored[4][64][4];   // kt-half partials from waves 4-7
  __shared__ float rs[16];           // reciprocal row sums
  const int q0 = blockIdx.x * 16;
  const int hh = blockIdx.y;
  const int bb = blockIdx.z;
  const int tid = threadIdx.x;
  const int lane = tid & 63, w = tid >> 6;   // 8 waves
  const int lr = lane & 15, lg = lane >> 4;

  const __bf16* qrow = qm + ((size_t)(bb * S_ + q0 + lr)) * D_ + hh * DK_;
  bf16x8 qf0 = *reinterpret_cast<const bf16x8*>(qrow + lg * 8);
  bf16x8 qf1 = *reinterpret_cast<const bf16x8*>(qrow + 32 + lg * 8);

  // ---- phase 1: scores via MFMA; 8 waves cover 128 keys per iteration ----
  const __bf16* kbase = km + ((size_t)bb * S_) * D_ + hh * DK_;
  #pragma unroll
  for (int kt = 0; kt < 8; ++kt) {
    int key0 = kt * 128 + w * 16;
    const __bf16* krow = kbase + (size_t)(key0 + lr) * D_;
    bf16x8 kf0 = *reinterpret_cast<const bf16x8*>(krow + lg * 8);
    bf16x8 kf1 = *reinterpret_cast<const bf16x8*>(krow + 32 + lg * 8);
    f32x4v d = {0.0f, 0.0f, 0.0f, 0.0f};
    __builtin_amdgcn_s_setprio(1);
    d = __builtin_amdgcn_mfma_f32_16x16x32_bf16(qf0, kf0, d, 0, 0, 0);
    d = __builtin_amdgcn_mfma_f32_16x16x32_bf16(qf1, kf1, d, 0, 0, 0);
    __builtin_amdgcn_s_setprio(0);
    #pragma unroll
    for (int j = 0; j < 4; ++j) {
      unsigned int u = f32_to_bf16_bits(d[j] * 0.125f);
      u = (u & 0x8000u) ? (~u & 0xFFFFu) : (u | 0x8000u);
      sc16[lg * 4 + j][key0 + lr] = (unsigned short)u;
    }
  }
  __syncthreads();

  // ---- phase 2: 32 threads per row (half-wave teams); 16-bit binary search ----
  {
    int r = tid >> 5, tc = tid & 31;
    const unsigned int* srow = reinterpret_cast<const unsigned int*>(&sc16[r][0]);
    unsigned int wv[16];   // 32 u16 values packed
    #pragma unroll
    for (int g = 0; g < 4; ++g) {
      uint4 t4 = *reinterpret_cast<const uint4*>(&srow[g * 128 + tc * 4]);
      wv[g * 4 + 0] = t4.x; wv[g * 4 + 1] = t4.y;
      wv[g * 4 + 2] = t4.z; wv[g * 4 + 3] = t4.w;
    }
    unsigned int umax = 0;
    #pragma unroll
    for (int i = 0; i < 16; ++i) {
      unsigned int a = wv[i] & 0xFFFFu, b = wv[i] >> 16;
      unsigned int mx = a > b ? a : b;
      umax = mx > umax ? mx : umax;
    }
    umax = red16umax(umax);
    {
      unsigned int other = (unsigned int)__shfl_xor((int)umax, 16, 32);
      umax = other > umax ? other : umax;
    }
    unsigned int lo = 0;
    for (int bit = 15; bit >= 0; --bit) {
      unsigned int cs = (lo | (1u << bit)) << 16;
      int cnt = 0;
      #pragma unroll
      for (int i = 0; i < 16; ++i) {
        cnt += ((wv[i] << 16) >= cs) ? 1 : 0;
        cnt += (wv[i] >= cs) ? 1 : 0;
      }
      cnt = red16i(cnt);
      cnt += __shfl_xor(cnt, 16, 32);
      if (cnt >= KTOP) lo |= (1u << bit);
    }
    unsigned int um = (umax & 0x8000u) ? (umax ^ 0x8000u) : (~umax & 0xFFFFu);
    float mval = __uint_as_float(um << 16);

    __bf16* P = reinterpret_cast<__bf16*>(&sc16[r][0]);
    float lsum = 0.0f;
    #pragma unroll
    for (int g = 0; g < 4; ++g) {
      bf16x8 pk;
      #pragma unroll
      for (int e = 0; e < 8; ++e) {
        unsigned int wrd = wv[g * 4 + (e >> 1)];
        unsigned int u = (e & 1) ? (wrd >> 16) : (wrd & 0xFFFFu);
        float p = 0.0f;
        if (u >= lo) {
          unsigned int ub = (u & 0x8000u) ? (u ^ 0x8000u) : (~u & 0xFFFFu);
          p = __expf(__uint_as_float(ub << 16) - mval);
        }
        pk[e] = (__bf16)p;
        lsum += (float)pk[e];
      }
      *reinterpret_cast<bf16x8*>(&P[tc * 8 + g * 256]) = pk;
    }
    lsum = red16f(lsum);
    lsum += __shfl_xor(lsum, 16, 32);
    if (tc == 0) rs[r] = 1.0f / lsum;
  }
  __syncthreads();

  // ---- phase 3: PV split across wave pairs (kt halves), LDS reduce ----
  {
    const __bf16* P0 = reinterpret_cast<const __bf16*>(&sc16[0][0]);
    int wc4 = w & 3;      // column group (16 cols each)
    int half = w >> 2;    // kt half
    const __bf16* vbase = vt + ((size_t)bb * D_ + hh * DK_ + wc4 * 16 + lr) * S_;
    const __bf16* prow = P0 + (size_t)lr * SRS;
    f32x4v oacc = {0.0f, 0.0f, 0.0f, 0.0f};
    int kt0 = half * 16;
    __builtin_amdgcn_s_setprio(1);
    #pragma unroll
    for (int kk = 0; kk < 16; ++kk) {
      int kt = kt0 + kk;
      bf16x8 a = *reinterpret_cast<const bf16x8*>(prow + kt * 32 + lg * 8);
      bf16x8 b = *reinterpret_cast<const bf16x8*>(vbase + kt * 32 + lg * 8);
      oacc = __builtin_amdgcn_mfma_f32_16x16x32_bf16(a, b, oacc, 0, 0, 0);
    }
    __builtin_amdgcn_s_setprio(0);
    if (half == 1) {
      float4 st;
      st.x = oacc[0]; st.y = oacc[1]; st.z = oacc[2]; st.w = oacc[3];
      *reinterpret_cast<float4*>(&ored[wc4][lane][0]) = st;
    }
    __syncthreads();
    if (half == 0) {
      float4 pv = *reinterpret_cast<const float4*>(&ored[wc4][lane][0]);
      oacc[0] += pv.x; oacc[1] += pv.y; oacc[2] += pv.z; oacc[3] += pv.w;
      #pragma unroll
      for (int j = 0; j < 4; ++j) {
        int qr = lg * 4 + j;
        float ov = oacc[j] * rs[qr];
        o[((size_t)(bb * S_ + q0 + qr)) * D_ + hh * DK_ + wc4 * 16 + lr] = (__bf16)ov;
      }
    }
  }
}

extern "C" void kernel_launch(void* const* d_in, const int* in_sizes, int n_in,
                              void* d_out, int out_size, void* d_ws, size_t ws_size,
                              hipStream_t stream) {
  (void)in_sizes; (void)n_in; (void)out_size; (void)ws_size;
  const int*   x    = (const int*)d_in[0];
  const float* tok  = (const float*)d_in[1];
  const float* pos  = (const float*)d_in[2];
  const float* Wq   = (const float*)d_in[3];
  const float* bq   = (const float*)d_in[4];
  const float* Wk   = (const float*)d_in[5];
  const float* bk   = (const float*)d_in[6];
  const float* Wv   = (const float*)d_in[7];
  const float* bv   = (const float*)d_in[8];
  const float* Wo   = (const float*)d_in[9];
  const float* bo   = (const float*)d_in[10];
  const float* g1   = (const float*)d_in[11];
  const float* be1  = (const float*)d_in[12];
  const float* g2   = (const float*)d_in[13];
  const float* be2  = (const float*)d_in[14];
  const float* W1   = (const float*)d_in[15];
  const float* b1   = (const float*)d_in[16];
  const float* Wm   = (const float*)d_in[17];
  const float* bm   = (const float*)d_in[18];
  const float* W2   = (const float*)d_in[19];
  const float* b2   = (const float*)d_in[20];
  const float* Wout = (const float*)d_in[21];
  const float* bout = (const float*)d_in[22];
  float* logits = (float*)d_out;

  const int M = B_ * S_;  // 4096
  float* ws = (float*)d_ws;
  float* h    = ws;
  float* bqkv = h + (size_t)M * D_;
  __bf16* y16  = (__bf16*)(bqkv + (size_t)L_ * 1536);
  __bf16* f1b  = y16  + (size_t)M * D_;
  __bf16* f2b  = f1b  + (size_t)M * DFF_;
  __bf16* qb16 = f2b  + (size_t)M * DFF_;
  __bf16* kb16 = qb16 + (size_t)M * D_;
  __bf16* vt16 = kb16 + (size_t)M * D_;
  __bf16* ob16 = vt16 + (size_t)M * D_;
  __bf16* h16  = ob16 + (size_t)M * D_;
  __bf16* WqkvT = h16 + (size_t)M * D_;
  __bf16* WoT  = WqkvT + (size_t)L_ * 1536 * D_;
  __bf16* W1T  = WoT  + (size_t)L_ * D_ * D_;
  __bf16* WmT  = W1T  + (size_t)L_ * D_ * DFF_;
  __bf16* W2T  = WmT  + (size_t)L_ * DFF_ * DFF_;
  __bf16* WoutT = W2T + (size_t)L_ * D_ * DFF_;

  const long DD = (long)D_ * D_;
  transpose_bf16_kernel<<<dim3(D_/32,  D_/32,   L_), 256, 0, stream>>>(Wq, WqkvT,            D_, D_, DD, 1536L*D_);
  transpose_bf16_kernel<<<dim3(D_/32,  D_/32,   L_), 256, 0, stream>>>(Wk, WqkvT + 512*512,  D_, D_, DD, 1536L*D_);
  transpose_bf16_kernel<<<dim3(D_/32,  D_/32,   L_), 256, 0, stream>>>(Wv, WqkvT + 1024*512, D_, D_, DD, 1536L*D_);
  transpose_bf16_kernel<<<dim3(D_/32,  D_/32,   L_), 256, 0, stream>>>(Wo, WoT, D_, D_, DD, DD);
  transpose_bf16_kernel<<<dim3(DFF_/32, D_/32,  L_), 256, 0, stream>>>(W1, W1T, D_, DFF_, (long)D_*DFF_, (long)D_*DFF_);
  transpose_bf16_kernel<<<dim3(DFF_/32, DFF_/32,L_), 256, 0, stream>>>(Wm, WmT, DFF_, DFF_, (long)DFF_*DFF_, (long)DFF_*DFF_);
  transpose_bf16_kernel<<<dim3(D_/32,  DFF_/32, L_), 256, 0, stream>>>(W2, W2T, DFF_, D_, (long)D_*DFF_, (long)D_*DFF_);
  transpose_bf16_kernel<<<dim3(V_/32,  D_/32,   1 ), 256, 0, stream>>>(Wout, WoutT, D_, V_, (long)D_*V_, (long)D_*V_);
  concat_bias_kernel<<<(L_*1536)/256, 256, 0, stream>>>(bq, bk, bv, bqkv);

  embed_kernel<<<M, 128, 0, stream>>>(x, tok, pos, h);

  for (int l = 0; l < L_; ++l) {
    ln_kernel<<<M/4, 256, 0, stream>>>(h, g1 + l * D_, be1 + l * D_, y16);
    gemm64_kernel<4,false><<<dim3(M/64, 1536/BN), 256, 0, stream>>>(
        y16, WqkvT + (size_t)l * 1536 * D_, bqkv + l * 1536, nullptr,
        qb16, kb16, vt16, M, 1536, D_);
    attn_kernel<<<dim3(S_/16, H_, B_), 512, 0, stream>>>(qb16, kb16, vt16, ob16);
    gemm64_kernel<0,true><<<dim3(M/64, D_/BN), 256, 0, stream>>>(
        ob16, WoT + (size_t)l * DD, bo + l * D_, h, h, nullptr, nullptr, M, D_, D_);
    ln_kernel<<<M/4, 256, 0, stream>>>(h, g2 + l * D_, be2 + l * D_, y16);
    gemm_bf16_kernel<1,true,false,true><<<dim3((M/BM) * (DFF_/BN)), 256, 0, stream>>>(
        y16, W1T + (size_t)l * D_ * DFF_, b1 + l * DFF_, nullptr, f1b, nullptr, nullptr, M, DFF_, D_);
    gemm_bf16_kernel<1,true,false,true><<<dim3((M/BM) * (DFF_/BN)), 256, 0, stream>>>(
        f1b, WmT + (size_t)l * DFF_ * DFF_, bm + l * DFF_, nullptr, f2b, nullptr, nullptr, M, DFF_, DFF_);
    gemm64_kernel<3,true><<<dim3(M/64, D_/BN), 256, 0, stream>>>(
        f2b, W2T + (size_t)l * D_ * DFF_, b2 + l * D_, h, h, h16, nullptr, M, D_, DFF_);
  }
  gemm_head_kernel<<<dim3((M/256) * (V_/256)), 512, 0, stream>>>(
      h16, WoutT, bout, logits, M, V_, D_);
}

// Round 12
// 1170.368 us; speedup vs baseline: 1.1004x; 1.0350x over previous
//
#include <hip/hip_runtime.h>
#include <hip/hip_bf16.h>
#include <math.h>

#define B_ 4
#define S_ 1024
#define D_ 512
#define H_ 8
#define L_ 4
#define DFF_ 2048
#define V_ 32000
#define DK_ 64
#define KTOP 307
#define SRS 1048    // score row stride in u16 elems

using bf16x8 = __attribute__((ext_vector_type(8))) __bf16;
using bf16x4 = __attribute__((ext_vector_type(4))) __bf16;
using bf16x2 = __attribute__((ext_vector_type(2))) __bf16;
using f32x4v = __attribute__((ext_vector_type(4))) float;

__device__ __forceinline__ void gload_lds16(const __bf16* g, __bf16* l) {
  __builtin_amdgcn_global_load_lds(
      (const __attribute__((address_space(1))) void*)g,
      (__attribute__((address_space(3))) void*)l, 16, 0, 0);
}

// fp32 -> bf16 bits (RNE), as low 16 of u32
__device__ __forceinline__ unsigned int f32_to_bf16_bits(float s) {
  unsigned int x = __float_as_uint(s);
  return (x + 0x7FFFu + ((x >> 16) & 1u)) >> 16;
}

// ---- DPP 16-lane reductions (teams aligned to DPP rows) ----
__device__ __forceinline__ int red16i(int x) {
  x += __builtin_amdgcn_update_dpp(0, x, 0xB1, 0xF, 0xF, true);
  x += __builtin_amdgcn_update_dpp(0, x, 0x4E, 0xF, 0xF, true);
  x += __builtin_amdgcn_update_dpp(0, x, 0x141, 0xF, 0xF, true);
  x += __builtin_amdgcn_update_dpp(0, x, 0x140, 0xF, 0xF, true);
  return x;
}
__device__ __forceinline__ unsigned int red16umax(unsigned int x) {
  unsigned int t;
  t = (unsigned int)__builtin_amdgcn_update_dpp(0, (int)x, 0xB1, 0xF, 0xF, true);  x = t > x ? t : x;
  t = (unsigned int)__builtin_amdgcn_update_dpp(0, (int)x, 0x4E, 0xF, 0xF, true);  x = t > x ? t : x;
  t = (unsigned int)__builtin_amdgcn_update_dpp(0, (int)x, 0x141, 0xF, 0xF, true); x = t > x ? t : x;
  t = (unsigned int)__builtin_amdgcn_update_dpp(0, (int)x, 0x140, 0xF, 0xF, true); x = t > x ? t : x;
  return x;
}
__device__ __forceinline__ float red16f(float x) {
  x += __int_as_float(__builtin_amdgcn_update_dpp(0, __float_as_int(x), 0xB1, 0xF, 0xF, true));
  x += __int_as_float(__builtin_amdgcn_update_dpp(0, __float_as_int(x), 0x4E, 0xF, 0xF, true));
  x += __int_as_float(__builtin_amdgcn_update_dpp(0, __float_as_int(x), 0x141, 0xF, 0xF, true));
  x += __int_as_float(__builtin_amdgcn_update_dpp(0, __float_as_int(x), 0x140, 0xF, 0xF, true));
  return x;
}
__device__ __forceinline__ float red64f(float x) {
  x = red16f(x);
  x += __shfl_xor(x, 16, 64);
  x += __shfl_xor(x, 32, 64);
  return x;
}

// ---- st_16x32-swizzled [R][64] bf16 LDS helpers; XOR (row&7)<<3 elements ----
template<int ROWS>
__device__ __forceinline__ void stage_tile4(const __bf16* src, int Kd, __bf16* lds,
                                            int w, int lane) {
  #pragma unroll
  for (int c = 0; c < ROWS / 32; ++c) {
    int rblk = (c * 4 + w) * 8;
    int row = rblk + (lane >> 3);
    int col = (lane & 7) * 8;
    int scol = col ^ ((row & 7) << 3);
    gload_lds16(src + (size_t)row * Kd + scol, lds + rblk * 64);
  }
}
__device__ __forceinline__ void stage_half8(const __bf16* src, int Kd, __bf16* lds,
                                            int w, int lane) {
  #pragma unroll
  for (int c = 0; c < 2; ++c) {
    int rblk = (c * 8 + w) * 8;
    int row = rblk + (lane >> 3);
    int col = (lane & 7) * 8;
    int scol = col ^ ((row & 7) << 3);
    gload_lds16(src + (size_t)row * Kd + scol, lds + rblk * 64);
  }
}
__device__ __forceinline__ bf16x8 lds_frag64(const __bf16* lds, int row, int colbase) {
  int col = colbase ^ ((row & 7) << 3);
  return *reinterpret_cast<const bf16x8*>(lds + row * 64 + col);
}

// ---------------- embedding ----------------
__global__ void embed_kernel(const int* __restrict__ x, const float* __restrict__ tok,
                             const float* __restrict__ pos, float* __restrict__ h) {
  int row = blockIdx.x;
  int t = threadIdx.x;
  int s = row & (S_ - 1);
  int token = x[row];
  const float4* t4 = reinterpret_cast<const float4*>(tok + (size_t)token * D_);
  const float4* p4 = reinterpret_cast<const float4*>(pos + (size_t)s * D_);
  float4 a = t4[t];
  float4 b = p4[t];
  a.x += b.x; a.y += b.y; a.z += b.z; a.w += b.w;
  reinterpret_cast<float4*>(h + (size_t)row * D_)[t] = a;
}

// ---------------- layernorm: one WAVE per row, no LDS/barrier ----------------
__global__ __launch_bounds__(256)
void ln_kernel(const float* __restrict__ xin, const float* __restrict__ g,
               const float* __restrict__ bta, __bf16* __restrict__ y) {
  int w = threadIdx.x >> 6, lane = threadIdx.x & 63;
  int row = blockIdx.x * 4 + w;
  const float4* x4 = reinterpret_cast<const float4*>(xin + (size_t)row * D_);
  float4 a = x4[lane * 2];
  float4 b = x4[lane * 2 + 1];
  float s = a.x + a.y + a.z + a.w + b.x + b.y + b.z + b.w;
  float q = a.x * a.x + a.y * a.y + a.z * a.z + a.w * a.w
          + b.x * b.x + b.y * b.y + b.z * b.z + b.w * b.w;
  s = red64f(s);
  q = red64f(q);
  float mu = s * (1.0f / D_);
  float var = q * (1.0f / D_) - mu * mu;
  float rstd = rsqrtf(var + 1e-5f);
  const float4* g4 = reinterpret_cast<const float4*>(g);
  const float4* b4 = reinterpret_cast<const float4*>(bta);
  float4 g0 = g4[lane * 2], g1 = g4[lane * 2 + 1];
  float4 e0 = b4[lane * 2], e1 = b4[lane * 2 + 1];
  bf16x8 o8;
  o8[0] = (__bf16)((a.x - mu) * rstd * g0.x + e0.x);
  o8[1] = (__bf16)((a.y - mu) * rstd * g0.y + e0.y);
  o8[2] = (__bf16)((a.z - mu) * rstd * g0.z + e0.z);
  o8[3] = (__bf16)((a.w - mu) * rstd * g0.w + e0.w);
  o8[4] = (__bf16)((b.x - mu) * rstd * g1.x + e1.x);
  o8[5] = (__bf16)((b.y - mu) * rstd * g1.y + e1.y);
  o8[6] = (__bf16)((b.z - mu) * rstd * g1.z + e1.z);
  o8[7] = (__bf16)((b.w - mu) * rstd * g1.w + e1.w);
  *reinterpret_cast<bf16x8*>(y + (size_t)row * D_ + lane * 8) = o8;
}

// ------------- transpose fp32 [Kd][N] -> bf16 [N][Kd] -------------
__global__ void transpose_bf16_kernel(const float* __restrict__ in, __bf16* __restrict__ out,
                                      int Kd, int N, long in_bstride, long out_bstride) {
  __shared__ float tile[32][33];
  const float* ib = in + (size_t)blockIdx.z * in_bstride;
  __bf16* ob = out + (size_t)blockIdx.z * out_bstride;
  int n0 = blockIdx.x * 32, k0 = blockIdx.y * 32;
  int tx = threadIdx.x & 31, ty = threadIdx.x >> 5;
  #pragma unroll
  for (int i = 0; i < 4; ++i)
    tile[ty + i * 8][tx] = ib[(size_t)(k0 + ty + i * 8) * N + n0 + tx];
  __syncthreads();
  #pragma unroll
  for (int i = 0; i < 4; ++i)
    ob[(size_t)(n0 + ty + i * 8) * Kd + k0 + tx] = (__bf16)tile[tx][ty + i * 8];
}

// ---------------- bias concat for fused QKV ----------------
__global__ void concat_bias_kernel(const float* __restrict__ bq, const float* __restrict__ bk,
                                   const float* __restrict__ bv, float* __restrict__ bqkv) {
  int i = blockIdx.x * 256 + threadIdx.x;
  int l = i / 1536, c = i - l * 1536;
  float v = (c < 512) ? bq[l * 512 + c]
          : (c < 1024) ? bk[l * 512 + c - 512]
                       : bv[l * 512 + c - 1024];
  bqkv[i] = v;
}

// ---------------- bf16 MFMA GEMM, 128x128 tile, BK=64, swizzled LDS (Wm) ----------------
#define BM 128
#define BN 128
#define BK 64

template<int OMODE, bool GELU_ACT, bool RES, bool SWZ>
__global__ __launch_bounds__(256)
void gemm_bf16_kernel(const __bf16* __restrict__ A, const __bf16* __restrict__ WT,
                      const float* __restrict__ bias, const float* __restrict__ res,
                      void* __restrict__ outp, void* __restrict__ outp2, void* __restrict__ outp3,
                      int M, int N, int Kd) {
  __shared__ __bf16 As[BM * BK];
  __shared__ __bf16 Ws[BN * BK];
  int tid = threadIdx.x;
  int lane = tid & 63, w = tid >> 6;
  int wr = w >> 1, wc = w & 1;
  int lr = lane & 15, lg = lane >> 4;
  int bx, by;
  if (SWZ) {
    int lid = blockIdx.x;
    int cpx = gridDim.x >> 3;
    int swz = (lid & 7) * cpx + (lid >> 3);
    int gx = M >> 7;
    bx = swz % gx;
    by = swz / gx;
  } else {
    bx = blockIdx.x; by = blockIdx.y;
  }
  int row0 = bx * BM, col0 = by * BN;

  const __bf16* Abase = A + (size_t)row0 * Kd;
  const __bf16* Wbase = WT + (size_t)col0 * Kd;

  f32x4v acc[4][4];
  #pragma unroll
  for (int i = 0; i < 4; ++i)
    #pragma unroll
    for (int j = 0; j < 4; ++j)
      #pragma unroll
      for (int e = 0; e < 4; ++e) acc[i][j][e] = 0.0f;

  for (int k0 = 0; k0 < Kd; k0 += BK) {
    stage_tile4<128>(Abase + k0, Kd, As, w, lane);
    stage_tile4<128>(Wbase + k0, Kd, Ws, w, lane);
    __syncthreads();
    bf16x8 af[4][2], bfr[4][2];
    #pragma unroll
    for (int mr = 0; mr < 4; ++mr)
      #pragma unroll
      for (int kk = 0; kk < 2; ++kk)
        af[mr][kk] = lds_frag64(As, wr * 64 + mr * 16 + lr, kk * 32 + lg * 8);
    #pragma unroll
    for (int nc = 0; nc < 4; ++nc)
      #pragma unroll
      for (int kk = 0; kk < 2; ++kk)
        bfr[nc][kk] = lds_frag64(Ws, wc * 64 + nc * 16 + lr, kk * 32 + lg * 8);
    __builtin_amdgcn_s_setprio(1);
    #pragma unroll
    for (int mr = 0; mr < 4; ++mr)
      #pragma unroll
      for (int nc = 0; nc < 4; ++nc) {
        acc[mr][nc] = __builtin_amdgcn_mfma_f32_16x16x32_bf16(af[mr][0], bfr[nc][0], acc[mr][nc], 0, 0, 0);
        acc[mr][nc] = __builtin_amdgcn_mfma_f32_16x16x32_bf16(af[mr][1], bfr[nc][1], acc[mr][nc], 0, 0, 0);
      }
    __builtin_amdgcn_s_setprio(0);
    __syncthreads();
  }

  #pragma unroll
  for (int mr = 0; mr < 4; ++mr) {
    #pragma unroll
    for (int nc = 0; nc < 4; ++nc) {
      int c = col0 + wc * 64 + nc * 16 + lr;
      int rb = row0 + wr * 64 + mr * 16 + lg * 4;
      float vv[4];
      #pragma unroll
      for (int j = 0; j < 4; ++j) {
        float t = acc[mr][nc][j] + bias[c];
        if (RES) t += res[(size_t)(rb + j) * N + c];
        if (GELU_ACT) t = 0.5f * t * (1.0f + erff(t * 0.70710678118654752f));
        vv[j] = t;
      }
      if (OMODE == 0) {
        float* out = (float*)outp;
        #pragma unroll
        for (int j = 0; j < 4; ++j) out[(size_t)(rb + j) * N + c] = vv[j];
      } else if (OMODE == 1) {
        __bf16* out = (__bf16*)outp;
        #pragma unroll
        for (int j = 0; j < 4; ++j) out[(size_t)(rb + j) * N + c] = (__bf16)vv[j];
      } else if (OMODE == 3) {
        float* out = (float*)outp;
        __bf16* out2 = (__bf16*)outp2;
        #pragma unroll
        for (int j = 0; j < 4; ++j) {
          out[(size_t)(rb + j) * N + c] = vv[j];
          out2[(size_t)(rb + j) * N + c] = (__bf16)vv[j];
        }
      }
    }
  }
}

// ----- MTILE x 128 GEMM, BK=64: MTILE in {32,64}. 4 waves 2x2; each wave (MTILE/2) x 64 -----
// OMODE: 0 fp32 (+res) | 1 bf16 (+gelu) | 3 fp32+bf16 dual (+res) | 4 fused-QKV
template<int MTILE, int OMODE, bool GELU_ACT, bool RES>
__global__ __launch_bounds__(256)
void gemm_n128_kernel(const __bf16* __restrict__ A, const __bf16* __restrict__ WT,
                      const float* __restrict__ bias, const float* __restrict__ res,
                      void* __restrict__ outp, void* __restrict__ outp2, void* __restrict__ outp3,
                      int M, int N, int Kd) {
  constexpr int FR = MTILE / 32;          // 16-row fragments per wave
  __shared__ __bf16 As[MTILE * BK];
  __shared__ __bf16 Ws[BN * BK];
  int tid = threadIdx.x;
  int lane = tid & 63, w = tid >> 6;
  int wr = w >> 1, wc = w & 1;
  int lr = lane & 15, lg = lane >> 4;
  int row0 = blockIdx.x * MTILE, col0 = blockIdx.y * BN;

  const __bf16* Abase = A + (size_t)row0 * Kd;
  const __bf16* Wbase = WT + (size_t)col0 * Kd;

  f32x4v acc[FR][4];
  #pragma unroll
  for (int i = 0; i < FR; ++i)
    #pragma unroll
    for (int j = 0; j < 4; ++j)
      #pragma unroll
      for (int e = 0; e < 4; ++e) acc[i][j][e] = 0.0f;

  for (int k0 = 0; k0 < Kd; k0 += BK) {
    stage_tile4<MTILE>(Abase + k0, Kd, As, w, lane);
    stage_tile4<128>(Wbase + k0, Kd, Ws, w, lane);
    __syncthreads();
    bf16x8 af[FR][2], bfr[4][2];
    #pragma unroll
    for (int mr = 0; mr < FR; ++mr)
      #pragma unroll
      for (int kk = 0; kk < 2; ++kk)
        af[mr][kk] = lds_frag64(As, wr * (16 * FR) + mr * 16 + lr, kk * 32 + lg * 8);
    #pragma unroll
    for (int nc = 0; nc < 4; ++nc)
      #pragma unroll
      for (int kk = 0; kk < 2; ++kk)
        bfr[nc][kk] = lds_frag64(Ws, wc * 64 + nc * 16 + lr, kk * 32 + lg * 8);
    __builtin_amdgcn_s_setprio(1);
    #pragma unroll
    for (int mr = 0; mr < FR; ++mr)
      #pragma unroll
      for (int nc = 0; nc < 4; ++nc) {
        acc[mr][nc] = __builtin_amdgcn_mfma_f32_16x16x32_bf16(af[mr][0], bfr[nc][0], acc[mr][nc], 0, 0, 0);
        acc[mr][nc] = __builtin_amdgcn_mfma_f32_16x16x32_bf16(af[mr][1], bfr[nc][1], acc[mr][nc], 0, 0, 0);
      }
    __builtin_amdgcn_s_setprio(0);
    __syncthreads();
  }

  #pragma unroll
  for (int mr = 0; mr < FR; ++mr) {
    #pragma unroll
    for (int nc = 0; nc < 4; ++nc) {
      int c = col0 + wc * 64 + nc * 16 + lr;
      int rb = row0 + wr * (16 * FR) + mr * 16 + lg * 4;
      float vv[4];
      #pragma unroll
      for (int j = 0; j < 4; ++j) {
        float t = acc[mr][nc][j] + bias[c];
        if (RES) t += res[(size_t)(rb + j) * N + c];
        if (GELU_ACT) t = 0.5f * t * (1.0f + erff(t * 0.70710678118654752f));
        vv[j] = t;
      }
      if (OMODE == 0) {
        float* out = (float*)outp;
        #pragma unroll
        for (int j = 0; j < 4; ++j) out[(size_t)(rb + j) * N + c] = vv[j];
      } else if (OMODE == 1) {
        __bf16* out = (__bf16*)outp;
        #pragma unroll
        for (int j = 0; j < 4; ++j) out[(size_t)(rb + j) * N + c] = (__bf16)vv[j];
      } else if (OMODE == 3) {
        float* out = (float*)outp;
        __bf16* out2 = (__bf16*)outp2;
        #pragma unroll
        for (int j = 0; j < 4; ++j) {
          out[(size_t)(rb + j) * N + c] = vv[j];
          out2[(size_t)(rb + j) * N + c] = (__bf16)vv[j];
        }
      } else {  // OMODE 4: fused QKV epilogue
        if (col0 < 512) {
          __bf16* out = (__bf16*)outp;
          #pragma unroll
          for (int j = 0; j < 4; ++j) out[(size_t)(rb + j) * D_ + c] = (__bf16)vv[j];
        } else if (col0 < 1024) {
          __bf16* out = (__bf16*)outp2;
          #pragma unroll
          for (int j = 0; j < 4; ++j) out[(size_t)(rb + j) * D_ + (c - 512)] = (__bf16)vv[j];
        } else {
          __bf16* out = (__bf16*)outp3;   // vt [B][D][S]
          int b = rb >> 10, s0 = rb & (S_ - 1);
          bf16x4 pk;
          #pragma unroll
          for (int j = 0; j < 4; ++j) pk[j] = (__bf16)vv[j];
          *reinterpret_cast<bf16x4*>(&out[((size_t)b * D_ + (c - 1024)) * S_ + s0]) = pk;
        }
      }
    }
  }
}

// ------- head GEMM: 256x256 tile, 8 waves, BK=64, double-buffered counted-vmcnt pipeline -------
__global__ __launch_bounds__(512)
void gemm_head_kernel(const __bf16* __restrict__ A, const __bf16* __restrict__ WT,
                      const float* __restrict__ bias, float* __restrict__ out,
                      int M, int N, int Kd) {
  __shared__ __bf16 lds[2][2][256 * 64];   // 128 KB
  const int tid = threadIdx.x;
  const int lane = tid & 63, w = tid >> 6;
  const int wr = w >> 2, wc = w & 3;
  const int lr = lane & 15, lg = lane >> 4;

  int lid = blockIdx.x;
  int cpx = gridDim.x >> 3;
  int swz = (lid & 7) * cpx + (lid >> 3);
  int gx = M >> 8;
  int bx = swz % gx, by = swz / gx;
  int row0 = bx * 256, col0 = by * 256;

  const __bf16* Asrc = A + (size_t)row0 * Kd;
  const __bf16* Bsrc = WT + (size_t)col0 * Kd;

  f32x4v acc[8][4];
  #pragma unroll
  for (int i = 0; i < 8; ++i)
    #pragma unroll
    for (int j = 0; j < 4; ++j)
      #pragma unroll
      for (int e = 0; e < 4; ++e) acc[i][j][e] = 0.0f;

  const int NT = Kd / 64;
  stage_half8(Asrc,                      Kd, &lds[0][0][0],    w, lane);
  stage_half8(Asrc + (size_t)128 * Kd,   Kd, &lds[0][0][8192], w, lane);
  stage_half8(Bsrc,                      Kd, &lds[0][1][0],    w, lane);
  stage_half8(Bsrc + (size_t)128 * Kd,   Kd, &lds[0][1][8192], w, lane);

  for (int t = 0; t < NT; ++t) {
    int cur = t & 1, nxt = cur ^ 1;
    int k1 = (t + 1) * 64;
    const __bf16* Ab = &lds[cur][0][0];
    const __bf16* Bb = &lds[cur][1][0];
    bf16x8 bfr[4][2];
    #pragma unroll
    for (int p = 0; p < 4; ++p) {
      if (t < NT - 1) {
        const __bf16* s;
        __bf16* d;
        if (p == 0)      { s = Asrc + k1;                    d = &lds[nxt][0][0]; }
        else if (p == 1) { s = Asrc + (size_t)128 * Kd + k1; d = &lds[nxt][0][8192]; }
        else if (p == 2) { s = Bsrc + k1;                    d = &lds[nxt][1][0]; }
        else             { s = Bsrc + (size_t)128 * Kd + k1; d = &lds[nxt][1][8192]; }
        stage_half8(s, Kd, d, w, lane);
      }
      if (p == 0) {
        if (t < NT - 1) asm volatile("s_waitcnt vmcnt(2)" ::: "memory");
        else            asm volatile("s_waitcnt vmcnt(0)" ::: "memory");
        __builtin_amdgcn_s_barrier();
        #pragma unroll
        for (int nn = 0; nn < 4; ++nn)
          #pragma unroll
          for (int kk = 0; kk < 2; ++kk)
            bfr[nn][kk] = lds_frag64(Bb, wc * 64 + nn * 16 + lr, kk * 32 + lg * 8);
      }
      bf16x8 af[2][2];
      #pragma unroll
      for (int mm = 0; mm < 2; ++mm)
        #pragma unroll
        for (int kk = 0; kk < 2; ++kk)
          af[mm][kk] = lds_frag64(Ab, wr * 128 + p * 32 + mm * 16 + lr, kk * 32 + lg * 8);
      asm volatile("s_waitcnt lgkmcnt(0)" ::: "memory");
      __builtin_amdgcn_sched_barrier(0);
      __builtin_amdgcn_s_setprio(1);
      #pragma unroll
      for (int mm = 0; mm < 2; ++mm)
        #pragma unroll
        for (int nn = 0; nn < 4; ++nn) {
          acc[p * 2 + mm][nn] = __builtin_amdgcn_mfma_f32_16x16x32_bf16(af[mm][0], bfr[nn][0], acc[p * 2 + mm][nn], 0, 0, 0);
          acc[p * 2 + mm][nn] = __builtin_amdgcn_mfma_f32_16x16x32_bf16(af[mm][1], bfr[nn][1], acc[p * 2 + mm][nn], 0, 0, 0);
        }
      __builtin_amdgcn_s_setprio(0);
    }
    __builtin_amdgcn_s_barrier();
  }

  #pragma unroll
  for (int mg = 0; mg < 8; ++mg) {
    #pragma unroll
    for (int nn = 0; nn < 4; ++nn) {
      int c = col0 + wc * 64 + nn * 16 + lr;
      int rb = row0 + wr * 128 + mg * 16 + lg * 4;
      float b = bias[c];
      #pragma unroll
      for (int j = 0; j < 4; ++j)
        out[(size_t)(rb + j) * N + c] = acc[mg][nn][j] + b;
    }
  }
}

// ---------------- fused attention: 8 waves, 16 q-rows, u16 scores ----------------
__global__ __launch_bounds__(512)
void attn_kernel(const __bf16* __restrict__ qm, const __bf16* __restrict__ km,
                 const __bf16* __restrict__ vt, __bf16* __restrict__ o) {
  __shared__ unsigned short sc16[16][SRS];
  __shared__ float ored[4][64][4];   // kt-half partials from waves 4-7
  __shared__ float rs[16];           // reciprocal row sums
  const int q0 = blockIdx.x * 16;
  const int hh = blockIdx.y;
  const int bb = blockIdx.z;
  const int tid = threadIdx.x;
  const int lane = tid & 63, w = tid >> 6;   // 8 waves
  const int lr = lane & 15, lg = lane >> 4;

  const __bf16* qrow = qm + ((size_t)(bb * S_ + q0 + lr)) * D_ + hh * DK_;
  bf16x8 qf0 = *reinterpret_cast<const bf16x8*>(qrow + lg * 8);
  bf16x8 qf1 = *reinterpret_cast<const bf16x8*>(qrow + 32 + lg * 8);

  // ---- phase 1: scores via MFMA; 8 waves cover 128 keys per iteration ----
  const __bf16* kbase = km + ((size_t)bb * S_) * D_ + hh * DK_;
  #pragma unroll
  for (int kt = 0; kt < 8; ++kt) {
    int key0 = kt * 128 + w * 16;
    const __bf16* krow = kbase + (size_t)(key0 + lr) * D_;
    bf16x8 kf0 = *reinterpret_cast<const bf16x8*>(krow + lg * 8);
    bf16x8 kf1 = *reinterpret_cast<const bf16x8*>(krow + 32 + lg * 8);
    f32x4v d = {0.0f, 0.0f, 0.0f, 0.0f};
    __builtin_amdgcn_s_setprio(1);
    d = __builtin_amdgcn_mfma_f32_16x16x32_bf16(qf0, kf0, d, 0, 0, 0);
    d = __builtin_amdgcn_mfma_f32_16x16x32_bf16(qf1, kf1, d, 0, 0, 0);
    __builtin_amdgcn_s_setprio(0);
    #pragma unroll
    for (int j = 0; j < 4; ++j) {
      unsigned int u = f32_to_bf16_bits(d[j] * 0.125f);
      u = (u & 0x8000u) ? (~u & 0xFFFFu) : (u | 0x8000u);
      sc16[lg * 4 + j][key0 + lr] = (unsigned short)u;
    }
  }
  __syncthreads();

  // ---- phase 2: 32 threads per row (half-wave teams); 16-bit binary search ----
  {
    int r = tid >> 5, tc = tid & 31;
    const unsigned int* srow = reinterpret_cast<const unsigned int*>(&sc16[r][0]);
    unsigned int wv[16];   // 32 u16 values packed
    #pragma unroll
    for (int g = 0; g < 4; ++g) {
      uint4 t4 = *reinterpret_cast<const uint4*>(&srow[g * 128 + tc * 4]);
      wv[g * 4 + 0] = t4.x; wv[g * 4 + 1] = t4.y;
      wv[g * 4 + 2] = t4.z; wv[g * 4 + 3] = t4.w;
    }
    unsigned int umax = 0;
    #pragma unroll
    for (int i = 0; i < 16; ++i) {
      unsigned int a = wv[i] & 0xFFFFu, b = wv[i] >> 16;
      unsigned int mx = a > b ? a : b;
      umax = mx > umax ? mx : umax;
    }
    umax = red16umax(umax);
    {
      unsigned int other = (unsigned int)__shfl_xor((int)umax, 16, 32);
      umax = other > umax ? other : umax;
    }
    unsigned int lo = 0;
    for (int bit = 15; bit >= 0; --bit) {
      unsigned int cs = (lo | (1u << bit)) << 16;
      int cnt = 0;
      #pragma unroll
      for (int i = 0; i < 16; ++i) {
        cnt += ((wv[i] << 16) >= cs) ? 1 : 0;
        cnt += (wv[i] >= cs) ? 1 : 0;
      }
      cnt = red16i(cnt);
      cnt += __shfl_xor(cnt, 16, 32);
      if (cnt >= KTOP) lo |= (1u << bit);
    }
    unsigned int um = (umax & 0x8000u) ? (umax ^ 0x8000u) : (~umax & 0xFFFFu);
    float mval = __uint_as_float(um << 16);

    __bf16* P = reinterpret_cast<__bf16*>(&sc16[r][0]);
    float lsum = 0.0f;
    #pragma unroll
    for (int g = 0; g < 4; ++g) {
      bf16x8 pk;
      #pragma unroll
      for (int e = 0; e < 8; ++e) {
        unsigned int wrd = wv[g * 4 + (e >> 1)];
        unsigned int u = (e & 1) ? (wrd >> 16) : (wrd & 0xFFFFu);
        float p = 0.0f;
        if (u >= lo) {
          unsigned int ub = (u & 0x8000u) ? (u ^ 0x8000u) : (~u & 0xFFFFu);
          p = __expf(__uint_as_float(ub << 16) - mval);
        }
        pk[e] = (__bf16)p;
        lsum += (float)pk[e];
      }
      *reinterpret_cast<bf16x8*>(&P[tc * 8 + g * 256]) = pk;
    }
    lsum = red16f(lsum);
    lsum += __shfl_xor(lsum, 16, 32);
    if (tc == 0) rs[r] = 1.0f / lsum;
  }
  __syncthreads();

  // ---- phase 3: PV split across wave pairs (kt halves), LDS reduce ----
  {
    const __bf16* P0 = reinterpret_cast<const __bf16*>(&sc16[0][0]);
    int wc4 = w & 3;      // column group (16 cols each)
    int half = w >> 2;    // kt half
    const __bf16* vbase = vt + ((size_t)bb * D_ + hh * DK_ + wc4 * 16 + lr) * S_;
    const __bf16* prow = P0 + (size_t)lr * SRS;
    f32x4v oacc = {0.0f, 0.0f, 0.0f, 0.0f};
    int kt0 = half * 16;
    __builtin_amdgcn_s_setprio(1);
    #pragma unroll
    for (int kk = 0; kk < 16; ++kk) {
      int kt = kt0 + kk;
      bf16x8 a = *reinterpret_cast<const bf16x8*>(prow + kt * 32 + lg * 8);
      bf16x8 b = *reinterpret_cast<const bf16x8*>(vbase + kt * 32 + lg * 8);
      oacc = __builtin_amdgcn_mfma_f32_16x16x32_bf16(a, b, oacc, 0, 0, 0);
    }
    __builtin_amdgcn_s_setprio(0);
    if (half == 1) {
      float4 st;
      st.x = oacc[0]; st.y = oacc[1]; st.z = oacc[2]; st.w = oacc[3];
      *reinterpret_cast<float4*>(&ored[wc4][lane][0]) = st;
    }
    __syncthreads();
    if (half == 0) {
      float4 pv = *reinterpret_cast<const float4*>(&ored[wc4][lane][0]);
      oacc[0] += pv.x; oacc[1] += pv.y; oacc[2] += pv.z; oacc[3] += pv.w;
      #pragma unroll
      for (int j = 0; j < 4; ++j) {
        int qr = lg * 4 + j;
        float ov = oacc[j] * rs[qr];
        o[((size_t)(bb * S_ + q0 + qr)) * D_ + hh * DK_ + wc4 * 16 + lr] = (__bf16)ov;
      }
    }
  }
}

extern "C" void kernel_launch(void* const* d_in, const int* in_sizes, int n_in,
                              void* d_out, int out_size, void* d_ws, size_t ws_size,
                              hipStream_t stream) {
  (void)in_sizes; (void)n_in; (void)out_size; (void)ws_size;
  const int*   x    = (const int*)d_in[0];
  const float* tok  = (const float*)d_in[1];
  const float* pos  = (const float*)d_in[2];
  const float* Wq   = (const float*)d_in[3];
  const float* bq   = (const float*)d_in[4];
  const float* Wk   = (const float*)d_in[5];
  const float* bk   = (const float*)d_in[6];
  const float* Wv   = (const float*)d_in[7];
  const float* bv   = (const float*)d_in[8];
  const float* Wo   = (const float*)d_in[9];
  const float* bo   = (const float*)d_in[10];
  const float* g1   = (const float*)d_in[11];
  const float* be1  = (const float*)d_in[12];
  const float* g2   = (const float*)d_in[13];
  const float* be2  = (const float*)d_in[14];
  const float* W1   = (const float*)d_in[15];
  const float* b1   = (const float*)d_in[16];
  const float* Wm   = (const float*)d_in[17];
  const float* bm   = (const float*)d_in[18];
  const float* W2   = (const float*)d_in[19];
  const float* b2   = (const float*)d_in[20];
  const float* Wout = (const float*)d_in[21];
  const float* bout = (const float*)d_in[22];
  float* logits = (float*)d_out;

  const int M = B_ * S_;  // 4096
  float* ws = (float*)d_ws;
  float* h    = ws;
  float* bqkv = h + (size_t)M * D_;
  __bf16* y16  = (__bf16*)(bqkv + (size_t)L_ * 1536);
  __bf16* f1b  = y16  + (size_t)M * D_;
  __bf16* f2b  = f1b  + (size_t)M * DFF_;
  __bf16* qb16 = f2b  + (size_t)M * DFF_;
  __bf16* kb16 = qb16 + (size_t)M * D_;
  __bf16* vt16 = kb16 + (size_t)M * D_;
  __bf16* ob16 = vt16 + (size_t)M * D_;
  __bf16* h16  = ob16 + (size_t)M * D_;
  __bf16* WqkvT = h16 + (size_t)M * D_;
  __bf16* WoT  = WqkvT + (size_t)L_ * 1536 * D_;
  __bf16* W1T  = WoT  + (size_t)L_ * D_ * D_;
  __bf16* WmT  = W1T  + (size_t)L_ * D_ * DFF_;
  __bf16* W2T  = WmT  + (size_t)L_ * DFF_ * DFF_;
  __bf16* WoutT = W2T + (size_t)L_ * D_ * DFF_;

  const long DD = (long)D_ * D_;
  transpose_bf16_kernel<<<dim3(D_/32,  D_/32,   L_), 256, 0, stream>>>(Wq, WqkvT,            D_, D_, DD, 1536L*D_);
  transpose_bf16_kernel<<<dim3(D_/32,  D_/32,   L_), 256, 0, stream>>>(Wk, WqkvT + 512*512,  D_, D_, DD, 1536L*D_);
  transpose_bf16_kernel<<<dim3(D_/32,  D_/32,   L_), 256, 0, stream>>>(Wv, WqkvT + 1024*512, D_, D_, DD, 1536L*D_);
  transpose_bf16_kernel<<<dim3(D_/32,  D_/32,   L_), 256, 0, stream>>>(Wo, WoT, D_, D_, DD, DD);
  transpose_bf16_kernel<<<dim3(DFF_/32, D_/32,  L_), 256, 0, stream>>>(W1, W1T, D_, DFF_, (long)D_*DFF_, (long)D_*DFF_);
  transpose_bf16_kernel<<<dim3(DFF_/32, DFF_/32,L_), 256, 0, stream>>>(Wm, WmT, DFF_, DFF_, (long)DFF_*DFF_, (long)DFF_*DFF_);
  transpose_bf16_kernel<<<dim3(D_/32,  DFF_/32, L_), 256, 0, stream>>>(W2, W2T, DFF_, D_, (long)D_*DFF_, (long)D_*DFF_);
  transpose_bf16_kernel<<<dim3(V_/32,  D_/32,   1 ), 256, 0, stream>>>(Wout, WoutT, D_, V_, (long)D_*V_, (long)D_*V_);
  concat_bias_kernel<<<(L_*1536)/256, 256, 0, stream>>>(bq, bk, bv, bqkv);

  embed_kernel<<<M, 128, 0, stream>>>(x, tok, pos, h);

  for (int l = 0; l < L_; ++l) {
    ln_kernel<<<M/4, 256, 0, stream>>>(h, g1 + l * D_, be1 + l * D_, y16);
    gemm_n128_kernel<64,4,false,false><<<dim3(M/64, 1536/BN), 256, 0, stream>>>(
        y16, WqkvT + (size_t)l * 1536 * D_, bqkv + l * 1536, nullptr,
        qb16, kb16, vt16, M, 1536, D_);
    attn_kernel<<<dim3(S_/16, H_, B_), 512, 0, stream>>>(qb16, kb16, vt16, ob16);
    gemm_n128_kernel<32,0,false,true><<<dim3(M/32, D_/BN), 256, 0, stream>>>(
        ob16, WoT + (size_t)l * DD, bo + l * D_, h, h, nullptr, nullptr, M, D_, D_);
    ln_kernel<<<M/4, 256, 0, stream>>>(h, g2 + l * D_, be2 + l * D_, y16);
    gemm_n128_kernel<64,1,true,false><<<dim3(M/64, DFF_/BN), 256, 0, stream>>>(
        y16, W1T + (size_t)l * D_ * DFF_, b1 + l * DFF_, nullptr, f1b, nullptr, nullptr, M, DFF_, D_);
    gemm_bf16_kernel<1,true,false,true><<<dim3((M/BM) * (DFF_/BN)), 256, 0, stream>>>(
        f1b, WmT + (size_t)l * DFF_ * DFF_, bm + l * DFF_, nullptr, f2b, nullptr, nullptr, M, DFF_, DFF_);
    gemm_n128_kernel<32,3,false,true><<<dim3(M/32, D_/BN), 256, 0, stream>>>(
        f2b, W2T + (size_t)l * D_ * DFF_, b2 + l * D_, h, h, h16, nullptr, M, D_, DFF_);
  }
  gemm_head_kernel<<<dim3((M/256) * (V_/256)), 512, 0, stream>>>(
      h16, WoutT, bout, logits, M, V_, D_);
}

// Round 13
// 1167.366 us; speedup vs baseline: 1.1033x; 1.0026x over previous
//
#include <hip/hip_runtime.h>
#include <hip/hip_bf16.h>
#include <math.h>

#define B_ 4
#define S_ 1024
#define D_ 512
#define H_ 8
#define L_ 4
#define DFF_ 2048
#define V_ 32000
#define DK_ 64
#define KTOP 307
#define SRS 1048    // score row stride in u16 elems

using bf16x8 = __attribute__((ext_vector_type(8))) __bf16;
using bf16x4 = __attribute__((ext_vector_type(4))) __bf16;
using bf16x2 = __attribute__((ext_vector_type(2))) __bf16;
using f32x4v = __attribute__((ext_vector_type(4))) float;

__device__ __forceinline__ void gload_lds16(const __bf16* g, __bf16* l) {
  __builtin_amdgcn_global_load_lds(
      (const __attribute__((address_space(1))) void*)g,
      (__attribute__((address_space(3))) void*)l, 16, 0, 0);
}

// fp32 -> bf16 bits (RNE), as low 16 of u32
__device__ __forceinline__ unsigned int f32_to_bf16_bits(float s) {
  unsigned int x = __float_as_uint(s);
  return (x + 0x7FFFu + ((x >> 16) & 1u)) >> 16;
}

// ---- DPP 16-lane reductions (teams aligned to DPP rows) ----
__device__ __forceinline__ int red16i(int x) {
  x += __builtin_amdgcn_update_dpp(0, x, 0xB1, 0xF, 0xF, true);
  x += __builtin_amdgcn_update_dpp(0, x, 0x4E, 0xF, 0xF, true);
  x += __builtin_amdgcn_update_dpp(0, x, 0x141, 0xF, 0xF, true);
  x += __builtin_amdgcn_update_dpp(0, x, 0x140, 0xF, 0xF, true);
  return x;
}
__device__ __forceinline__ unsigned int red16umax(unsigned int x) {
  unsigned int t;
  t = (unsigned int)__builtin_amdgcn_update_dpp(0, (int)x, 0xB1, 0xF, 0xF, true);  x = t > x ? t : x;
  t = (unsigned int)__builtin_amdgcn_update_dpp(0, (int)x, 0x4E, 0xF, 0xF, true);  x = t > x ? t : x;
  t = (unsigned int)__builtin_amdgcn_update_dpp(0, (int)x, 0x141, 0xF, 0xF, true); x = t > x ? t : x;
  t = (unsigned int)__builtin_amdgcn_update_dpp(0, (int)x, 0x140, 0xF, 0xF, true); x = t > x ? t : x;
  return x;
}
__device__ __forceinline__ float red16f(float x) {
  x += __int_as_float(__builtin_amdgcn_update_dpp(0, __float_as_int(x), 0xB1, 0xF, 0xF, true));
  x += __int_as_float(__builtin_amdgcn_update_dpp(0, __float_as_int(x), 0x4E, 0xF, 0xF, true));
  x += __int_as_float(__builtin_amdgcn_update_dpp(0, __float_as_int(x), 0x141, 0xF, 0xF, true));
  x += __int_as_float(__builtin_amdgcn_update_dpp(0, __float_as_int(x), 0x140, 0xF, 0xF, true));
  return x;
}
__device__ __forceinline__ float red64f(float x) {
  x = red16f(x);
  x += __shfl_xor(x, 16, 64);
  x += __shfl_xor(x, 32, 64);
  return x;
}

// ---- st_16x32-swizzled [R][64] bf16 LDS helpers; XOR (row&7)<<3 elements ----
template<int ROWS>
__device__ __forceinline__ void stage_tile4(const __bf16* src, int Kd, __bf16* lds,
                                            int w, int lane) {
  #pragma unroll
  for (int c = 0; c < ROWS / 32; ++c) {
    int rblk = (c * 4 + w) * 8;
    int row = rblk + (lane >> 3);
    int col = (lane & 7) * 8;
    int scol = col ^ ((row & 7) << 3);
    gload_lds16(src + (size_t)row * Kd + scol, lds + rblk * 64);
  }
}
__device__ __forceinline__ void stage_half8(const __bf16* src, int Kd, __bf16* lds,
                                            int w, int lane) {
  #pragma unroll
  for (int c = 0; c < 2; ++c) {
    int rblk = (c * 8 + w) * 8;
    int row = rblk + (lane >> 3);
    int col = (lane & 7) * 8;
    int scol = col ^ ((row & 7) << 3);
    gload_lds16(src + (size_t)row * Kd + scol, lds + rblk * 64);
  }
}
__device__ __forceinline__ bf16x8 lds_frag64(const __bf16* lds, int row, int colbase) {
  int col = colbase ^ ((row & 7) << 3);
  return *reinterpret_cast<const bf16x8*>(lds + row * 64 + col);
}

// ---- bijective XCD swizzle for 1-D grids with nwg % 8 == 0 ----
__device__ __forceinline__ int xcd_swz(int lid, int nwg) {
  int cpx = nwg >> 3;
  return (lid & 7) * cpx + (lid >> 3);
}

// ---------------- embedding ----------------
__global__ void embed_kernel(const int* __restrict__ x, const float* __restrict__ tok,
                             const float* __restrict__ pos, float* __restrict__ h) {
  int row = blockIdx.x;
  int t = threadIdx.x;
  int s = row & (S_ - 1);
  int token = x[row];
  const float4* t4 = reinterpret_cast<const float4*>(tok + (size_t)token * D_);
  const float4* p4 = reinterpret_cast<const float4*>(pos + (size_t)s * D_);
  float4 a = t4[t];
  float4 b = p4[t];
  a.x += b.x; a.y += b.y; a.z += b.z; a.w += b.w;
  reinterpret_cast<float4*>(h + (size_t)row * D_)[t] = a;
}

// ---------------- layernorm: one WAVE per row, no LDS/barrier ----------------
__global__ __launch_bounds__(256)
void ln_kernel(const float* __restrict__ xin, const float* __restrict__ g,
               const float* __restrict__ bta, __bf16* __restrict__ y) {
  int w = threadIdx.x >> 6, lane = threadIdx.x & 63;
  int row = blockIdx.x * 4 + w;
  const float4* x4 = reinterpret_cast<const float4*>(xin + (size_t)row * D_);
  float4 a = x4[lane * 2];
  float4 b = x4[lane * 2 + 1];
  float s = a.x + a.y + a.z + a.w + b.x + b.y + b.z + b.w;
  float q = a.x * a.x + a.y * a.y + a.z * a.z + a.w * a.w
          + b.x * b.x + b.y * b.y + b.z * b.z + b.w * b.w;
  s = red64f(s);
  q = red64f(q);
  float mu = s * (1.0f / D_);
  float var = q * (1.0f / D_) - mu * mu;
  float rstd = rsqrtf(var + 1e-5f);
  const float4* g4 = reinterpret_cast<const float4*>(g);
  const float4* b4 = reinterpret_cast<const float4*>(bta);
  float4 g0 = g4[lane * 2], g1 = g4[lane * 2 + 1];
  float4 e0 = b4[lane * 2], e1 = b4[lane * 2 + 1];
  bf16x8 o8;
  o8[0] = (__bf16)((a.x - mu) * rstd * g0.x + e0.x);
  o8[1] = (__bf16)((a.y - mu) * rstd * g0.y + e0.y);
  o8[2] = (__bf16)((a.z - mu) * rstd * g0.z + e0.z);
  o8[3] = (__bf16)((a.w - mu) * rstd * g0.w + e0.w);
  o8[4] = (__bf16)((b.x - mu) * rstd * g1.x + e1.x);
  o8[5] = (__bf16)((b.y - mu) * rstd * g1.y + e1.y);
  o8[6] = (__bf16)((b.z - mu) * rstd * g1.z + e1.z);
  o8[7] = (__bf16)((b.w - mu) * rstd * g1.w + e1.w);
  *reinterpret_cast<bf16x8*>(y + (size_t)row * D_ + lane * 8) = o8;
}

// ------------- batched transpose fp32 [Kd][N] -> bf16 [N][Kd], 8 jobs in one dispatch -------------
struct TJob {
  const float* src;
  __bf16* dst;
  int Kd, N, nx, ny;
  long ibs, obs;
  int base, cnt;   // block range [base, base+cnt)
};
struct TJobs { TJob j[8]; };

__global__ __launch_bounds__(256)
void transpose_batch_kernel(TJobs jobs) {
  int bid = blockIdx.x;
  #pragma unroll
  for (int d = 0; d < 8; ++d) {
    const TJob& J = jobs.j[d];
    if (bid >= J.base && bid < J.base + J.cnt) {
      int lid = bid - J.base;
      int pz = J.nx * J.ny;
      int z = lid / pz;
      int rem = lid - z * pz;
      int y = rem / J.nx;
      int x = rem - y * J.nx;
      __shared__ float tile[32][33];
      const float* ib = J.src + (size_t)z * J.ibs;
      __bf16* ob = J.dst + (size_t)z * J.obs;
      int n0 = x * 32, k0 = y * 32;
      int tx = threadIdx.x & 31, ty = threadIdx.x >> 5;
      #pragma unroll
      for (int i = 0; i < 4; ++i)
        tile[ty + i * 8][tx] = ib[(size_t)(k0 + ty + i * 8) * J.N + n0 + tx];
      __syncthreads();
      #pragma unroll
      for (int i = 0; i < 4; ++i)
        ob[(size_t)(n0 + ty + i * 8) * J.Kd + k0 + tx] = (__bf16)tile[tx][ty + i * 8];
      return;
    }
  }
}

// ---------------- bias concat for fused QKV ----------------
__global__ void concat_bias_kernel(const float* __restrict__ bq, const float* __restrict__ bk,
                                   const float* __restrict__ bv, float* __restrict__ bqkv) {
  int i = blockIdx.x * 256 + threadIdx.x;
  int l = i / 1536, c = i - l * 1536;
  float v = (c < 512) ? bq[l * 512 + c]
          : (c < 1024) ? bk[l * 512 + c - 512]
                       : bv[l * 512 + c - 1024];
  bqkv[i] = v;
}

// ---------------- bf16 MFMA GEMM, 128x128 tile, BK=64, swizzled LDS (Wm) ----------------
#define BM 128
#define BN 128
#define BK 64

template<int OMODE, bool GELU_ACT, bool RES, bool SWZ>
__global__ __launch_bounds__(256)
void gemm_bf16_kernel(const __bf16* __restrict__ A, const __bf16* __restrict__ WT,
                      const float* __restrict__ bias, const float* __restrict__ res,
                      void* __restrict__ outp, void* __restrict__ outp2, void* __restrict__ outp3,
                      int M, int N, int Kd) {
  __shared__ __bf16 As[BM * BK];
  __shared__ __bf16 Ws[BN * BK];
  int tid = threadIdx.x;
  int lane = tid & 63, w = tid >> 6;
  int wr = w >> 1, wc = w & 1;
  int lr = lane & 15, lg = lane >> 4;
  int bx, by;
  if (SWZ) {
    int swz = xcd_swz(blockIdx.x, gridDim.x);
    int gx = M >> 7;
    bx = swz % gx;
    by = swz / gx;
  } else {
    bx = blockIdx.x; by = blockIdx.y;
  }
  int row0 = bx * BM, col0 = by * BN;

  const __bf16* Abase = A + (size_t)row0 * Kd;
  const __bf16* Wbase = WT + (size_t)col0 * Kd;

  f32x4v acc[4][4];
  #pragma unroll
  for (int i = 0; i < 4; ++i)
    #pragma unroll
    for (int j = 0; j < 4; ++j)
      #pragma unroll
      for (int e = 0; e < 4; ++e) acc[i][j][e] = 0.0f;

  for (int k0 = 0; k0 < Kd; k0 += BK) {
    stage_tile4<128>(Abase + k0, Kd, As, w, lane);
    stage_tile4<128>(Wbase + k0, Kd, Ws, w, lane);
    __syncthreads();
    bf16x8 af[4][2], bfr[4][2];
    #pragma unroll
    for (int mr = 0; mr < 4; ++mr)
      #pragma unroll
      for (int kk = 0; kk < 2; ++kk)
        af[mr][kk] = lds_frag64(As, wr * 64 + mr * 16 + lr, kk * 32 + lg * 8);
    #pragma unroll
    for (int nc = 0; nc < 4; ++nc)
      #pragma unroll
      for (int kk = 0; kk < 2; ++kk)
        bfr[nc][kk] = lds_frag64(Ws, wc * 64 + nc * 16 + lr, kk * 32 + lg * 8);
    __builtin_amdgcn_s_setprio(1);
    #pragma unroll
    for (int mr = 0; mr < 4; ++mr)
      #pragma unroll
      for (int nc = 0; nc < 4; ++nc) {
        acc[mr][nc] = __builtin_amdgcn_mfma_f32_16x16x32_bf16(af[mr][0], bfr[nc][0], acc[mr][nc], 0, 0, 0);
        acc[mr][nc] = __builtin_amdgcn_mfma_f32_16x16x32_bf16(af[mr][1], bfr[nc][1], acc[mr][nc], 0, 0, 0);
      }
    __builtin_amdgcn_s_setprio(0);
    __syncthreads();
  }

  #pragma unroll
  for (int mr = 0; mr < 4; ++mr) {
    #pragma unroll
    for (int nc = 0; nc < 4; ++nc) {
      int c = col0 + wc * 64 + nc * 16 + lr;
      int rb = row0 + wr * 64 + mr * 16 + lg * 4;
      float vv[4];
      #pragma unroll
      for (int j = 0; j < 4; ++j) {
        float t = acc[mr][nc][j] + bias[c];
        if (RES) t += res[(size_t)(rb + j) * N + c];
        if (GELU_ACT) t = 0.5f * t * (1.0f + erff(t * 0.70710678118654752f));
        vv[j] = t;
      }
      if (OMODE == 0) {
        float* out = (float*)outp;
        #pragma unroll
        for (int j = 0; j < 4; ++j) out[(size_t)(rb + j) * N + c] = vv[j];
      } else if (OMODE == 1) {
        __bf16* out = (__bf16*)outp;
        #pragma unroll
        for (int j = 0; j < 4; ++j) out[(size_t)(rb + j) * N + c] = (__bf16)vv[j];
      } else if (OMODE == 3) {
        float* out = (float*)outp;
        __bf16* out2 = (__bf16*)outp2;
        #pragma unroll
        for (int j = 0; j < 4; ++j) {
          out[(size_t)(rb + j) * N + c] = vv[j];
          out2[(size_t)(rb + j) * N + c] = (__bf16)vv[j];
        }
      }
    }
  }
}

// ----- MTILE x 128 GEMM, BK=64: MTILE in {32,64}; XCD-swizzled 1-D grid -----
// OMODE: 0 fp32 (+res) | 1 bf16 (+gelu) | 3 fp32+bf16 dual (+res) | 4 fused-QKV
template<int MTILE, int OMODE, bool GELU_ACT, bool RES>
__global__ __launch_bounds__(256)
void gemm_n128_kernel(const __bf16* __restrict__ A, const __bf16* __restrict__ WT,
                      const float* __restrict__ bias, const float* __restrict__ res,
                      void* __restrict__ outp, void* __restrict__ outp2, void* __restrict__ outp3,
                      int M, int N, int Kd) {
  constexpr int FR = MTILE / 32;          // 16-row fragments per wave
  __shared__ __bf16 As[MTILE * BK];
  __shared__ __bf16 Ws[BN * BK];
  int tid = threadIdx.x;
  int lane = tid & 63, w = tid >> 6;
  int wr = w >> 1, wc = w & 1;
  int lr = lane & 15, lg = lane >> 4;
  int swz = xcd_swz(blockIdx.x, gridDim.x);
  int gx = M / MTILE;
  int bx = swz % gx, by = swz / gx;
  int row0 = bx * MTILE, col0 = by * BN;

  const __bf16* Abase = A + (size_t)row0 * Kd;
  const __bf16* Wbase = WT + (size_t)col0 * Kd;

  f32x4v acc[FR][4];
  #pragma unroll
  for (int i = 0; i < FR; ++i)
    #pragma unroll
    for (int j = 0; j < 4; ++j)
      #pragma unroll
      for (int e = 0; e < 4; ++e) acc[i][j][e] = 0.0f;

  for (int k0 = 0; k0 < Kd; k0 += BK) {
    stage_tile4<MTILE>(Abase + k0, Kd, As, w, lane);
    stage_tile4<128>(Wbase + k0, Kd, Ws, w, lane);
    __syncthreads();
    bf16x8 af[FR][2], bfr[4][2];
    #pragma unroll
    for (int mr = 0; mr < FR; ++mr)
      #pragma unroll
      for (int kk = 0; kk < 2; ++kk)
        af[mr][kk] = lds_frag64(As, wr * (16 * FR) + mr * 16 + lr, kk * 32 + lg * 8);
    #pragma unroll
    for (int nc = 0; nc < 4; ++nc)
      #pragma unroll
      for (int kk = 0; kk < 2; ++kk)
        bfr[nc][kk] = lds_frag64(Ws, wc * 64 + nc * 16 + lr, kk * 32 + lg * 8);
    __builtin_amdgcn_s_setprio(1);
    #pragma unroll
    for (int mr = 0; mr < FR; ++mr)
      #pragma unroll
      for (int nc = 0; nc < 4; ++nc) {
        acc[mr][nc] = __builtin_amdgcn_mfma_f32_16x16x32_bf16(af[mr][0], bfr[nc][0], acc[mr][nc], 0, 0, 0);
        acc[mr][nc] = __builtin_amdgcn_mfma_f32_16x16x32_bf16(af[mr][1], bfr[nc][1], acc[mr][nc], 0, 0, 0);
      }
    __builtin_amdgcn_s_setprio(0);
    __syncthreads();
  }

  #pragma unroll
  for (int mr = 0; mr < FR; ++mr) {
    #pragma unroll
    for (int nc = 0; nc < 4; ++nc) {
      int c = col0 + wc * 64 + nc * 16 + lr;
      int rb = row0 + wr * (16 * FR) + mr * 16 + lg * 4;
      float vv[4];
      #pragma unroll
      for (int j = 0; j < 4; ++j) {
        float t = acc[mr][nc][j] + bias[c];
        if (RES) t += res[(size_t)(rb + j) * N + c];
        if (GELU_ACT) t = 0.5f * t * (1.0f + erff(t * 0.70710678118654752f));
        vv[j] = t;
      }
      if (OMODE == 0) {
        float* out = (float*)outp;
        #pragma unroll
        for (int j = 0; j < 4; ++j) out[(size_t)(rb + j) * N + c] = vv[j];
      } else if (OMODE == 1) {
        __bf16* out = (__bf16*)outp;
        #pragma unroll
        for (int j = 0; j < 4; ++j) out[(size_t)(rb + j) * N + c] = (__bf16)vv[j];
      } else if (OMODE == 3) {
        float* out = (float*)outp;
        __bf16* out2 = (__bf16*)outp2;
        #pragma unroll
        for (int j = 0; j < 4; ++j) {
          out[(size_t)(rb + j) * N + c] = vv[j];
          out2[(size_t)(rb + j) * N + c] = (__bf16)vv[j];
        }
      } else {  // OMODE 4: fused QKV epilogue
        if (col0 < 512) {
          __bf16* out = (__bf16*)outp;
          #pragma unroll
          for (int j = 0; j < 4; ++j) out[(size_t)(rb + j) * D_ + c] = (__bf16)vv[j];
        } else if (col0 < 1024) {
          __bf16* out = (__bf16*)outp2;
          #pragma unroll
          for (int j = 0; j < 4; ++j) out[(size_t)(rb + j) * D_ + (c - 512)] = (__bf16)vv[j];
        } else {
          __bf16* out = (__bf16*)outp3;   // vt [B][D][S]
          int b = rb >> 10, s0 = rb & (S_ - 1);
          bf16x4 pk;
          #pragma unroll
          for (int j = 0; j < 4; ++j) pk[j] = (__bf16)vv[j];
          *reinterpret_cast<bf16x4*>(&out[((size_t)b * D_ + (c - 1024)) * S_ + s0]) = pk;
        }
      }
    }
  }
}

// ------- head GEMM: 256x256 tile, 8 waves, BK=64, double-buffered counted-vmcnt pipeline -------
__global__ __launch_bounds__(512)
void gemm_head_kernel(const __bf16* __restrict__ A, const __bf16* __restrict__ WT,
                      const float* __restrict__ bias, float* __restrict__ out,
                      int M, int N, int Kd) {
  __shared__ __bf16 lds[2][2][256 * 64];   // 128 KB
  const int tid = threadIdx.x;
  const int lane = tid & 63, w = tid >> 6;
  const int wr = w >> 2, wc = w & 3;
  const int lr = lane & 15, lg = lane >> 4;

  int swz = xcd_swz(blockIdx.x, gridDim.x);
  int gx = M >> 8;
  int bx = swz % gx, by = swz / gx;
  int row0 = bx * 256, col0 = by * 256;

  const __bf16* Asrc = A + (size_t)row0 * Kd;
  const __bf16* Bsrc = WT + (size_t)col0 * Kd;

  f32x4v acc[8][4];
  #pragma unroll
  for (int i = 0; i < 8; ++i)
    #pragma unroll
    for (int j = 0; j < 4; ++j)
      #pragma unroll
      for (int e = 0; e < 4; ++e) acc[i][j][e] = 0.0f;

  const int NT = Kd / 64;
  stage_half8(Asrc,                      Kd, &lds[0][0][0],    w, lane);
  stage_half8(Asrc + (size_t)128 * Kd,   Kd, &lds[0][0][8192], w, lane);
  stage_half8(Bsrc,                      Kd, &lds[0][1][0],    w, lane);
  stage_half8(Bsrc + (size_t)128 * Kd,   Kd, &lds[0][1][8192], w, lane);

  for (int t = 0; t < NT; ++t) {
    int cur = t & 1, nxt = cur ^ 1;
    int k1 = (t + 1) * 64;
    const __bf16* Ab = &lds[cur][0][0];
    const __bf16* Bb = &lds[cur][1][0];
    bf16x8 bfr[4][2];
    #pragma unroll
    for (int p = 0; p < 4; ++p) {
      if (t < NT - 1) {
        const __bf16* s;
        __bf16* d;
        if (p == 0)      { s = Asrc + k1;                    d = &lds[nxt][0][0]; }
        else if (p == 1) { s = Asrc + (size_t)128 * Kd + k1; d = &lds[nxt][0][8192]; }
        else if (p == 2) { s = Bsrc + k1;                    d = &lds[nxt][1][0]; }
        else             { s = Bsrc + (size_t)128 * Kd + k1; d = &lds[nxt][1][8192]; }
        stage_half8(s, Kd, d, w, lane);
      }
      if (p == 0) {
        if (t < NT - 1) asm volatile("s_waitcnt vmcnt(2)" ::: "memory");
        else            asm volatile("s_waitcnt vmcnt(0)" ::: "memory");
        __builtin_amdgcn_s_barrier();
        #pragma unroll
        for (int nn = 0; nn < 4; ++nn)
          #pragma unroll
          for (int kk = 0; kk < 2; ++kk)
            bfr[nn][kk] = lds_frag64(Bb, wc * 64 + nn * 16 + lr, kk * 32 + lg * 8);
      }
      bf16x8 af[2][2];
      #pragma unroll
      for (int mm = 0; mm < 2; ++mm)
        #pragma unroll
        for (int kk = 0; kk < 2; ++kk)
          af[mm][kk] = lds_frag64(Ab, wr * 128 + p * 32 + mm * 16 + lr, kk * 32 + lg * 8);
      asm volatile("s_waitcnt lgkmcnt(0)" ::: "memory");
      __builtin_amdgcn_sched_barrier(0);
      __builtin_amdgcn_s_setprio(1);
      #pragma unroll
      for (int mm = 0; mm < 2; ++mm)
        #pragma unroll
        for (int nn = 0; nn < 4; ++nn) {
          acc[p * 2 + mm][nn] = __builtin_amdgcn_mfma_f32_16x16x32_bf16(af[mm][0], bfr[nn][0], acc[p * 2 + mm][nn], 0, 0, 0);
          acc[p * 2 + mm][nn] = __builtin_amdgcn_mfma_f32_16x16x32_bf16(af[mm][1], bfr[nn][1], acc[p * 2 + mm][nn], 0, 0, 0);
        }
      __builtin_amdgcn_s_setprio(0);
    }
    __builtin_amdgcn_s_barrier();
  }

  #pragma unroll
  for (int mg = 0; mg < 8; ++mg) {
    #pragma unroll
    for (int nn = 0; nn < 4; ++nn) {
      int c = col0 + wc * 64 + nn * 16 + lr;
      int rb = row0 + wr * 128 + mg * 16 + lg * 4;
      float b = bias[c];
      #pragma unroll
      for (int j = 0; j < 4; ++j)
        out[(size_t)(rb + j) * N + c] = acc[mg][nn][j] + b;
    }
  }
}

// ---------------- fused attention: 8 waves, 16 q-rows, u16 scores ----------------
__global__ __launch_bounds__(512)
void attn_kernel(const __bf16* __restrict__ qm, const __bf16* __restrict__ km,
                 const __bf16* __restrict__ vt, __bf16* __restrict__ o) {
  __shared__ unsigned short sc16[16][SRS];
  __shared__ float ored[4][64][4];   // kt-half partials from waves 4-7
  __shared__ float rs[16];           // reciprocal row sums
  const int q0 = blockIdx.x * 16;
  const int hh = blockIdx.y;
  const int bb = blockIdx.z;
  const int tid = threadIdx.x;
  const int lane = tid & 63, w = tid >> 6;   // 8 waves
  const int lr = lane & 15, lg = lane >> 4;

  const __bf16* qrow = qm + ((size_t)(bb * S_ + q0 + lr)) * D_ + hh * DK_;
  bf16x8 qf0 = *reinterpret_cast<const bf16x8*>(qrow + lg * 8);
  bf16x8 qf1 = *reinterpret_cast<const bf16x8*>(qrow + 32 + lg * 8);

  // ---- phase 1: scores via MFMA; 8 waves cover 128 keys per iteration ----
  const __bf16* kbase = km + ((size_t)bb * S_) * D_ + hh * DK_;
  #pragma unroll
  for (int kt = 0; kt < 8; ++kt) {
    int key0 = kt * 128 + w * 16;
    const __bf16* krow = kbase + (size_t)(key0 + lr) * D_;
    bf16x8 kf0 = *reinterpret_cast<const bf16x8*>(krow + lg * 8);
    bf16x8 kf1 = *reinterpret_cast<const bf16x8*>(krow + 32 + lg * 8);
    f32x4v d = {0.0f, 0.0f, 0.0f, 0.0f};
    __builtin_amdgcn_s_setprio(1);
    d = __builtin_amdgcn_mfma_f32_16x16x32_bf16(qf0, kf0, d, 0, 0, 0);
    d = __builtin_amdgcn_mfma_f32_16x16x32_bf16(qf1, kf1, d, 0, 0, 0);
    __builtin_amdgcn_s_setprio(0);
    #pragma unroll
    for (int j = 0; j < 4; ++j) {
      unsigned int u = f32_to_bf16_bits(d[j] * 0.125f);
      u = (u & 0x8000u) ? (~u & 0xFFFFu) : (u | 0x8000u);
      sc16[lg * 4 + j][key0 + lr] = (unsigned short)u;
    }
  }
  __syncthreads();

  // ---- phase 2: 32 threads per row (half-wave teams); 16-bit binary search ----
  {
    int r = tid >> 5, tc = tid & 31;
    const unsigned int* srow = reinterpret_cast<const unsigned int*>(&sc16[r][0]);
    unsigned int wv[16];   // 32 u16 values packed
    #pragma unroll
    for (int g = 0; g < 4; ++g) {
      uint4 t4 = *reinterpret_cast<const uint4*>(&srow[g * 128 + tc * 4]);
      wv[g * 4 + 0] = t4.x; wv[g * 4 + 1] = t4.y;
      wv[g * 4 + 2] = t4.z; wv[g * 4 + 3] = t4.w;
    }
    unsigned int umax = 0;
    #pragma unroll
    for (int i = 0; i < 16; ++i) {
      unsigned int a = wv[i] & 0xFFFFu, b = wv[i] >> 16;
      unsigned int mx = a > b ? a : b;
      umax = mx > umax ? mx : umax;
    }
    umax = red16umax(umax);
    {
      unsigned int other = (unsigned int)__shfl_xor((int)umax, 16, 32);
      umax = other > umax ? other : umax;
    }
    unsigned int lo = 0;
    for (int bit = 15; bit >= 0; --bit) {
      unsigned int cs = (lo | (1u << bit)) << 16;
      int cnt = 0;
      #pragma unroll
      for (int i = 0; i < 16; ++i) {
        cnt += ((wv[i] << 16) >= cs) ? 1 : 0;
        cnt += (wv[i] >= cs) ? 1 : 0;
      }
      cnt = red16i(cnt);
      cnt += __shfl_xor(cnt, 16, 32);
      if (cnt >= KTOP) lo |= (1u << bit);
    }
    unsigned int um = (umax & 0x8000u) ? (umax ^ 0x8000u) : (~umax & 0xFFFFu);
    float mval = __uint_as_float(um << 16);

    __bf16* P = reinterpret_cast<__bf16*>(&sc16[r][0]);
    float lsum = 0.0f;
    #pragma unroll
    for (int g = 0; g < 4; ++g) {
      bf16x8 pk;
      #pragma unroll
      for (int e = 0; e < 8; ++e) {
        unsigned int wrd = wv[g * 4 + (e >> 1)];
        unsigned int u = (e & 1) ? (wrd >> 16) : (wrd & 0xFFFFu);
        float p = 0.0f;
        if (u >= lo) {
          unsigned int ub = (u & 0x8000u) ? (u ^ 0x8000u) : (~u & 0xFFFFu);
          p = __expf(__uint_as_float(ub << 16) - mval);
        }
        pk[e] = (__bf16)p;
        lsum += (float)pk[e];
      }
      *reinterpret_cast<bf16x8*>(&P[tc * 8 + g * 256]) = pk;
    }
    lsum = red16f(lsum);
    lsum += __shfl_xor(lsum, 16, 32);
    if (tc == 0) rs[r] = 1.0f / lsum;
  }
  __syncthreads();

  // ---- phase 3: PV split across wave pairs (kt halves), LDS reduce ----
  {
    const __bf16* P0 = reinterpret_cast<const __bf16*>(&sc16[0][0]);
    int wc4 = w & 3;      // column group (16 cols each)
    int half = w >> 2;    // kt half
    const __bf16* vbase = vt + ((size_t)bb * D_ + hh * DK_ + wc4 * 16 + lr) * S_;
    const __bf16* prow = P0 + (size_t)lr * SRS;
    f32x4v oacc = {0.0f, 0.0f, 0.0f, 0.0f};
    int kt0 = half * 16;
    __builtin_amdgcn_s_setprio(1);
    #pragma unroll
    for (int kk = 0; kk < 16; ++kk) {
      int kt = kt0 + kk;
      bf16x8 a = *reinterpret_cast<const bf16x8*>(prow + kt * 32 + lg * 8);
      bf16x8 b = *reinterpret_cast<const bf16x8*>(vbase + kt * 32 + lg * 8);
      oacc = __builtin_amdgcn_mfma_f32_16x16x32_bf16(a, b, oacc, 0, 0, 0);
    }
    __builtin_amdgcn_s_setprio(0);
    if (half == 1) {
      float4 st;
      st.x = oacc[0]; st.y = oacc[1]; st.z = oacc[2]; st.w = oacc[3];
      *reinterpret_cast<float4*>(&ored[wc4][lane][0]) = st;
    }
    __syncthreads();
    if (half == 0) {
      float4 pv = *reinterpret_cast<const float4*>(&ored[wc4][lane][0]);
      oacc[0] += pv.x; oacc[1] += pv.y; oacc[2] += pv.z; oacc[3] += pv.w;
      #pragma unroll
      for (int j = 0; j < 4; ++j) {
        int qr = lg * 4 + j;
        float ov = oacc[j] * rs[qr];
        o[((size_t)(bb * S_ + q0 + qr)) * D_ + hh * DK_ + wc4 * 16 + lr] = (__bf16)ov;
      }
    }
  }
}

extern "C" void kernel_launch(void* const* d_in, const int* in_sizes, int n_in,
                              void* d_out, int out_size, void* d_ws, size_t ws_size,
                              hipStream_t stream) {
  (void)in_sizes; (void)n_in; (void)out_size; (void)ws_size;
  const int*   x    = (const int*)d_in[0];
  const float* tok  = (const float*)d_in[1];
  const float* pos  = (const float*)d_in[2];
  const float* Wq   = (const float*)d_in[3];
  const float* bq   = (const float*)d_in[4];
  const float* Wk   = (const float*)d_in[5];
  const float* bk   = (const float*)d_in[6];
  const float* Wv   = (const float*)d_in[7];
  const float* bv   = (const float*)d_in[8];
  const float* Wo   = (const float*)d_in[9];
  const float* bo   = (const float*)d_in[10];
  const float* g1   = (const float*)d_in[11];
  const float* be1  = (const float*)d_in[12];
  const float* g2   = (const float*)d_in[13];
  const float* be2  = (const float*)d_in[14];
  const float* W1   = (const float*)d_in[15];
  const float* b1   = (const float*)d_in[16];
  const float* Wm   = (const float*)d_in[17];
  const float* bm   = (const float*)d_in[18];
  const float* W2   = (const float*)d_in[19];
  const float* b2   = (const float*)d_in[20];
  const float* Wout = (const float*)d_in[21];
  const float* bout = (const float*)d_in[22];
  float* logits = (float*)d_out;

  const int M = B_ * S_;  // 4096
  float* ws = (float*)d_ws;
  float* h    = ws;
  float* bqkv = h + (size_t)M * D_;
  __bf16* y16  = (__bf16*)(bqkv + (size_t)L_ * 1536);
  __bf16* f1b  = y16  + (size_t)M * D_;
  __bf16* f2b  = f1b  + (size_t)M * DFF_;
  __bf16* qb16 = f2b  + (size_t)M * DFF_;
  __bf16* kb16 = qb16 + (size_t)M * D_;
  __bf16* vt16 = kb16 + (size_t)M * D_;
  __bf16* ob16 = vt16 + (size_t)M * D_;
  __bf16* h16  = ob16 + (size_t)M * D_;
  __bf16* WqkvT = h16 + (size_t)M * D_;
  __bf16* WoT  = WqkvT + (size_t)L_ * 1536 * D_;
  __bf16* W1T  = WoT  + (size_t)L_ * D_ * D_;
  __bf16* WmT  = W1T  + (size_t)L_ * D_ * DFF_;
  __bf16* W2T  = WmT  + (size_t)L_ * DFF_ * DFF_;
  __bf16* WoutT = W2T + (size_t)L_ * D_ * DFF_;

  // ---- batched weight transposes: one dispatch, 8 jobs ----
  TJobs tj;
  int base = 0;
  auto addjob = [&](int idx, const float* src, __bf16* dst, int Kd, int N,
                    long ibs, long obs, int nz) {
    TJob& J = tj.j[idx];
    J.src = src; J.dst = dst; J.Kd = Kd; J.N = N;
    J.nx = N / 32; J.ny = Kd / 32; J.ibs = ibs; J.obs = obs;
    J.base = base; J.cnt = J.nx * J.ny * nz;
    base += J.cnt;
  };
  const long DD = (long)D_ * D_;
  addjob(0, Wq,   WqkvT,            D_,   D_,   DD, 1536L * D_, L_);
  addjob(1, Wk,   WqkvT + 512*512,  D_,   D_,   DD, 1536L * D_, L_);
  addjob(2, Wv,   WqkvT + 1024*512, D_,   D_,   DD, 1536L * D_, L_);
  addjob(3, Wo,   WoT,              D_,   D_,   DD, DD,          L_);
  addjob(4, W1,   W1T,              D_,   DFF_, (long)D_*DFF_, (long)D_*DFF_, L_);
  addjob(5, Wm,   WmT,              DFF_, DFF_, (long)DFF_*DFF_, (long)DFF_*DFF_, L_);
  addjob(6, W2,   W2T,              DFF_, D_,   (long)D_*DFF_, (long)D_*DFF_, L_);
  addjob(7, Wout, WoutT,            D_,   V_,   (long)D_*V_,   (long)D_*V_,   1);
  transpose_batch_kernel<<<base, 256, 0, stream>>>(tj);

  concat_bias_kernel<<<(L_*1536)/256, 256, 0, stream>>>(bq, bk, bv, bqkv);
  embed_kernel<<<M, 128, 0, stream>>>(x, tok, pos, h);

  for (int l = 0; l < L_; ++l) {
    ln_kernel<<<M/4, 256, 0, stream>>>(h, g1 + l * D_, be1 + l * D_, y16);
    gemm_n128_kernel<64,4,false,false><<<dim3((M/64) * (1536/BN)), 256, 0, stream>>>(
        y16, WqkvT + (size_t)l * 1536 * D_, bqkv + l * 1536, nullptr,
        qb16, kb16, vt16, M, 1536, D_);
    attn_kernel<<<dim3(S_/16, H_, B_), 512, 0, stream>>>(qb16, kb16, vt16, ob16);
    gemm_n128_kernel<32,0,false,true><<<dim3((M/32) * (D_/BN)), 256, 0, stream>>>(
        ob16, WoT + (size_t)l * DD, bo + l * D_, h, h, nullptr, nullptr, M, D_, D_);
    ln_kernel<<<M/4, 256, 0, stream>>>(h, g2 + l * D_, be2 + l * D_, y16);
    gemm_n128_kernel<64,1,true,false><<<dim3((M/64) * (DFF_/BN)), 256, 0, stream>>>(
        y16, W1T + (size_t)l * D_ * DFF_, b1 + l * DFF_, nullptr, f1b, nullptr, nullptr, M, DFF_, D_);
    gemm_bf16_kernel<1,true,false,true><<<dim3((M/BM) * (DFF_/BN)), 256, 0, stream>>>(
        f1b, WmT + (size_t)l * DFF_ * DFF_, bm + l * DFF_, nullptr, f2b, nullptr, nullptr, M, DFF_, DFF_);
    gemm_n128_kernel<32,3,false,true><<<dim3((M/32) * (D_/BN)), 256, 0, stream>>>(
        f2b, W2T + (size_t)l * D_ * DFF_, b2 + l * D_, h, h, h16, nullptr, M, D_, DFF_);
  }
  gemm_head_kernel<<<dim3((M/256) * (V_/256)), 512, 0, stream>>>(
      h16, WoutT, bout, logits, M, V_, D_);
}

// Round 14
// 1162.936 us; speedup vs baseline: 1.1075x; 1.0038x over previous
//
#include <hip/hip_runtime.h>
#include <hip/hip_bf16.h>
#include <math.h>

#define B_ 4
#define S_ 1024
#define D_ 512
#define H_ 8
#define L_ 4
#define DFF_ 2048
#define V_ 32000
#define DK_ 64
#define KTOP 307
#define SRS 1048    // score row stride in u16 elems

using bf16x8 = __attribute__((ext_vector_type(8))) __bf16;
using bf16x4 = __attribute__((ext_vector_type(4))) __bf16;
using bf16x2 = __attribute__((ext_vector_type(2))) __bf16;
using f32x4v = __attribute__((ext_vector_type(4))) float;

__device__ __forceinline__ void gload_lds16(const __bf16* g, __bf16* l) {
  __builtin_amdgcn_global_load_lds(
      (const __attribute__((address_space(1))) void*)g,
      (__attribute__((address_space(3))) void*)l, 16, 0, 0);
}

// fp32 -> bf16 bits (RNE), as low 16 of u32
__device__ __forceinline__ unsigned int f32_to_bf16_bits(float s) {
  unsigned int x = __float_as_uint(s);
  return (x + 0x7FFFu + ((x >> 16) & 1u)) >> 16;
}

// ---- DPP 16-lane reductions (teams aligned to DPP rows) ----
__device__ __forceinline__ int red16i(int x) {
  x += __builtin_amdgcn_update_dpp(0, x, 0xB1, 0xF, 0xF, true);
  x += __builtin_amdgcn_update_dpp(0, x, 0x4E, 0xF, 0xF, true);
  x += __builtin_amdgcn_update_dpp(0, x, 0x141, 0xF, 0xF, true);
  x += __builtin_amdgcn_update_dpp(0, x, 0x140, 0xF, 0xF, true);
  return x;
}
__device__ __forceinline__ unsigned int red16umax(unsigned int x) {
  unsigned int t;
  t = (unsigned int)__builtin_amdgcn_update_dpp(0, (int)x, 0xB1, 0xF, 0xF, true);  x = t > x ? t : x;
  t = (unsigned int)__builtin_amdgcn_update_dpp(0, (int)x, 0x4E, 0xF, 0xF, true);  x = t > x ? t : x;
  t = (unsigned int)__builtin_amdgcn_update_dpp(0, (int)x, 0x141, 0xF, 0xF, true); x = t > x ? t : x;
  t = (unsigned int)__builtin_amdgcn_update_dpp(0, (int)x, 0x140, 0xF, 0xF, true); x = t > x ? t : x;
  return x;
}
__device__ __forceinline__ float red16f(float x) {
  x += __int_as_float(__builtin_amdgcn_update_dpp(0, __float_as_int(x), 0xB1, 0xF, 0xF, true));
  x += __int_as_float(__builtin_amdgcn_update_dpp(0, __float_as_int(x), 0x4E, 0xF, 0xF, true));
  x += __int_as_float(__builtin_amdgcn_update_dpp(0, __float_as_int(x), 0x141, 0xF, 0xF, true));
  x += __int_as_float(__builtin_amdgcn_update_dpp(0, __float_as_int(x), 0x140, 0xF, 0xF, true));
  return x;
}
__device__ __forceinline__ float red64f(float x) {
  x = red16f(x);
  x += __shfl_xor(x, 16, 64);
  x += __shfl_xor(x, 32, 64);
  return x;
}

// ---- st_16x32-swizzled [R][64] bf16 LDS helpers; XOR (row&7)<<3 elements ----
template<int ROWS>
__device__ __forceinline__ void stage_tile4(const __bf16* src, int Kd, __bf16* lds,
                                            int w, int lane) {
  #pragma unroll
  for (int c = 0; c < ROWS / 32; ++c) {
    int rblk = (c * 4 + w) * 8;
    int row = rblk + (lane >> 3);
    int col = (lane & 7) * 8;
    int scol = col ^ ((row & 7) << 3);
    gload_lds16(src + (size_t)row * Kd + scol, lds + rblk * 64);
  }
}
__device__ __forceinline__ void stage_half8(const __bf16* src, int Kd, __bf16* lds,
                                            int w, int lane) {
  #pragma unroll
  for (int c = 0; c < 2; ++c) {
    int rblk = (c * 8 + w) * 8;
    int row = rblk + (lane >> 3);
    int col = (lane & 7) * 8;
    int scol = col ^ ((row & 7) << 3);
    gload_lds16(src + (size_t)row * Kd + scol, lds + rblk * 64);
  }
}
__device__ __forceinline__ bf16x8 lds_frag64(const __bf16* lds, int row, int colbase) {
  int col = colbase ^ ((row & 7) << 3);
  return *reinterpret_cast<const bf16x8*>(lds + row * 64 + col);
}

// ---- bijective XCD swizzle for 1-D grids with nwg % 8 == 0 ----
__device__ __forceinline__ int xcd_swz(int lid, int nwg) {
  int cpx = nwg >> 3;
  return (lid & 7) * cpx + (lid >> 3);
}

// ---------------- embedding ----------------
__global__ void embed_kernel(const int* __restrict__ x, const float* __restrict__ tok,
                             const float* __restrict__ pos, float* __restrict__ h) {
  int row = blockIdx.x;
  int t = threadIdx.x;
  int s = row & (S_ - 1);
  int token = x[row];
  const float4* t4 = reinterpret_cast<const float4*>(tok + (size_t)token * D_);
  const float4* p4 = reinterpret_cast<const float4*>(pos + (size_t)s * D_);
  float4 a = t4[t];
  float4 b = p4[t];
  a.x += b.x; a.y += b.y; a.z += b.z; a.w += b.w;
  reinterpret_cast<float4*>(h + (size_t)row * D_)[t] = a;
}

// ---------------- layernorm: one WAVE per row, no LDS/barrier ----------------
__global__ __launch_bounds__(256)
void ln_kernel(const float* __restrict__ xin, const float* __restrict__ g,
               const float* __restrict__ bta, __bf16* __restrict__ y) {
  int w = threadIdx.x >> 6, lane = threadIdx.x & 63;
  int row = blockIdx.x * 4 + w;
  const float4* x4 = reinterpret_cast<const float4*>(xin + (size_t)row * D_);
  float4 a = x4[lane * 2];
  float4 b = x4[lane * 2 + 1];
  float s = a.x + a.y + a.z + a.w + b.x + b.y + b.z + b.w;
  float q = a.x * a.x + a.y * a.y + a.z * a.z + a.w * a.w
          + b.x * b.x + b.y * b.y + b.z * b.z + b.w * b.w;
  s = red64f(s);
  q = red64f(q);
  float mu = s * (1.0f / D_);
  float var = q * (1.0f / D_) - mu * mu;
  float rstd = rsqrtf(var + 1e-5f);
  const float4* g4 = reinterpret_cast<const float4*>(g);
  const float4* b4 = reinterpret_cast<const float4*>(bta);
  float4 g0 = g4[lane * 2], g1 = g4[lane * 2 + 1];
  float4 e0 = b4[lane * 2], e1 = b4[lane * 2 + 1];
  bf16x8 o8;
  o8[0] = (__bf16)((a.x - mu) * rstd * g0.x + e0.x);
  o8[1] = (__bf16)((a.y - mu) * rstd * g0.y + e0.y);
  o8[2] = (__bf16)((a.z - mu) * rstd * g0.z + e0.z);
  o8[3] = (__bf16)((a.w - mu) * rstd * g0.w + e0.w);
  o8[4] = (__bf16)((b.x - mu) * rstd * g1.x + e1.x);
  o8[5] = (__bf16)((b.y - mu) * rstd * g1.y + e1.y);
  o8[6] = (__bf16)((b.z - mu) * rstd * g1.z + e1.z);
  o8[7] = (__bf16)((b.w - mu) * rstd * g1.w + e1.w);
  *reinterpret_cast<bf16x8*>(y + (size_t)row * D_ + lane * 8) = o8;
}

// ------------- batched transpose fp32 [Kd][N] -> bf16 [N][Kd], 8 jobs in one dispatch -------------
struct TJob {
  const float* src;
  __bf16* dst;
  int Kd, N, nx, ny;
  long ibs, obs;
  int base, cnt;   // block range [base, base+cnt)
};
struct TJobs { TJob j[8]; };

__global__ __launch_bounds__(256)
void transpose_batch_kernel(TJobs jobs) {
  int bid = blockIdx.x;
  #pragma unroll
  for (int d = 0; d < 8; ++d) {
    const TJob& J = jobs.j[d];
    if (bid >= J.base && bid < J.base + J.cnt) {
      int lid = bid - J.base;
      int pz = J.nx * J.ny;
      int z = lid / pz;
      int rem = lid - z * pz;
      int y = rem / J.nx;
      int x = rem - y * J.nx;
      __shared__ float tile[32][33];
      const float* ib = J.src + (size_t)z * J.ibs;
      __bf16* ob = J.dst + (size_t)z * J.obs;
      int n0 = x * 32, k0 = y * 32;
      int tx = threadIdx.x & 31, ty = threadIdx.x >> 5;
      #pragma unroll
      for (int i = 0; i < 4; ++i)
        tile[ty + i * 8][tx] = ib[(size_t)(k0 + ty + i * 8) * J.N + n0 + tx];
      __syncthreads();
      #pragma unroll
      for (int i = 0; i < 4; ++i)
        ob[(size_t)(n0 + ty + i * 8) * J.Kd + k0 + tx] = (__bf16)tile[tx][ty + i * 8];
      return;
    }
  }
}

// ---------------- bias concat for fused QKV ----------------
__global__ void concat_bias_kernel(const float* __restrict__ bq, const float* __restrict__ bk,
                                   const float* __restrict__ bv, float* __restrict__ bqkv) {
  int i = blockIdx.x * 256 + threadIdx.x;
  int l = i / 1536, c = i - l * 1536;
  float v = (c < 512) ? bq[l * 512 + c]
          : (c < 1024) ? bk[l * 512 + c - 512]
                       : bv[l * 512 + c - 1024];
  bqkv[i] = v;
}

#define BN 128
#define BK 64

// ----- MTILE x 128 GEMM, BK=64: MTILE in {32,64}; XCD-swizzled 1-D grid -----
// OMODE: 0 fp32 (+res) | 1 bf16 (+gelu) | 3 fp32+bf16 dual (+res) | 4 fused-QKV
template<int MTILE, int OMODE, bool GELU_ACT, bool RES>
__global__ __launch_bounds__(256)
void gemm_n128_kernel(const __bf16* __restrict__ A, const __bf16* __restrict__ WT,
                      const float* __restrict__ bias, const float* __restrict__ res,
                      void* __restrict__ outp, void* __restrict__ outp2, void* __restrict__ outp3,
                      int M, int N, int Kd) {
  constexpr int FR = MTILE / 32;          // 16-row fragments per wave
  __shared__ __bf16 As[MTILE * BK];
  __shared__ __bf16 Ws[BN * BK];
  int tid = threadIdx.x;
  int lane = tid & 63, w = tid >> 6;
  int wr = w >> 1, wc = w & 1;
  int lr = lane & 15, lg = lane >> 4;
  int swz = xcd_swz(blockIdx.x, gridDim.x);
  int gx = M / MTILE;
  int bx = swz % gx, by = swz / gx;
  int row0 = bx * MTILE, col0 = by * BN;

  const __bf16* Abase = A + (size_t)row0 * Kd;
  const __bf16* Wbase = WT + (size_t)col0 * Kd;

  f32x4v acc[FR][4];
  #pragma unroll
  for (int i = 0; i < FR; ++i)
    #pragma unroll
    for (int j = 0; j < 4; ++j)
      #pragma unroll
      for (int e = 0; e < 4; ++e) acc[i][j][e] = 0.0f;

  for (int k0 = 0; k0 < Kd; k0 += BK) {
    stage_tile4<MTILE>(Abase + k0, Kd, As, w, lane);
    stage_tile4<128>(Wbase + k0, Kd, Ws, w, lane);
    __syncthreads();
    bf16x8 af[FR][2], bfr[4][2];
    #pragma unroll
    for (int mr = 0; mr < FR; ++mr)
      #pragma unroll
      for (int kk = 0; kk < 2; ++kk)
        af[mr][kk] = lds_frag64(As, wr * (16 * FR) + mr * 16 + lr, kk * 32 + lg * 8);
    #pragma unroll
    for (int nc = 0; nc < 4; ++nc)
      #pragma unroll
      for (int kk = 0; kk < 2; ++kk)
        bfr[nc][kk] = lds_frag64(Ws, wc * 64 + nc * 16 + lr, kk * 32 + lg * 8);
    __builtin_amdgcn_s_setprio(1);
    #pragma unroll
    for (int mr = 0; mr < FR; ++mr)
      #pragma unroll
      for (int nc = 0; nc < 4; ++nc) {
        acc[mr][nc] = __builtin_amdgcn_mfma_f32_16x16x32_bf16(af[mr][0], bfr[nc][0], acc[mr][nc], 0, 0, 0);
        acc[mr][nc] = __builtin_amdgcn_mfma_f32_16x16x32_bf16(af[mr][1], bfr[nc][1], acc[mr][nc], 0, 0, 0);
      }
    __builtin_amdgcn_s_setprio(0);
    __syncthreads();
  }

  #pragma unroll
  for (int mr = 0; mr < FR; ++mr) {
    #pragma unroll
    for (int nc = 0; nc < 4; ++nc) {
      int c = col0 + wc * 64 + nc * 16 + lr;
      int rb = row0 + wr * (16 * FR) + mr * 16 + lg * 4;
      float vv[4];
      #pragma unroll
      for (int j = 0; j < 4; ++j) {
        float t = acc[mr][nc][j] + bias[c];
        if (RES) t += res[(size_t)(rb + j) * N + c];
        if (GELU_ACT) t = 0.5f * t * (1.0f + erff(t * 0.70710678118654752f));
        vv[j] = t;
      }
      if (OMODE == 0) {
        float* out = (float*)outp;
        #pragma unroll
        for (int j = 0; j < 4; ++j) out[(size_t)(rb + j) * N + c] = vv[j];
      } else if (OMODE == 1) {
        __bf16* out = (__bf16*)outp;
        #pragma unroll
        for (int j = 0; j < 4; ++j) out[(size_t)(rb + j) * N + c] = (__bf16)vv[j];
      } else if (OMODE == 3) {
        float* out = (float*)outp;
        __bf16* out2 = (__bf16*)outp2;
        #pragma unroll
        for (int j = 0; j < 4; ++j) {
          out[(size_t)(rb + j) * N + c] = vv[j];
          out2[(size_t)(rb + j) * N + c] = (__bf16)vv[j];
        }
      } else {  // OMODE 4: fused QKV epilogue
        if (col0 < 512) {
          __bf16* out = (__bf16*)outp;
          #pragma unroll
          for (int j = 0; j < 4; ++j) out[(size_t)(rb + j) * D_ + c] = (__bf16)vv[j];
        } else if (col0 < 1024) {
          __bf16* out = (__bf16*)outp2;
          #pragma unroll
          for (int j = 0; j < 4; ++j) out[(size_t)(rb + j) * D_ + (c - 512)] = (__bf16)vv[j];
        } else {
          __bf16* out = (__bf16*)outp3;   // vt [B][D][S]
          int b = rb >> 10, s0 = rb & (S_ - 1);
          bf16x4 pk;
          #pragma unroll
          for (int j = 0; j < 4; ++j) pk[j] = (__bf16)vv[j];
          *reinterpret_cast<bf16x4*>(&out[((size_t)b * D_ + (c - 1024)) * S_ + s0]) = pk;
        }
      }
    }
  }
}

// ------- head GEMM: 256x256 tile, 8 waves, BK=64, double-buffered counted-vmcnt pipeline -------
__global__ __launch_bounds__(512)
void gemm_head_kernel(const __bf16* __restrict__ A, const __bf16* __restrict__ WT,
                      const float* __restrict__ bias, float* __restrict__ out,
                      int M, int N, int Kd) {
  __shared__ __bf16 lds[2][2][256 * 64];   // 128 KB
  const int tid = threadIdx.x;
  const int lane = tid & 63, w = tid >> 6;
  const int wr = w >> 2, wc = w & 3;
  const int lr = lane & 15, lg = lane >> 4;

  int swz = xcd_swz(blockIdx.x, gridDim.x);
  int gx = M >> 8;
  int bx = swz % gx, by = swz / gx;
  int row0 = bx * 256, col0 = by * 256;

  const __bf16* Asrc = A + (size_t)row0 * Kd;
  const __bf16* Bsrc = WT + (size_t)col0 * Kd;

  f32x4v acc[8][4];
  #pragma unroll
  for (int i = 0; i < 8; ++i)
    #pragma unroll
    for (int j = 0; j < 4; ++j)
      #pragma unroll
      for (int e = 0; e < 4; ++e) acc[i][j][e] = 0.0f;

  const int NT = Kd / 64;
  stage_half8(Asrc,                      Kd, &lds[0][0][0],    w, lane);
  stage_half8(Asrc + (size_t)128 * Kd,   Kd, &lds[0][0][8192], w, lane);
  stage_half8(Bsrc,                      Kd, &lds[0][1][0],    w, lane);
  stage_half8(Bsrc + (size_t)128 * Kd,   Kd, &lds[0][1][8192], w, lane);

  for (int t = 0; t < NT; ++t) {
    int cur = t & 1, nxt = cur ^ 1;
    int k1 = (t + 1) * 64;
    const __bf16* Ab = &lds[cur][0][0];
    const __bf16* Bb = &lds[cur][1][0];
    bf16x8 bfr[4][2];
    #pragma unroll
    for (int p = 0; p < 4; ++p) {
      if (t < NT - 1) {
        const __bf16* s;
        __bf16* d;
        if (p == 0)      { s = Asrc + k1;                    d = &lds[nxt][0][0]; }
        else if (p == 1) { s = Asrc + (size_t)128 * Kd + k1; d = &lds[nxt][0][8192]; }
        else if (p == 2) { s = Bsrc + k1;                    d = &lds[nxt][1][0]; }
        else             { s = Bsrc + (size_t)128 * Kd + k1; d = &lds[nxt][1][8192]; }
        stage_half8(s, Kd, d, w, lane);
      }
      if (p == 0) {
        if (t < NT - 1) asm volatile("s_waitcnt vmcnt(2)" ::: "memory");
        else            asm volatile("s_waitcnt vmcnt(0)" ::: "memory");
        __builtin_amdgcn_s_barrier();
        #pragma unroll
        for (int nn = 0; nn < 4; ++nn)
          #pragma unroll
          for (int kk = 0; kk < 2; ++kk)
            bfr[nn][kk] = lds_frag64(Bb, wc * 64 + nn * 16 + lr, kk * 32 + lg * 8);
      }
      bf16x8 af[2][2];
      #pragma unroll
      for (int mm = 0; mm < 2; ++mm)
        #pragma unroll
        for (int kk = 0; kk < 2; ++kk)
          af[mm][kk] = lds_frag64(Ab, wr * 128 + p * 32 + mm * 16 + lr, kk * 32 + lg * 8);
      asm volatile("s_waitcnt lgkmcnt(0)" ::: "memory");
      __builtin_amdgcn_sched_barrier(0);
      __builtin_amdgcn_s_setprio(1);
      #pragma unroll
      for (int mm = 0; mm < 2; ++mm)
        #pragma unroll
        for (int nn = 0; nn < 4; ++nn) {
          acc[p * 2 + mm][nn] = __builtin_amdgcn_mfma_f32_16x16x32_bf16(af[mm][0], bfr[nn][0], acc[p * 2 + mm][nn], 0, 0, 0);
          acc[p * 2 + mm][nn] = __builtin_amdgcn_mfma_f32_16x16x32_bf16(af[mm][1], bfr[nn][1], acc[p * 2 + mm][nn], 0, 0, 0);
        }
      __builtin_amdgcn_s_setprio(0);
    }
    __builtin_amdgcn_s_barrier();
  }

  #pragma unroll
  for (int mg = 0; mg < 8; ++mg) {
    #pragma unroll
    for (int nn = 0; nn < 4; ++nn) {
      int c = col0 + wc * 64 + nn * 16 + lr;
      int rb = row0 + wr * 128 + mg * 16 + lg * 4;
      float b = bias[c];
      #pragma unroll
      for (int j = 0; j < 4; ++j)
        out[(size_t)(rb + j) * N + c] = acc[mg][nn][j] + b;
    }
  }
}

// ---------------- fused attention: 8 waves, 16 q-rows, u16 scores ----------------
__global__ __launch_bounds__(512)
void attn_kernel(const __bf16* __restrict__ qm, const __bf16* __restrict__ km,
                 const __bf16* __restrict__ vt, __bf16* __restrict__ o) {
  __shared__ unsigned short sc16[16][SRS];
  __shared__ float ored[4][64][4];   // kt-half partials from waves 4-7
  __shared__ float rs[16];           // reciprocal row sums
  const int q0 = blockIdx.x * 16;
  const int hh = blockIdx.y;
  const int bb = blockIdx.z;
  const int tid = threadIdx.x;
  const int lane = tid & 63, w = tid >> 6;   // 8 waves
  const int lr = lane & 15, lg = lane >> 4;

  const __bf16* qrow = qm + ((size_t)(bb * S_ + q0 + lr)) * D_ + hh * DK_;
  bf16x8 qf0 = *reinterpret_cast<const bf16x8*>(qrow + lg * 8);
  bf16x8 qf1 = *reinterpret_cast<const bf16x8*>(qrow + 32 + lg * 8);

  // ---- phase 1: scores via MFMA; 8 waves cover 128 keys per iteration ----
  const __bf16* kbase = km + ((size_t)bb * S_) * D_ + hh * DK_;
  #pragma unroll
  for (int kt = 0; kt < 8; ++kt) {
    int key0 = kt * 128 + w * 16;
    const __bf16* krow = kbase + (size_t)(key0 + lr) * D_;
    bf16x8 kf0 = *reinterpret_cast<const bf16x8*>(krow + lg * 8);
    bf16x8 kf1 = *reinterpret_cast<const bf16x8*>(krow + 32 + lg * 8);
    f32x4v d = {0.0f, 0.0f, 0.0f, 0.0f};
    __builtin_amdgcn_s_setprio(1);
    d = __builtin_amdgcn_mfma_f32_16x16x32_bf16(qf0, kf0, d, 0, 0, 0);
    d = __builtin_amdgcn_mfma_f32_16x16x32_bf16(qf1, kf1, d, 0, 0, 0);
    __builtin_amdgcn_s_setprio(0);
    #pragma unroll
    for (int j = 0; j < 4; ++j) {
      unsigned int u = f32_to_bf16_bits(d[j] * 0.125f);
      u = (u & 0x8000u) ? (~u & 0xFFFFu) : (u | 0x8000u);
      sc16[lg * 4 + j][key0 + lr] = (unsigned short)u;
    }
  }
  __syncthreads();

  // ---- phase 2: 32 threads per row (half-wave teams); 16-bit binary search ----
  {
    int r = tid >> 5, tc = tid & 31;
    const unsigned int* srow = reinterpret_cast<const unsigned int*>(&sc16[r][0]);
    unsigned int wv[16];   // 32 u16 values packed
    #pragma unroll
    for (int g = 0; g < 4; ++g) {
      uint4 t4 = *reinterpret_cast<const uint4*>(&srow[g * 128 + tc * 4]);
      wv[g * 4 + 0] = t4.x; wv[g * 4 + 1] = t4.y;
      wv[g * 4 + 2] = t4.z; wv[g * 4 + 3] = t4.w;
    }
    unsigned int umax = 0;
    #pragma unroll
    for (int i = 0; i < 16; ++i) {
      unsigned int a = wv[i] & 0xFFFFu, b = wv[i] >> 16;
      unsigned int mx = a > b ? a : b;
      umax = mx > umax ? mx : umax;
    }
    umax = red16umax(umax);
    {
      unsigned int other = (unsigned int)__shfl_xor((int)umax, 16, 32);
      umax = other > umax ? other : umax;
    }
    unsigned int lo = 0;
    for (int bit = 15; bit >= 0; --bit) {
      unsigned int cs = (lo | (1u << bit)) << 16;
      int cnt = 0;
      #pragma unroll
      for (int i = 0; i < 16; ++i) {
        cnt += ((wv[i] << 16) >= cs) ? 1 : 0;
        cnt += (wv[i] >= cs) ? 1 : 0;
      }
      cnt = red16i(cnt);
      cnt += __shfl_xor(cnt, 16, 32);
      if (cnt >= KTOP) lo |= (1u << bit);
    }
    unsigned int um = (umax & 0x8000u) ? (umax ^ 0x8000u) : (~umax & 0xFFFFu);
    float mval = __uint_as_float(um << 16);

    __bf16* P = reinterpret_cast<__bf16*>(&sc16[r][0]);
    float lsum = 0.0f;
    #pragma unroll
    for (int g = 0; g < 4; ++g) {
      bf16x8 pk;
      #pragma unroll
      for (int e = 0; e < 8; ++e) {
        unsigned int wrd = wv[g * 4 + (e >> 1)];
        unsigned int u = (e & 1) ? (wrd >> 16) : (wrd & 0xFFFFu);
        float p = 0.0f;
        if (u >= lo) {
          unsigned int ub = (u & 0x8000u) ? (u ^ 0x8000u) : (~u & 0xFFFFu);
          p = __expf(__uint_as_float(ub << 16) - mval);
        }
        pk[e] = (__bf16)p;
        lsum += (float)pk[e];
      }
      *reinterpret_cast<bf16x8*>(&P[tc * 8 + g * 256]) = pk;
    }
    lsum = red16f(lsum);
    lsum += __shfl_xor(lsum, 16, 32);
    if (tc == 0) rs[r] = 1.0f / lsum;
  }
  __syncthreads();

  // ---- phase 3: PV split across wave pairs (kt halves), LDS reduce ----
  {
    const __bf16* P0 = reinterpret_cast<const __bf16*>(&sc16[0][0]);
    int wc4 = w & 3;      // column group (16 cols each)
    int half = w >> 2;    // kt half
    const __bf16* vbase = vt + ((size_t)bb * D_ + hh * DK_ + wc4 * 16 + lr) * S_;
    const __bf16* prow = P0 + (size_t)lr * SRS;
    f32x4v oacc = {0.0f, 0.0f, 0.0f, 0.0f};
    int kt0 = half * 16;
    __builtin_amdgcn_s_setprio(1);
    #pragma unroll
    for (int kk = 0; kk < 16; ++kk) {
      int kt = kt0 + kk;
      bf16x8 a = *reinterpret_cast<const bf16x8*>(prow + kt * 32 + lg * 8);
      bf16x8 b = *reinterpret_cast<const bf16x8*>(vbase + kt * 32 + lg * 8);
      oacc = __builtin_amdgcn_mfma_f32_16x16x32_bf16(a, b, oacc, 0, 0, 0);
    }
    __builtin_amdgcn_s_setprio(0);
    if (half == 1) {
      float4 st;
      st.x = oacc[0]; st.y = oacc[1]; st.z = oacc[2]; st.w = oacc[3];
      *reinterpret_cast<float4*>(&ored[wc4][lane][0]) = st;
    }
    __syncthreads();
    if (half == 0) {
      float4 pv = *reinterpret_cast<const float4*>(&ored[wc4][lane][0]);
      oacc[0] += pv.x; oacc[1] += pv.y; oacc[2] += pv.z; oacc[3] += pv.w;
      #pragma unroll
      for (int j = 0; j < 4; ++j) {
        int qr = lg * 4 + j;
        float ov = oacc[j] * rs[qr];
        o[((size_t)(bb * S_ + q0 + qr)) * D_ + hh * DK_ + wc4 * 16 + lr] = (__bf16)ov;
      }
    }
  }
}

extern "C" void kernel_launch(void* const* d_in, const int* in_sizes, int n_in,
                              void* d_out, int out_size, void* d_ws, size_t ws_size,
                              hipStream_t stream) {
  (void)in_sizes; (void)n_in; (void)out_size; (void)ws_size;
  const int*   x    = (const int*)d_in[0];
  const float* tok  = (const float*)d_in[1];
  const float* pos  = (const float*)d_in[2];
  const float* Wq   = (const float*)d_in[3];
  const float* bq   = (const float*)d_in[4];
  const float* Wk   = (const float*)d_in[5];
  const float* bk   = (const float*)d_in[6];
  const float* Wv   = (const float*)d_in[7];
  const float* bv   = (const float*)d_in[8];
  const float* Wo   = (const float*)d_in[9];
  const float* bo   = (const float*)d_in[10];
  const float* g1   = (const float*)d_in[11];
  const float* be1  = (const float*)d_in[12];
  const float* g2   = (const float*)d_in[13];
  const float* be2  = (const float*)d_in[14];
  const float* W1   = (const float*)d_in[15];
  const float* b1   = (const float*)d_in[16];
  const float* Wm   = (const float*)d_in[17];
  const float* bm   = (const float*)d_in[18];
  const float* W2   = (const float*)d_in[19];
  const float* b2   = (const float*)d_in[20];
  const float* Wout = (const float*)d_in[21];
  const float* bout = (const float*)d_in[22];
  float* logits = (float*)d_out;

  const int M = B_ * S_;  // 4096
  float* ws = (float*)d_ws;
  float* h    = ws;
  float* bqkv = h + (size_t)M * D_;
  __bf16* y16  = (__bf16*)(bqkv + (size_t)L_ * 1536);
  __bf16* f1b  = y16  + (size_t)M * D_;
  __bf16* f2b  = f1b  + (size_t)M * DFF_;
  __bf16* qb16 = f2b  + (size_t)M * DFF_;
  __bf16* kb16 = qb16 + (size_t)M * D_;
  __bf16* vt16 = kb16 + (size_t)M * D_;
  __bf16* ob16 = vt16 + (size_t)M * D_;
  __bf16* h16  = ob16 + (size_t)M * D_;
  __bf16* WqkvT = h16 + (size_t)M * D_;
  __bf16* WoT  = WqkvT + (size_t)L_ * 1536 * D_;
  __bf16* W1T  = WoT  + (size_t)L_ * D_ * D_;
  __bf16* WmT  = W1T  + (size_t)L_ * D_ * DFF_;
  __bf16* W2T  = WmT  + (size_t)L_ * DFF_ * DFF_;
  __bf16* WoutT = W2T + (size_t)L_ * D_ * DFF_;

  // ---- batched weight transposes: one dispatch, 8 jobs ----
  TJobs tj;
  int base = 0;
  auto addjob = [&](int idx, const float* src, __bf16* dst, int Kd, int N,
                    long ibs, long obs, int nz) {
    TJob& J = tj.j[idx];
    J.src = src; J.dst = dst; J.Kd = Kd; J.N = N;
    J.nx = N / 32; J.ny = Kd / 32; J.ibs = ibs; J.obs = obs;
    J.base = base; J.cnt = J.nx * J.ny * nz;
    base += J.cnt;
  };
  const long DD = (long)D_ * D_;
  addjob(0, Wq,   WqkvT,            D_,   D_,   DD, 1536L * D_, L_);
  addjob(1, Wk,   WqkvT + 512*512,  D_,   D_,   DD, 1536L * D_, L_);
  addjob(2, Wv,   WqkvT + 1024*512, D_,   D_,   DD, 1536L * D_, L_);
  addjob(3, Wo,   WoT,              D_,   D_,   DD, DD,          L_);
  addjob(4, W1,   W1T,              D_,   DFF_, (long)D_*DFF_, (long)D_*DFF_, L_);
  addjob(5, Wm,   WmT,              DFF_, DFF_, (long)DFF_*DFF_, (long)DFF_*DFF_, L_);
  addjob(6, W2,   W2T,              DFF_, D_,   (long)D_*DFF_, (long)D_*DFF_, L_);
  addjob(7, Wout, WoutT,            D_,   V_,   (long)D_*V_,   (long)D_*V_,   1);
  transpose_batch_kernel<<<base, 256, 0, stream>>>(tj);

  concat_bias_kernel<<<(L_*1536)/256, 256, 0, stream>>>(bq, bk, bv, bqkv);
  embed_kernel<<<M, 128, 0, stream>>>(x, tok, pos, h);

  for (int l = 0; l < L_; ++l) {
    ln_kernel<<<M/4, 256, 0, stream>>>(h, g1 + l * D_, be1 + l * D_, y16);
    gemm_n128_kernel<32,4,false,false><<<dim3((M/32) * (1536/BN)), 256, 0, stream>>>(
        y16, WqkvT + (size_t)l * 1536 * D_, bqkv + l * 1536, nullptr,
        qb16, kb16, vt16, M, 1536, D_);
    attn_kernel<<<dim3(S_/16, H_, B_), 512, 0, stream>>>(qb16, kb16, vt16, ob16);
    gemm_n128_kernel<32,0,false,true><<<dim3((M/32) * (D_/BN)), 256, 0, stream>>>(
        ob16, WoT + (size_t)l * DD, bo + l * D_, h, h, nullptr, nullptr, M, D_, D_);
    ln_kernel<<<M/4, 256, 0, stream>>>(h, g2 + l * D_, be2 + l * D_, y16);
    gemm_n128_kernel<32,1,true,false><<<dim3((M/32) * (DFF_/BN)), 256, 0, stream>>>(
        y16, W1T + (size_t)l * D_ * DFF_, b1 + l * DFF_, nullptr, f1b, nullptr, nullptr, M, DFF_, D_);
    gemm_n128_kernel<64,1,true,false><<<dim3((M/64) * (DFF_/BN)), 256, 0, stream>>>(
        f1b, WmT + (size_t)l * DFF_ * DFF_, bm + l * DFF_, nullptr, f2b, nullptr, nullptr, M, DFF_, DFF_);
    gemm_n128_kernel<32,3,false,true><<<dim3((M/32) * (D_/BN)), 256, 0, stream>>>(
        f2b, W2T + (size_t)l * D_ * DFF_, b2 + l * D_, h, h, h16, nullptr, M, D_, DFF_);
  }
  gemm_head_kernel<<<dim3((M/256) * (V_/256)), 512, 0, stream>>>(
      h16, WoutT, bout, logits, M, V_, D_);
}